// Round 2
// baseline (8790.197 us; speedup 1.0000x reference)
//
#include <hip/hip_runtime.h>
#include <math.h>

// ---- problem constants (from reference) ----
#define N_   8192
#define E_   131072
#define T_   262144
#define H_   128
#define IND_ 64
#define G_   32
#define L_   2

// generic GEMM tiling
#define CW 64   // K-chunk width staged in LDS
#define RB 16   // rows per block-iteration (register accumulators)

// fused 2-layer MLP tiling
#define FCW 64
#define FRB 16

// RBF constants
#define STEP_E  ((float)(5.0/31.0))
#define GAMMA_E ((float)(1.0/(2.0*((5.0/31.0)*(5.0/31.0) + 1e-12))))
#define PI_D    3.14159265358979323846
#define STEP_A  ((float)(PI_D/15.0))
#define GAMMA_A ((float)(1.0/(2.0*((PI_D/15.0)*(PI_D/15.0) + 1e-12))))

static __device__ __forceinline__ float silu_f(float x){ return x / (1.f + expf(-x)); }
static __device__ __forceinline__ float sigmoid_f(float x){ return 1.f / (1.f + expf(-x)); }

// ---------------- small utility kernels ----------------

__global__ void k_zero(float* __restrict__ p, long n){
  long i = (long)blockIdx.x*256 + threadIdx.x;
  long stride = (long)gridDim.x*256;
  for (; i < n; i += stride) p[i] = 0.f;
}

__global__ void k_sentinel(float* __restrict__ p, int n){
  int i = blockIdx.x*256 + threadIdx.x;
  if (i < n) p[i] = 1.0e30f;
}

__global__ void k_init_vn(float* __restrict__ vn, const float* __restrict__ vn_init){
  int i = blockIdx.x*256 + threadIdx.x;
  if (i < G_*H_) vn[i] = vn_init[i & 127];
}

// per-edge: vec, dir, edge RBF(32)
__global__ void k_geom(const float* __restrict__ pos, const float* __restrict__ dist,
                       const int* __restrict__ ei,
                       float* __restrict__ vec, float* __restrict__ dir,
                       float* __restrict__ rbf){
  int e = blockIdx.x*256 + threadIdx.x;
  if (e >= E_) return;
  int s = ei[e], d = ei[E_ + e];
  float vx = pos[d*3+0] - pos[s*3+0];
  float vy = pos[d*3+1] - pos[s*3+1];
  float vz = pos[d*3+2] - pos[s*3+2];
  vec[e*3+0]=vx; vec[e*3+1]=vy; vec[e*3+2]=vz;
  float dd = dist[e];
  float inv = 1.f / (dd + 1e-9f);
  dir[e*3+0]=vx*inv; dir[e*3+1]=vy*inv; dir[e*3+2]=vz*inv;
  #pragma unroll
  for (int i=0;i<32;i++){
    float df = dd - i*STEP_E;
    rbf[e*32+i] = expf(-GAMMA_E*df*df);
  }
}

// per-triplet: just the angle (features computed on the fly in fused MLP)
__global__ void k_angle(const float* __restrict__ vec,
                        const int* __restrict__ kj, const int* __restrict__ ji,
                        float* __restrict__ angle){
  int t = blockIdx.x*256 + threadIdx.x;
  if (t >= T_) return;
  int ea = ji[t], eb = kj[t];   // a = vec[ji], b = vec[kj]
  float ax=vec[ea*3+0], ay=vec[ea*3+1], az=vec[ea*3+2];
  float bx=vec[eb*3+0], by=vec[eb*3+1], bz=vec[eb*3+2];
  float dot = ax*bx + ay*by + az*bz;
  float na = sqrtf(ax*ax+ay*ay+az*az + 1e-12f);
  float nb = sqrtf(bx*bx+by*by+bz*bz + 1e-12f);
  float c = dot / (na*nb + 1e-9f);
  c = fminf(fmaxf(c, -1.f + 1e-7f), 1.f - 1e-7f);
  angle[t] = acosf(c);
}

// ---------------- fused 2-layer MLP + scatter ----------------
// SM==1 (triplet): in = [rbf[kj] (32) | rbf[ji] (32) | angRBF(angle[row]) (16)], K1=80
//                  out (128) -> atomicAdd eagg[ji[row]*128 + col]
// SM==2 (edge):    in = [s[src] | s[dst] | rbf[row] | eagg[row]], K1=416
//                  out (256): cols 0..127 -> atomicAdd aggs[dst*128+c]
//                             cols 128..255 -> atomicAdd aggv[(dst*128+c)*3+xyz] += m*dir
__launch_bounds__(128)
__global__ void k_mlp2_fused(int SM,
    const int* __restrict__ idx1, const int* __restrict__ idx2,
    const float* __restrict__ rbf, const float* __restrict__ angle,
    const float* __restrict__ s_in, const float* __restrict__ eagg_in,
    const float* __restrict__ W1, const float* __restrict__ b1, int K1,
    const float* __restrict__ W2, const float* __restrict__ b2, int OUTgrp,
    const float* __restrict__ dir,
    float* __restrict__ out0, float* __restrict__ out1,
    int R)
{
  __shared__ float ws[FCW*128];     // 32 KB
  __shared__ float as[FRB][FCW];    // 4 KB
  __shared__ float hb[FRB][128];    // 8 KB
  const int tid = threadIdx.x;
  const int OS2 = OUTgrp*128;
  const int nch = (K1 + FCW - 1)/FCW;

  for (int rb = blockIdx.x*FRB; rb < R; rb += gridDim.x*FRB){
    // ---------- phase A: hidden = silu(in @ W1 + b1) ----------
    float acc[FRB];
    #pragma unroll
    for (int r=0;r<FRB;r++) acc[r] = 0.f;

    for (int c=0;c<nch;c++){
      const int k0 = c*FCW;
      for (int i=tid; i<FCW*128; i+=128){
        int kk = i >> 7, col = i & 127;
        int k = k0 + kk;
        ws[i] = (k < K1) ? W1[k*128 + col] : 0.f;
      }
      for (int i=tid; i<FRB*FCW; i+=128){
        int r = i >> 6, kk = i & 63;
        int k = k0 + kk;
        int row = rb + r;
        float v = 0.f;
        if (k < K1){
          if (SM == 1){
            if (k < 32)       v = rbf[idx1[row]*32 + k];
            else if (k < 64)  v = rbf[idx2[row]*32 + (k-32)];
            else { float df = angle[row] - (k-64)*STEP_A; v = expf(-GAMMA_A*df*df); }
          } else {
            if (k < 128)      v = s_in[idx1[row]*128 + k];
            else if (k < 256) v = s_in[idx2[row]*128 + (k-128)];
            else if (k < 288) v = rbf[row*32 + (k-256)];
            else              v = eagg_in[row*128 + (k-288)];
          }
        }
        as[r][kk] = v;
      }
      __syncthreads();
      #pragma unroll 4
      for (int kq=0; kq<FCW/4; kq++){
        float w0 = ws[(4*kq+0)*128 + tid];
        float w1 = ws[(4*kq+1)*128 + tid];
        float w2 = ws[(4*kq+2)*128 + tid];
        float w3 = ws[(4*kq+3)*128 + tid];
        #pragma unroll
        for (int r=0;r<FRB;r++){
          const float4 av = *reinterpret_cast<const float4*>(&as[r][4*kq]);
          acc[r] = fmaf(av.x, w0, acc[r]);
          acc[r] = fmaf(av.y, w1, acc[r]);
          acc[r] = fmaf(av.z, w2, acc[r]);
          acc[r] = fmaf(av.w, w3, acc[r]);
        }
      }
      __syncthreads();
    }
    {
      const float b1v = b1[tid];
      #pragma unroll
      for (int r=0;r<FRB;r++) hb[r][tid] = silu_f(acc[r] + b1v);
    }
    __syncthreads();

    // ---------- phase B: out = hidden @ W2 + b2, scatter ----------
    for (int og=0; og<OUTgrp; og++){
      float acc2[FRB];
      #pragma unroll
      for (int r=0;r<FRB;r++) acc2[r] = 0.f;
      for (int c2=0; c2<2; c2++){           // K2 = 128 = 2*FCW
        const int k0 = c2*FCW;
        for (int i=tid; i<FCW*128; i+=128){
          int kk = i >> 7, col = i & 127;
          ws[i] = W2[(k0+kk)*OS2 + og*128 + col];
        }
        __syncthreads();
        #pragma unroll 4
        for (int kq=0; kq<FCW/4; kq++){
          float w0 = ws[(4*kq+0)*128 + tid];
          float w1 = ws[(4*kq+1)*128 + tid];
          float w2 = ws[(4*kq+2)*128 + tid];
          float w3 = ws[(4*kq+3)*128 + tid];
          #pragma unroll
          for (int r=0;r<FRB;r++){
            const float4 hv = *reinterpret_cast<const float4*>(&hb[r][k0 + 4*kq]);
            acc2[r] = fmaf(hv.x, w0, acc2[r]);
            acc2[r] = fmaf(hv.y, w1, acc2[r]);
            acc2[r] = fmaf(hv.z, w2, acc2[r]);
            acc2[r] = fmaf(hv.w, w3, acc2[r]);
          }
        }
        __syncthreads();
      }
      const float b2v = b2[og*128 + tid];
      if (SM == 1 || og == 0){
        // scalar message -> out0[idx2[row]*128 + tid]
        #pragma unroll
        for (int r=0;r<FRB;r++){
          int row = rb + r;
          atomicAdd(&out0[idx2[row]*128 + tid], acc2[r] + b2v);
        }
      } else {
        // vector message: m * dir -> out1[(dst*128+tid)*3 + xyz]
        #pragma unroll
        for (int r=0;r<FRB;r++){
          int row = rb + r;
          float m = acc2[r] + b2v;
          int dnode = idx2[row];
          float dx = dir[row*3+0], dy = dir[row*3+1], dz = dir[row*3+2];
          int base = (dnode*128 + tid)*3;
          atomicAdd(&out1[base+0], m*dx);
          atomicAdd(&out1[base+1], m*dy);
          atomicAdd(&out1[base+2], m*dz);
        }
      }
    }
  }
}

// ---------------- generic row-MLP GEMM ----------------
// SM: 0 = direct A[r*K+k]
//     3 = ctx gather: k<128 -> g1(s), k<256 -> g2(aggs), else ||g3 row|| (v norm)
// MODE: 0 = store, 1 = silu+store, 2 = C += (acc+bias)
__launch_bounds__(128)
__global__ void k_gemm(int SM, int MODE,
                       const float* __restrict__ A,
                       const float* __restrict__ g1, const float* __restrict__ g2,
                       const float* __restrict__ g3,
                       const float* __restrict__ W, int WS, int woff,
                       const float* __restrict__ bias,
                       float* __restrict__ C, int OS, int coff,
                       int R, int K)
{
  __shared__ float ws[CW*128];
  __shared__ float as[RB][CW];
  const int tid = threadIdx.x;
  const int nchunk = (K + CW - 1) / CW;

  for (int rb = blockIdx.x*RB; rb < R; rb += gridDim.x*RB){
    float acc[RB];
    #pragma unroll
    for (int r=0;r<RB;r++) acc[r] = 0.f;

    for (int c=0;c<nchunk;c++){
      const int k0 = c*CW;
      for (int i=tid; i<CW*128; i+=128){
        int kk = i >> 7, col = i & 127;
        int k = k0 + kk;
        ws[i] = (k < K) ? W[k*WS + woff + col] : 0.f;
      }
      for (int i=tid; i<RB*CW; i+=128){
        int r  = i >> 6, kk = i & 63;
        int k  = k0 + kk;
        int row = rb + r;
        float v = 0.f;
        if (k < K){
          if (SM == 0){
            v = A[(long)row*K + k];
          } else {
            if (k < 128)      v = g1[row*128 + k];
            else if (k < 256) v = g2[row*128 + (k-128)];
            else {
              int h = k - 256;
              float v0 = g3[(row*128+h)*3+0];
              float v1 = g3[(row*128+h)*3+1];
              float v2 = g3[(row*128+h)*3+2];
              v = sqrtf(v0*v0 + v1*v1 + v2*v2 + 1e-12f);
            }
          }
        }
        as[r][kk] = v;
      }
      __syncthreads();
      #pragma unroll 4
      for (int kq=0; kq<CW/4; kq++){
        float w0 = ws[(4*kq+0)*128 + tid];
        float w1 = ws[(4*kq+1)*128 + tid];
        float w2 = ws[(4*kq+2)*128 + tid];
        float w3 = ws[(4*kq+3)*128 + tid];
        #pragma unroll
        for (int r=0;r<RB;r++){
          const float4 av = *reinterpret_cast<const float4*>(&as[r][4*kq]);
          acc[r] = fmaf(av.x, w0, acc[r]);
          acc[r] = fmaf(av.y, w1, acc[r]);
          acc[r] = fmaf(av.z, w2, acc[r]);
          acc[r] = fmaf(av.w, w3, acc[r]);
        }
      }
      __syncthreads();
    }

    const float bv = bias[woff + tid];
    #pragma unroll
    for (int r=0;r<RB;r++){
      int row = rb + r;
      float v = acc[r] + bv;
      if (MODE == 1) v = silu_f(v);
      float* cp = &C[(long)row*OS + coff + tid];
      if (MODE == 2) *cp += v; else *cp = v;
    }
  }
}

// ---------------- elementwise / reduction kernels ----------------

__global__ void k_sadd_batch(float* __restrict__ s, const float* __restrict__ t2,
                             const int* __restrict__ batch){
  int i = blockIdx.x*256 + threadIdx.x;
  if (i >= N_*H_) return;
  int n = i >> 7, h = i & 127;
  s[i] += t2[batch[n]*128 + h];
}

__global__ void k_gate_v(const float* __restrict__ dg, const float* __restrict__ aggv,
                         float* __restrict__ v){
  int i = blockIdx.x*256 + threadIdx.x;
  if (i >= N_*H_) return;
  float g = sigmoid_f(dg[i]);
  v[i*3+0] += g*aggv[i*3+0];
  v[i*3+1] += g*aggv[i*3+1];
  v[i*3+2] += g*aggv[i*3+2];
}

__global__ void k_ln_silu(float* __restrict__ s, const float* __restrict__ g,
                          const float* __restrict__ b){
  __shared__ float red[128];
  int n = blockIdx.x, tid = threadIdx.x;
  float x = s[n*128 + tid];
  red[tid] = x; __syncthreads();
  for (int o=64;o>0;o>>=1){ if (tid<o) red[tid]+=red[tid+o]; __syncthreads(); }
  float mu = red[0] * (1.f/128.f);
  __syncthreads();
  float dx = x - mu;
  red[tid] = dx*dx; __syncthreads();
  for (int o=64;o>0;o>>=1){ if (tid<o) red[tid]+=red[tid+o]; __syncthreads(); }
  float var = red[0] * (1.f/128.f);
  float y = dx * rsqrtf(var + 1e-5f) * g[tid] + b[tid];
  s[n*128 + tid] = silu_f(y);
}

__global__ void k_segsum(const float* __restrict__ s, const int* __restrict__ batch,
                         float* __restrict__ ssum){
  int i = blockIdx.x*256 + threadIdx.x;
  if (i >= N_*H_) return;
  int n = i >> 7, h = i & 127;
  atomicAdd(&ssum[batch[n]*128 + h], s[i]);
}

__global__ void k_scatter_nf(const float* __restrict__ s, const float* __restrict__ v,
                             const int* __restrict__ batch, float* __restrict__ addp){
  int i = blockIdx.x*256 + threadIdx.x;
  if (i >= N_*256) return;
  int n = i >> 8, j = i & 255;
  float val;
  if (j < 128){
    val = s[n*128 + j];
  } else {
    int h = j - 128;
    float v0 = v[(n*128+h)*3+0], v1 = v[(n*128+h)*3+1], v2 = v[(n*128+h)*3+2];
    val = sqrtf(v0*v0 + v1*v1 + v2*v2 + 1e-12f);
  }
  atomicAdd(&addp[batch[n]*256 + j], val);
}

__global__ void k_counts(const int* __restrict__ batch, float* __restrict__ counts){
  int n = blockIdx.x*256 + threadIdx.x;
  if (n < N_) atomicAdd(&counts[batch[n]], 1.f);
}

__global__ void k_build_g(const float* __restrict__ addp, const float* __restrict__ counts,
                          const float* __restrict__ vn, float* __restrict__ gbuf){
  int i = blockIdx.x*256 + threadIdx.x;
  if (i >= G_*640) return;
  int g = i / 640, j = i % 640;
  float val;
  if (j < 256)       val = addp[g*256 + j];
  else if (j < 512)  val = addp[g*256 + (j-256)] / fmaxf(counts[g], 1.f);
  else               val = vn[g*128 + (j-512)];
  gbuf[i] = val;
}

__global__ void k_head_final(const float* __restrict__ hh, const float* __restrict__ w2,
                             const float* __restrict__ b2, float* __restrict__ out){
  __shared__ float red[128];
  int g = blockIdx.x, tid = threadIdx.x;
  red[tid] = hh[g*128 + tid] * w2[tid];
  __syncthreads();
  for (int o=64;o>0;o>>=1){ if (tid<o) red[tid]+=red[tid+o]; __syncthreads(); }
  if (tid == 0) out[g] = red[0] + b2[0];
}

// ---------------- host launcher ----------------

extern "C" void kernel_launch(void* const* d_in, const int* in_sizes, int n_in,
                              void* d_out, int out_size, void* d_ws, size_t ws_size,
                              hipStream_t stream)
{
  const float* x         = (const float*)d_in[0];
  const float* pos       = (const float*)d_in[1];
  const float* edist     = (const float*)d_in[2];
  const float* node_in_w = (const float*)d_in[3];
  const float* node_in_b = (const float*)d_in[4];
  const float* tm_w1 = (const float*)d_in[5];
  const float* tm_b1 = (const float*)d_in[6];
  const float* tm_w2 = (const float*)d_in[7];
  const float* tm_b2 = (const float*)d_in[8];
  const float* mm_w1 = (const float*)d_in[9];
  const float* mm_b1 = (const float*)d_in[10];
  const float* mm_w2 = (const float*)d_in[11];
  const float* mm_b2 = (const float*)d_in[12];
  const float* us_w1 = (const float*)d_in[13];
  const float* us_b1 = (const float*)d_in[14];
  const float* us_w2 = (const float*)d_in[15];
  const float* us_b2 = (const float*)d_in[16];
  const float* gv_w1 = (const float*)d_in[17];
  const float* gv_b1 = (const float*)d_in[18];
  const float* gv_w2 = (const float*)d_in[19];
  const float* gv_b2 = (const float*)d_in[20];
  const float* ln_g  = (const float*)d_in[21];
  const float* ln_b  = (const float*)d_in[22];
  const float* vn_init = (const float*)d_in[23];
  const float* v2n_w1 = (const float*)d_in[24];
  const float* v2n_b1 = (const float*)d_in[25];
  const float* v2n_w2 = (const float*)d_in[26];
  const float* v2n_b2 = (const float*)d_in[27];
  const float* n2v_w1 = (const float*)d_in[28];
  const float* n2v_b1 = (const float*)d_in[29];
  const float* n2v_w2 = (const float*)d_in[30];
  const float* n2v_b2 = (const float*)d_in[31];
  const float* head_w1 = (const float*)d_in[32];
  const float* head_b1 = (const float*)d_in[33];
  const float* head_w2 = (const float*)d_in[34];
  const float* head_b2 = (const float*)d_in[35];
  const int* ei    = (const int*)d_in[36];
  const int* t_kj  = (const int*)d_in[37];
  const int* t_ji  = (const int*)d_in[38];
  const int* batch = (const int*)d_in[39];
  float* out = (float*)d_out;

  // ---- workspace layout (fp32). Total ~124.2 MiB ----
  float* f = (float*)d_ws;
  size_t off = 0;
  auto alloc = [&](size_t n){ float* p = f + off; off += n; return p; };
  float* vec   = alloc((size_t)E_*3);     // 1.5 MB
  float* dir   = alloc((size_t)E_*3);     // 1.5 MB
  float* rbf   = alloc((size_t)E_*32);    // 16 MB
  float* angle = alloc((size_t)T_);       // 1 MB
  float* eagg  = alloc((size_t)E_*128);   // 64 MB
  float* s     = alloc((size_t)N_*128);   // 4 MB
  float* v     = alloc((size_t)N_*384);   // 12 MB
  float* aggs  = alloc((size_t)N_*128);   // 4 MB
  float* aggv  = alloc((size_t)N_*384);   // 12 MB
  float* hu    = alloc((size_t)N_*128);   // 4 MB
  float* hg    = alloc((size_t)N_*128);   // 4 MB
  float* vn    = alloc((size_t)G_*128);
  float* tg1   = alloc((size_t)G_*128);
  float* tg2   = alloc((size_t)G_*128);
  float* ssum  = alloc((size_t)G_*128);
  float* addp  = alloc((size_t)G_*256);
  float* counts= alloc((size_t)G_);
  float* gbuf  = alloc((size_t)G_*640);
  float* hh    = alloc((size_t)G_*128);

  if (off * sizeof(float) > ws_size){
    // diagnostic sentinel: absmax ~1e30 means "workspace too small"
    k_sentinel<<<1, 64, 0, stream>>>(out, G_);
    return;
  }

  auto zero = [&](float* p, long n){
    int blocks = (int)((n + 255)/256); if (blocks > 16384) blocks = 16384;
    k_zero<<<blocks, 256, 0, stream>>>(p, n);
  };
  auto gemm = [&](int SM, int MODE, const float* A,
                  const float* g1, const float* g2, const float* g3,
                  const float* W, int WS, int woff, const float* bias,
                  float* C, int OS, int coff, int R, int K){
    int nblk = (R + RB - 1)/RB; if (nblk > 4096) nblk = 4096;
    k_gemm<<<nblk, 128, 0, stream>>>(SM, MODE, A, g1, g2, g3,
                                     W, WS, woff, bias, C, OS, coff, R, K);
  };
  auto fused = [&](int SM, const int* i1, const int* i2,
                   const float* W1, const float* b1, int K1,
                   const float* W2, const float* b2, int OUTgrp,
                   float* o0, float* o1, int R){
    int nblk = (R + FRB - 1)/FRB; if (nblk > 8192) nblk = 8192;
    k_mlp2_fused<<<nblk, 128, 0, stream>>>(SM, i1, i2, rbf, angle, s, eagg,
                                           W1, b1, K1, W2, b2, OUTgrp, dir, o0, o1, R);
  };

  // ---- prologue ----
  zero(v, (long)N_*384);
  k_init_vn<<<(G_*H_ + 255)/256, 256, 0, stream>>>(vn, vn_init);
  k_geom<<<(E_ + 255)/256, 256, 0, stream>>>(pos, edist, ei, vec, dir, rbf);
  k_angle<<<(T_ + 255)/256, 256, 0, stream>>>(vec, t_kj, t_ji, angle);
  // s = x @ node_in_w + b
  gemm(0,0, x, nullptr,nullptr,nullptr,
       node_in_w,128,0, node_in_b, s,128,0, N_, IND_);

  for (int l=0; l<L_; l++){
    // 1) s += v2n_mlp(vn)[batch]
    gemm(0,1, vn, nullptr,nullptr,nullptr, v2n_w1,128,0, v2n_b1, tg1,128,0, G_,128);
    gemm(0,0, tg1,nullptr,nullptr,nullptr, v2n_w2,128,0, v2n_b2, tg2,128,0, G_,128);
    k_sadd_batch<<<(N_*H_ + 255)/256, 256, 0, stream>>>(s, tg2, batch);

    // 2) triplet MLP fused -> eagg (segment-sum over ji)
    zero(eagg, (long)E_*128);
    fused(1, t_kj, t_ji,
          tm_w1 + l*80*128,  tm_b1 + l*128, 80,
          tm_w2 + l*128*128, tm_b2 + l*128, 1,
          eagg, nullptr, T_);

    // 3) edge MLP fused -> aggs, aggv
    zero(aggs, (long)N_*128);
    zero(aggv, (long)N_*384);
    fused(2, ei, ei + E_,
          mm_w1 + l*416*128, mm_b1 + l*128, 416,
          mm_w2 + l*128*256, mm_b2 + l*256, 2,
          aggs, aggv, E_);

    // 4+5) hu = silu(ctx@us_w1+b) ; hg = silu(ctx@gv_w1+b)   [ctx gathered, pre-update s]
    gemm(3,1, nullptr, s, aggs, v, us_w1 + l*384*128,128,0, us_b1 + l*128, hu,128,0, N_,384);
    gemm(3,1, nullptr, s, aggs, v, gv_w1 + l*384*128,128,0, gv_b1 + l*128, hg,128,0, N_,384);
    // s += hu @ us_w2 + b
    gemm(0,2, hu, nullptr,nullptr,nullptr, us_w2 + l*128*128,128,0, us_b2 + l*128, s,128,0, N_,128);
    // dg = hg @ gv_w2 + b  (reuse hu buffer; hu is dead now)
    gemm(0,0, hg, nullptr,nullptr,nullptr, gv_w2 + l*128*128,128,0, gv_b2 + l*128, hu,128,0, N_,128);
    k_gate_v<<<(N_*H_ + 255)/256, 256, 0, stream>>>(hu, aggv, v);

    // 7) s = silu(LN(s))
    k_ln_silu<<<N_, 128, 0, stream>>>(s, ln_g + l*128, ln_b + l*128);

    // 8) vn += n2v_mlp(segment_sum(s, batch))
    zero(ssum, (long)G_*128);
    k_segsum<<<(N_*H_ + 255)/256, 256, 0, stream>>>(s, batch, ssum);
    gemm(0,1, ssum,nullptr,nullptr,nullptr, n2v_w1,128,0, n2v_b1, tg1,128,0, G_,128);
    gemm(0,2, tg1, nullptr,nullptr,nullptr, n2v_w2,128,0, n2v_b2, vn,128,0, G_,128);
  }

  // ---- readout ----
  zero(addp, (long)(G_*256 + G_));   // addp and counts are contiguous
  k_scatter_nf<<<(N_*256 + 255)/256, 256, 0, stream>>>(s, v, batch, addp);
  k_counts<<<(N_ + 255)/256, 256, 0, stream>>>(batch, counts);
  k_build_g<<<(G_*640 + 255)/256, 256, 0, stream>>>(addp, counts, vn, gbuf);
  gemm(0,1, gbuf,nullptr,nullptr,nullptr, head_w1,128,0, head_b1, hh,128,0, G_,640);
  k_head_final<<<G_, 128, 0, stream>>>(hh, head_w2, head_b2, out);
}

// Round 3
// 3766.728 us; speedup vs baseline: 2.3336x; 2.3336x over previous
//
#include <hip/hip_runtime.h>
#include <math.h>

// ---- problem constants (from reference) ----
#define N_   8192
#define E_   131072
#define T_   262144
#define H_   128
#define IND_ 64
#define G_   32
#define L_   2

// generic fp32 GEMM tiling (node-level MLPs)
#define CW 64
#define RB 16

// MFMA fused MLP tiling
#define MROWS 32     // rows per wave
#define BROWS 128    // rows per block (4 waves)
#define HSTRIDE 136  // LDS hidden row stride (bf16 elems): 272B rows, 16B-aligned

// RBF constants
#define STEP_E  ((float)(5.0/31.0))
#define GAMMA_E ((float)(1.0/(2.0*((5.0/31.0)*(5.0/31.0) + 1e-12))))
#define PI_D    3.14159265358979323846
#define STEP_A  ((float)(PI_D/15.0))
#define GAMMA_A ((float)(1.0/(2.0*((PI_D/15.0)*(PI_D/15.0) + 1e-12))))

typedef __attribute__((ext_vector_type(8))) short short8;
typedef __attribute__((ext_vector_type(4))) float f32x4;
typedef unsigned short ushort_t;

static __device__ __forceinline__ float silu_f(float x){ return x / (1.f + expf(-x)); }
static __device__ __forceinline__ float sigmoid_f(float x){ return 1.f / (1.f + expf(-x)); }

// RNE float->bf16 (values here are finite; no NaN handling needed)
static __device__ __forceinline__ ushort_t f2bf(float x){
  unsigned int u = __builtin_bit_cast(unsigned int, x);
  u += 0x7FFFu + ((u >> 16) & 1u);
  return (ushort_t)(u >> 16);
}

// ---------------- small utility kernels ----------------

__global__ void k_zero(float* __restrict__ p, long n){
  long i = (long)blockIdx.x*256 + threadIdx.x;
  long stride = (long)gridDim.x*256;
  for (; i < n; i += stride) p[i] = 0.f;
}

__global__ void k_sentinel(float* __restrict__ p, int n){
  int i = blockIdx.x*256 + threadIdx.x;
  if (i < n) p[i] = 1.0e30f;
}

__global__ void k_init_vn(float* __restrict__ vn, const float* __restrict__ vn_init){
  int i = blockIdx.x*256 + threadIdx.x;
  if (i < G_*H_) vn[i] = vn_init[i & 127];
}

// fp32 -> bf16 copy
__global__ void k_cvt(const float* __restrict__ src, ushort_t* __restrict__ dst, int n){
  int i = blockIdx.x*256 + threadIdx.x;
  if (i < n) dst[i] = f2bf(src[i]);
}

// weight convert+transpose: W fp32 [K][C] -> Wt bf16 [C][Kpad] (zero-padded)
__global__ void k_wt(const float* __restrict__ W, ushort_t* __restrict__ Wt,
                     int K, int C, int Kpad){
  int i = blockIdx.x*256 + threadIdx.x;
  if (i >= C*Kpad) return;
  int c = i / Kpad, k = i % Kpad;
  Wt[i] = (k < K) ? f2bf(W[(size_t)k*C + c]) : (ushort_t)0;
}

// per-edge: vec, dir, edge RBF(32) in bf16
__global__ void k_geom(const float* __restrict__ pos, const float* __restrict__ dist,
                       const int* __restrict__ ei,
                       float* __restrict__ vec, float* __restrict__ dir,
                       ushort_t* __restrict__ rbf16){
  int e = blockIdx.x*256 + threadIdx.x;
  if (e >= E_) return;
  int s = ei[e], d = ei[E_ + e];
  float vx = pos[d*3+0] - pos[s*3+0];
  float vy = pos[d*3+1] - pos[s*3+1];
  float vz = pos[d*3+2] - pos[s*3+2];
  vec[e*3+0]=vx; vec[e*3+1]=vy; vec[e*3+2]=vz;
  float dd = dist[e];
  float inv = 1.f / (dd + 1e-9f);
  dir[e*3+0]=vx*inv; dir[e*3+1]=vy*inv; dir[e*3+2]=vz*inv;
  #pragma unroll
  for (int i=0;i<32;i++){
    float df = dd - i*STEP_E;
    rbf16[e*32+i] = f2bf(expf(-GAMMA_E*df*df));
  }
}

// per-triplet angle
__global__ void k_angle(const float* __restrict__ vec,
                        const int* __restrict__ kj, const int* __restrict__ ji,
                        float* __restrict__ angle){
  int t = blockIdx.x*256 + threadIdx.x;
  if (t >= T_) return;
  int ea = ji[t], eb = kj[t];
  float ax=vec[ea*3+0], ay=vec[ea*3+1], az=vec[ea*3+2];
  float bx=vec[eb*3+0], by=vec[eb*3+1], bz=vec[eb*3+2];
  float dot = ax*bx + ay*by + az*bz;
  float na = sqrtf(ax*ax+ay*ay+az*az + 1e-12f);
  float nb = sqrtf(bx*bx+by*by+bz*bz + 1e-12f);
  float c = dot / (na*nb + 1e-9f);
  c = fminf(fmaxf(c, -1.f + 1e-7f), 1.f - 1e-7f);
  angle[t] = acosf(c);
}

// ---------------- MFMA fused 2-layer MLP + scatter ----------------
// SM==1 (triplet, K1pad=96):  in = [rbf16[kj] | rbf16[ji] | angRBF(angle) pad], OUTgrp=1
//     out(128) -> atomicAdd out0[ji*128 + col]          (out0 = eagg fp32)
// SM==2 (edge, K1pad=416):    in = [s16[src] | s16[dst] | rbf16[row] | bf16(eagg fp32)]
//     OUTgrp=2: og0 -> atomicAdd out0[dst*128+col]      (aggs)
//               og1 -> atomicAdd out1[(dst*128+col)*3+xyz] += m*dir[row]  (aggv)
__launch_bounds__(256, 4)
__global__ void k_mlp2_mfma(int SM,
    const int* __restrict__ idx1, const int* __restrict__ idx2,
    const ushort_t* __restrict__ rbf16, const float* __restrict__ angle,
    const ushort_t* __restrict__ s16, const float* __restrict__ eagg_in,
    const ushort_t* __restrict__ W1t, const float* __restrict__ b1, int K1pad,
    const ushort_t* __restrict__ W2t, const float* __restrict__ b2, int OUTgrp,
    const float* __restrict__ dir,
    float* __restrict__ out0, float* __restrict__ out1)
{
  __shared__ ushort_t hid[BROWS*HSTRIDE];   // 34816 B
  const int tid  = threadIdx.x;
  const int wave = tid >> 6;
  const int lane = tid & 63;
  const int n    = lane & 15;
  const int quad = lane >> 4;
  const int kq   = quad*8;
  const int wrow = blockIdx.x*BROWS + wave*MROWS;  // global row base of this wave
  const int lrow = wave*MROWS;                     // LDS row base

  const int r0 = wrow + n;        // A-frag row (half 0)
  const int r1 = wrow + 16 + n;   // A-frag row (half 1)

  int i1a, i1b, i2a, i2b; float ang0 = 0.f, ang1 = 0.f;
  i1a = idx1[r0]; i1b = idx1[r1];
  i2a = idx2[r0]; i2b = idx2[r1];
  if (SM == 1){ ang0 = angle[r0]; ang1 = angle[r1]; }

  // ---------- phase A: hidden = silu(in @ W1 + b1) ----------
  f32x4 acc[2][8];
  #pragma unroll
  for (int rh=0;rh<2;rh++)
    #pragma unroll
    for (int ct=0;ct<8;ct++) acc[rh][ct] = (f32x4){0.f,0.f,0.f,0.f};

  for (int k0 = 0; k0 < K1pad; k0 += 32){
    short8 a0, a1;
    if (SM == 1){
      if (k0 == 0){
        a0 = *(const short8*)&rbf16[(size_t)i1a*32 + kq];
        a1 = *(const short8*)&rbf16[(size_t)i1b*32 + kq];
      } else if (k0 == 32){
        a0 = *(const short8*)&rbf16[(size_t)i2a*32 + kq];
        a1 = *(const short8*)&rbf16[(size_t)i2b*32 + kq];
      } else {
        #pragma unroll
        for (int j=0;j<8;j++){
          int kk = kq + j;            // angle-feature index, valid < 16
          float v0 = 0.f, v1 = 0.f;
          if (kk < 16){
            float c = (float)kk*STEP_A;
            float d0 = ang0 - c, d1 = ang1 - c;
            v0 = expf(-GAMMA_A*d0*d0); v1 = expf(-GAMMA_A*d1*d1);
          }
          a0[j] = (short)f2bf(v0); a1[j] = (short)f2bf(v1);
        }
      }
    } else {
      int k = k0 + kq;
      if (k0 < 128){
        a0 = *(const short8*)&s16[(size_t)i1a*128 + k];
        a1 = *(const short8*)&s16[(size_t)i1b*128 + k];
      } else if (k0 < 256){
        a0 = *(const short8*)&s16[(size_t)i2a*128 + (k-128)];
        a1 = *(const short8*)&s16[(size_t)i2b*128 + (k-128)];
      } else if (k0 < 288){
        a0 = *(const short8*)&rbf16[(size_t)r0*32 + (k-256)];
        a1 = *(const short8*)&rbf16[(size_t)r1*32 + (k-256)];
      } else {
        const float* p0 = &eagg_in[(size_t)r0*128 + (k-288)];
        const float* p1 = &eagg_in[(size_t)r1*128 + (k-288)];
        f32x4 x0 = *(const f32x4*)p0, x1 = *(const f32x4*)(p0+4);
        f32x4 y0 = *(const f32x4*)p1, y1 = *(const f32x4*)(p1+4);
        #pragma unroll
        for (int j=0;j<4;j++){
          a0[j] = (short)f2bf(x0[j]); a0[4+j] = (short)f2bf(x1[j]);
          a1[j] = (short)f2bf(y0[j]); a1[4+j] = (short)f2bf(y1[j]);
        }
      }
    }
    #pragma unroll
    for (int ct=0;ct<8;ct++){
      short8 b = *(const short8*)&W1t[(size_t)(ct*16 + n)*K1pad + k0 + kq];
      acc[0][ct] = __builtin_amdgcn_mfma_f32_16x16x32_bf16(a0, b, acc[0][ct], 0,0,0);
      acc[1][ct] = __builtin_amdgcn_mfma_f32_16x16x32_bf16(a1, b, acc[1][ct], 0,0,0);
    }
  }

  // bias + silu -> LDS (bf16). Wave-private rows: no barrier needed (lgkmcnt only).
  #pragma unroll
  for (int rh=0;rh<2;rh++){
    #pragma unroll
    for (int ct=0;ct<8;ct++){
      int col = ct*16 + n;
      float bv = b1[col];
      #pragma unroll
      for (int reg=0;reg<4;reg++){
        int rloc = lrow + rh*16 + quad*4 + reg;
        float h = acc[rh][ct][reg] + bv;
        hid[rloc*HSTRIDE + col] = f2bf(silu_f(h));
      }
    }
  }

  // ---------- phase B: out = hidden @ W2 + b2, scatter ----------
  for (int og=0; og<OUTgrp; og++){
    f32x4 acc2[2][8];
    #pragma unroll
    for (int rh=0;rh<2;rh++)
      #pragma unroll
      for (int ct=0;ct<8;ct++) acc2[rh][ct] = (f32x4){0.f,0.f,0.f,0.f};

    #pragma unroll
    for (int k0=0;k0<128;k0+=32){
      short8 a0 = *(const short8*)&hid[(size_t)(lrow + n)*HSTRIDE + k0 + kq];
      short8 a1 = *(const short8*)&hid[(size_t)(lrow + 16 + n)*HSTRIDE + k0 + kq];
      #pragma unroll
      for (int ct=0;ct<8;ct++){
        short8 b = *(const short8*)&W2t[(size_t)(og*128 + ct*16 + n)*128 + k0 + kq];
        acc2[0][ct] = __builtin_amdgcn_mfma_f32_16x16x32_bf16(a0, b, acc2[0][ct], 0,0,0);
        acc2[1][ct] = __builtin_amdgcn_mfma_f32_16x16x32_bf16(a1, b, acc2[1][ct], 0,0,0);
      }
    }

    if (SM == 1 || og == 0){
      #pragma unroll
      for (int rh=0;rh<2;rh++){
        #pragma unroll
        for (int reg=0;reg<4;reg++){
          int row = wrow + rh*16 + quad*4 + reg;
          int dnode = idx2[row];
          #pragma unroll
          for (int ct=0;ct<8;ct++){
            int col = ct*16 + n;
            float v = acc2[rh][ct][reg] + b2[og*128 + col];
            atomicAdd(&out0[(size_t)dnode*128 + col], v);
          }
        }
      }
    } else {
      #pragma unroll
      for (int rh=0;rh<2;rh++){
        #pragma unroll
        for (int reg=0;reg<4;reg++){
          int row = wrow + rh*16 + quad*4 + reg;
          int dnode = idx2[row];
          float dx = dir[row*3+0], dy = dir[row*3+1], dz = dir[row*3+2];
          #pragma unroll
          for (int ct=0;ct<8;ct++){
            int col = ct*16 + n;
            float m = acc2[rh][ct][reg] + b2[128 + col];
            size_t base = ((size_t)dnode*128 + col)*3;
            atomicAdd(&out1[base+0], m*dx);
            atomicAdd(&out1[base+1], m*dy);
            atomicAdd(&out1[base+2], m*dz);
          }
        }
      }
    }
  }
}

// ---------------- generic fp32 row-MLP GEMM (node-level) ----------------
// SM: 0 = direct A[r*K+k]
//     3 = ctx gather: k<128 -> g1(s), k<256 -> g2(aggs), else ||g3 row|| (v norm)
// MODE: 0 = store, 1 = silu+store, 2 = C += (acc+bias)
__launch_bounds__(128)
__global__ void k_gemm(int SM, int MODE,
                       const float* __restrict__ A,
                       const float* __restrict__ g1, const float* __restrict__ g2,
                       const float* __restrict__ g3,
                       const float* __restrict__ W, int WS, int woff,
                       const float* __restrict__ bias,
                       float* __restrict__ C, int OS, int coff,
                       int R, int K)
{
  __shared__ float ws[CW*128];
  __shared__ float as[RB][CW];
  const int tid = threadIdx.x;
  const int nchunk = (K + CW - 1) / CW;

  for (int rb = blockIdx.x*RB; rb < R; rb += gridDim.x*RB){
    float acc[RB];
    #pragma unroll
    for (int r=0;r<RB;r++) acc[r] = 0.f;

    for (int c=0;c<nchunk;c++){
      const int k0 = c*CW;
      for (int i=tid; i<CW*128; i+=128){
        int kk = i >> 7, col = i & 127;
        int k = k0 + kk;
        ws[i] = (k < K) ? W[k*WS + woff + col] : 0.f;
      }
      for (int i=tid; i<RB*CW; i+=128){
        int r  = i >> 6, kk = i & 63;
        int k  = k0 + kk;
        int row = rb + r;
        float v = 0.f;
        if (k < K){
          if (SM == 0){
            v = A[(long)row*K + k];
          } else {
            if (k < 128)      v = g1[row*128 + k];
            else if (k < 256) v = g2[row*128 + (k-128)];
            else {
              int h = k - 256;
              float v0 = g3[(row*128+h)*3+0];
              float v1 = g3[(row*128+h)*3+1];
              float v2 = g3[(row*128+h)*3+2];
              v = sqrtf(v0*v0 + v1*v1 + v2*v2 + 1e-12f);
            }
          }
        }
        as[r][kk] = v;
      }
      __syncthreads();
      #pragma unroll 4
      for (int kq2=0; kq2<CW/4; kq2++){
        float w0 = ws[(4*kq2+0)*128 + tid];
        float w1 = ws[(4*kq2+1)*128 + tid];
        float w2 = ws[(4*kq2+2)*128 + tid];
        float w3 = ws[(4*kq2+3)*128 + tid];
        #pragma unroll
        for (int r=0;r<RB;r++){
          const float4 av = *reinterpret_cast<const float4*>(&as[r][4*kq2]);
          acc[r] = fmaf(av.x, w0, acc[r]);
          acc[r] = fmaf(av.y, w1, acc[r]);
          acc[r] = fmaf(av.z, w2, acc[r]);
          acc[r] = fmaf(av.w, w3, acc[r]);
        }
      }
      __syncthreads();
    }

    const float bv = bias[woff + tid];
    #pragma unroll
    for (int r=0;r<RB;r++){
      int row = rb + r;
      float v = acc[r] + bv;
      if (MODE == 1) v = silu_f(v);
      float* cp = &C[(long)row*OS + coff + tid];
      if (MODE == 2) *cp += v; else *cp = v;
    }
  }
}

// ---------------- elementwise / reduction kernels ----------------

__global__ void k_sadd_batch(float* __restrict__ s, const float* __restrict__ t2,
                             const int* __restrict__ batch, ushort_t* __restrict__ s16){
  int i = blockIdx.x*256 + threadIdx.x;
  if (i >= N_*H_) return;
  int n = i >> 7, h = i & 127;
  float v = s[i] + t2[batch[n]*128 + h];
  s[i] = v;
  s16[i] = f2bf(v);
}

__global__ void k_gate_v(const float* __restrict__ dg, const float* __restrict__ aggv,
                         float* __restrict__ v){
  int i = blockIdx.x*256 + threadIdx.x;
  if (i >= N_*H_) return;
  float g = sigmoid_f(dg[i]);
  v[i*3+0] += g*aggv[i*3+0];
  v[i*3+1] += g*aggv[i*3+1];
  v[i*3+2] += g*aggv[i*3+2];
}

__global__ void k_ln_silu(float* __restrict__ s, const float* __restrict__ g,
                          const float* __restrict__ b){
  __shared__ float red[128];
  int n = blockIdx.x, tid = threadIdx.x;
  float x = s[n*128 + tid];
  red[tid] = x; __syncthreads();
  for (int o=64;o>0;o>>=1){ if (tid<o) red[tid]+=red[tid+o]; __syncthreads(); }
  float mu = red[0] * (1.f/128.f);
  __syncthreads();
  float dx = x - mu;
  red[tid] = dx*dx; __syncthreads();
  for (int o=64;o>0;o>>=1){ if (tid<o) red[tid]+=red[tid+o]; __syncthreads(); }
  float var = red[0] * (1.f/128.f);
  float y = dx * rsqrtf(var + 1e-5f) * g[tid] + b[tid];
  s[n*128 + tid] = silu_f(y);
}

__global__ void k_segsum(const float* __restrict__ s, const int* __restrict__ batch,
                         float* __restrict__ ssum){
  int i = blockIdx.x*256 + threadIdx.x;
  if (i >= N_*H_) return;
  int n = i >> 7, h = i & 127;
  atomicAdd(&ssum[batch[n]*128 + h], s[i]);
}

__global__ void k_scatter_nf(const float* __restrict__ s, const float* __restrict__ v,
                             const int* __restrict__ batch, float* __restrict__ addp){
  int i = blockIdx.x*256 + threadIdx.x;
  if (i >= N_*256) return;
  int n = i >> 8, j = i & 255;
  float val;
  if (j < 128){
    val = s[n*128 + j];
  } else {
    int h = j - 128;
    float v0 = v[(n*128+h)*3+0], v1 = v[(n*128+h)*3+1], v2 = v[(n*128+h)*3+2];
    val = sqrtf(v0*v0 + v1*v1 + v2*v2 + 1e-12f);
  }
  atomicAdd(&addp[batch[n]*256 + j], val);
}

__global__ void k_counts(const int* __restrict__ batch, float* __restrict__ counts){
  int n = blockIdx.x*256 + threadIdx.x;
  if (n < N_) atomicAdd(&counts[batch[n]], 1.f);
}

__global__ void k_build_g(const float* __restrict__ addp, const float* __restrict__ counts,
                          const float* __restrict__ vn, float* __restrict__ gbuf){
  int i = blockIdx.x*256 + threadIdx.x;
  if (i >= G_*640) return;
  int g = i / 640, j = i % 640;
  float val;
  if (j < 256)       val = addp[g*256 + j];
  else if (j < 512)  val = addp[g*256 + (j-256)] / fmaxf(counts[g], 1.f);
  else               val = vn[g*128 + (j-512)];
  gbuf[i] = val;
}

__global__ void k_head_final(const float* __restrict__ hh, const float* __restrict__ w2,
                             const float* __restrict__ b2, float* __restrict__ out){
  __shared__ float red[128];
  int g = blockIdx.x, tid = threadIdx.x;
  red[tid] = hh[g*128 + tid] * w2[tid];
  __syncthreads();
  for (int o=64;o>0;o>>=1){ if (tid<o) red[tid]+=red[tid+o]; __syncthreads(); }
  if (tid == 0) out[g] = red[0] + b2[0];
}

// ---------------- host launcher ----------------

extern "C" void kernel_launch(void* const* d_in, const int* in_sizes, int n_in,
                              void* d_out, int out_size, void* d_ws, size_t ws_size,
                              hipStream_t stream)
{
  const float* x         = (const float*)d_in[0];
  const float* pos       = (const float*)d_in[1];
  const float* edist     = (const float*)d_in[2];
  const float* node_in_w = (const float*)d_in[3];
  const float* node_in_b = (const float*)d_in[4];
  const float* tm_w1 = (const float*)d_in[5];
  const float* tm_b1 = (const float*)d_in[6];
  const float* tm_w2 = (const float*)d_in[7];
  const float* tm_b2 = (const float*)d_in[8];
  const float* mm_w1 = (const float*)d_in[9];
  const float* mm_b1 = (const float*)d_in[10];
  const float* mm_w2 = (const float*)d_in[11];
  const float* mm_b2 = (const float*)d_in[12];
  const float* us_w1 = (const float*)d_in[13];
  const float* us_b1 = (const float*)d_in[14];
  const float* us_w2 = (const float*)d_in[15];
  const float* us_b2 = (const float*)d_in[16];
  const float* gv_w1 = (const float*)d_in[17];
  const float* gv_b1 = (const float*)d_in[18];
  const float* gv_w2 = (const float*)d_in[19];
  const float* gv_b2 = (const float*)d_in[20];
  const float* ln_g  = (const float*)d_in[21];
  const float* ln_b  = (const float*)d_in[22];
  const float* vn_init = (const float*)d_in[23];
  const float* v2n_w1 = (const float*)d_in[24];
  const float* v2n_b1 = (const float*)d_in[25];
  const float* v2n_w2 = (const float*)d_in[26];
  const float* v2n_b2 = (const float*)d_in[27];
  const float* n2v_w1 = (const float*)d_in[28];
  const float* n2v_b1 = (const float*)d_in[29];
  const float* n2v_w2 = (const float*)d_in[30];
  const float* n2v_b2 = (const float*)d_in[31];
  const float* head_w1 = (const float*)d_in[32];
  const float* head_b1 = (const float*)d_in[33];
  const float* head_w2 = (const float*)d_in[34];
  const float* head_b2 = (const float*)d_in[35];
  const int* ei    = (const int*)d_in[36];
  const int* t_kj  = (const int*)d_in[37];
  const int* t_ji  = (const int*)d_in[38];
  const int* batch = (const int*)d_in[39];
  float* out = (float*)d_out;

  // ---- workspace layout (~118.7 MiB), 16B-aligned chunks ----
  float* f = (float*)d_ws;
  size_t off = 0;
  auto alloc = [&](size_t n){ n = (n + 3) & ~(size_t)3; float* p = f + off; off += n; return p; };
  float*    vec    = alloc((size_t)E_*3);
  float*    dir    = alloc((size_t)E_*3);
  ushort_t* rbf16  = (ushort_t*)alloc((size_t)E_*16);      // E*32 bf16
  float*    angle  = alloc((size_t)T_);
  float*    eagg   = alloc((size_t)E_*128);                // fp32 atomic target
  float*    s      = alloc((size_t)N_*128);
  ushort_t* s16    = (ushort_t*)alloc((size_t)N_*64);      // N*128 bf16
  float*    v      = alloc((size_t)N_*384);
  float*    aggs   = alloc((size_t)N_*128);
  float*    aggv   = alloc((size_t)N_*384);
  float*    hu     = alloc((size_t)N_*128);
  float*    hg     = alloc((size_t)N_*128);
  // bf16 transposed weights, per layer: tm1[128][96] tm2[128][128] mm1[128][416] mm2[256][128]
  ushort_t* wtbuf  = (ushort_t*)alloc((size_t)229376/2);
  float*    vn     = alloc((size_t)G_*128);
  float*    tg1    = alloc((size_t)G_*128);
  float*    tg2    = alloc((size_t)G_*128);
  float*    ssum   = alloc((size_t)G_*128);
  float*    addp   = alloc((size_t)G_*256);
  float*    counts = alloc((size_t)G_);
  float*    gbuf   = alloc((size_t)G_*640);
  float*    hh     = alloc((size_t)G_*128);

  if (off * sizeof(float) > ws_size){
    k_sentinel<<<1, 64, 0, stream>>>(out, G_);
    return;
  }

  ushort_t* wt_tm1[2], *wt_tm2[2], *wt_mm1[2], *wt_mm2[2];
  {
    ushort_t* p = wtbuf;
    for (int l=0;l<2;l++){
      wt_tm1[l] = p; p += 128*96;
      wt_tm2[l] = p; p += 128*128;
      wt_mm1[l] = p; p += 128*416;
      wt_mm2[l] = p; p += 256*128;
    }
  }

  auto zero = [&](float* p, long n){
    int blocks = (int)((n + 255)/256); if (blocks > 16384) blocks = 16384;
    k_zero<<<blocks, 256, 0, stream>>>(p, n);
  };
  auto gemm = [&](int SM, int MODE, const float* A,
                  const float* g1, const float* g2, const float* g3,
                  const float* W, int WS, int woff, const float* bias,
                  float* C, int OS, int coff, int R, int K){
    int nblk = (R + RB - 1)/RB; if (nblk > 4096) nblk = 4096;
    k_gemm<<<nblk, 128, 0, stream>>>(SM, MODE, A, g1, g2, g3,
                                     W, WS, woff, bias, C, OS, coff, R, K);
  };
  auto wt = [&](const float* W, ushort_t* Wt, int K, int C, int Kpad){
    int n = C*Kpad;
    k_wt<<<(n + 255)/256, 256, 0, stream>>>(W, Wt, K, C, Kpad);
  };

  // ---- prologue ----
  zero(v, (long)N_*384);
  k_init_vn<<<(G_*H_ + 255)/256, 256, 0, stream>>>(vn, vn_init);
  k_geom<<<(E_ + 255)/256, 256, 0, stream>>>(pos, edist, ei, vec, dir, rbf16);
  k_angle<<<(T_ + 255)/256, 256, 0, stream>>>(vec, t_kj, t_ji, angle);
  for (int l=0;l<2;l++){
    wt(tm_w1 + l*80*128,  wt_tm1[l],  80, 128,  96);
    wt(tm_w2 + l*128*128, wt_tm2[l], 128, 128, 128);
    wt(mm_w1 + l*416*128, wt_mm1[l], 416, 128, 416);
    wt(mm_w2 + l*128*256, wt_mm2[l], 128, 256, 128);
  }
  // s = x @ node_in_w + b
  gemm(0,0, x, nullptr,nullptr,nullptr,
       node_in_w,128,0, node_in_b, s,128,0, N_, IND_);

  for (int l=0; l<L_; l++){
    // 1) s += v2n_mlp(vn)[batch]  (also snapshots s16 = bf16(s))
    gemm(0,1, vn, nullptr,nullptr,nullptr, v2n_w1,128,0, v2n_b1, tg1,128,0, G_,128);
    gemm(0,0, tg1,nullptr,nullptr,nullptr, v2n_w2,128,0, v2n_b2, tg2,128,0, G_,128);
    k_sadd_batch<<<(N_*H_ + 255)/256, 256, 0, stream>>>(s, tg2, batch, s16);

    // 2) triplet MLP (MFMA) -> eagg
    zero(eagg, (long)E_*128);
    k_mlp2_mfma<<<T_/BROWS, 256, 0, stream>>>(1, t_kj, t_ji, rbf16, angle, s16, eagg,
        wt_tm1[l], tm_b1 + l*128, 96,
        wt_tm2[l], tm_b2 + l*128, 1, dir, eagg, nullptr);

    // 3) edge MLP (MFMA) -> aggs, aggv
    zero(aggs, (long)N_*128);
    zero(aggv, (long)N_*384);
    k_mlp2_mfma<<<E_/BROWS, 256, 0, stream>>>(2, ei, ei + E_, rbf16, angle, s16, eagg,
        wt_mm1[l], mm_b1 + l*128, 416,
        wt_mm2[l], mm_b2 + l*256, 2, dir, aggs, aggv);

    // 4+5) hu = silu(ctx@us_w1+b) ; hg = silu(ctx@gv_w1+b)   [ctx gathered, pre-update s]
    gemm(3,1, nullptr, s, aggs, v, us_w1 + l*384*128,128,0, us_b1 + l*128, hu,128,0, N_,384);
    gemm(3,1, nullptr, s, aggs, v, gv_w1 + l*384*128,128,0, gv_b1 + l*128, hg,128,0, N_,384);
    gemm(0,2, hu, nullptr,nullptr,nullptr, us_w2 + l*128*128,128,0, us_b2 + l*128, s,128,0, N_,128);
    gemm(0,0, hg, nullptr,nullptr,nullptr, gv_w2 + l*128*128,128,0, gv_b2 + l*128, hu,128,0, N_,128);
    k_gate_v<<<(N_*H_ + 255)/256, 256, 0, stream>>>(hu, aggv, v);

    // 7) s = silu(LN(s))
    k_ln_silu<<<N_, 128, 0, stream>>>(s, ln_g + l*128, ln_b + l*128);

    // 8) vn += n2v_mlp(segment_sum(s, batch))
    zero(ssum, (long)G_*128);
    k_segsum<<<(N_*H_ + 255)/256, 256, 0, stream>>>(s, batch, ssum);
    gemm(0,1, ssum,nullptr,nullptr,nullptr, n2v_w1,128,0, n2v_b1, tg1,128,0, G_,128);
    gemm(0,2, tg1, nullptr,nullptr,nullptr, n2v_w2,128,0, n2v_b2, vn,128,0, G_,128);
  }

  // ---- readout ----
  zero(addp, (long)(G_*256 + G_));   // addp and counts contiguous
  k_scatter_nf<<<(N_*256 + 255)/256, 256, 0, stream>>>(s, v, batch, addp);
  k_counts<<<(N_ + 255)/256, 256, 0, stream>>>(batch, counts);
  k_build_g<<<(G_*640 + 255)/256, 256, 0, stream>>>(addp, counts, vn, gbuf);
  gemm(0,1, gbuf,nullptr,nullptr,nullptr, head_w1,128,0, head_b1, hh,128,0, G_,640);
  k_head_final<<<G_, 128, 0, stream>>>(hh, head_w2, head_b2, out);
}

// Round 4
// 2510.974 us; speedup vs baseline: 3.5007x; 1.5001x over previous
//
#include <hip/hip_runtime.h>
#include <math.h>

// ---- problem constants (from reference) ----
#define N_   8192
#define E_   131072
#define T_   262144
#define H_   128
#define IND_ 64
#define G_   32
#define L_   2

// generic fp32 GEMM tiling (node-level MLPs)
#define CW 64
#define RB 16

// MFMA fused MLP tiling
#define MROWS 32     // rows per wave
#define BROWS 128    // rows per block (4 waves)
#define HSTRIDE 136  // LDS hidden row stride (bf16 elems)

// RBF constants
#define STEP_E  ((float)(5.0/31.0))
#define GAMMA_E ((float)(1.0/(2.0*((5.0/31.0)*(5.0/31.0) + 1e-12))))
#define PI_D    3.14159265358979323846
#define STEP_A  ((float)(PI_D/15.0))
#define GAMMA_A ((float)(1.0/(2.0*((PI_D/15.0)*(PI_D/15.0) + 1e-12))))

typedef __attribute__((ext_vector_type(8))) short short8;
typedef __attribute__((ext_vector_type(4))) float f32x4;
typedef unsigned short ushort_t;

static __device__ __forceinline__ float silu_f(float x){ return x / (1.f + expf(-x)); }
static __device__ __forceinline__ float sigmoid_f(float x){ return 1.f / (1.f + expf(-x)); }

static __device__ __forceinline__ ushort_t f2bf(float x){
  unsigned int u = __builtin_bit_cast(unsigned int, x);
  u += 0x7FFFu + ((u >> 16) & 1u);
  return (ushort_t)(u >> 16);
}

// ---------------- small utility kernels ----------------

__global__ void k_zero(float* __restrict__ p, long n){
  long i = (long)blockIdx.x*256 + threadIdx.x;
  long stride = (long)gridDim.x*256;
  for (; i < n; i += stride) p[i] = 0.f;
}

__global__ void k_sentinel(float* __restrict__ p, int n){
  int i = blockIdx.x*256 + threadIdx.x;
  if (i < n) p[i] = 1.0e30f;
}

__global__ void k_init_vn(float* __restrict__ vn, const float* __restrict__ vn_init){
  int i = blockIdx.x*256 + threadIdx.x;
  if (i < G_*H_) vn[i] = vn_init[i & 127];
}

// weight convert+transpose: W fp32 [K][C] -> Wt bf16 [C][Kpad] (zero-padded)
__global__ void k_wt(const float* __restrict__ W, ushort_t* __restrict__ Wt,
                     int K, int C, int Kpad){
  int i = blockIdx.x*256 + threadIdx.x;
  if (i >= C*Kpad) return;
  int c = i / Kpad, k = i % Kpad;
  Wt[i] = (k < K) ? f2bf(W[(size_t)k*C + c]) : (ushort_t)0;
}

// per-edge: vec, dir, edge RBF(32) in bf16
__global__ void k_geom(const float* __restrict__ pos, const float* __restrict__ dist,
                       const int* __restrict__ ei,
                       float* __restrict__ vec, float* __restrict__ dir,
                       ushort_t* __restrict__ rbf16){
  int e = blockIdx.x*256 + threadIdx.x;
  if (e >= E_) return;
  int s = ei[e], d = ei[E_ + e];
  float vx = pos[d*3+0] - pos[s*3+0];
  float vy = pos[d*3+1] - pos[s*3+1];
  float vz = pos[d*3+2] - pos[s*3+2];
  vec[e*3+0]=vx; vec[e*3+1]=vy; vec[e*3+2]=vz;
  float dd = dist[e];
  float inv = 1.f / (dd + 1e-9f);
  dir[e*3+0]=vx*inv; dir[e*3+1]=vy*inv; dir[e*3+2]=vz*inv;
  #pragma unroll
  for (int i=0;i<32;i++){
    float df = dd - i*STEP_E;
    rbf16[e*32+i] = f2bf(expf(-GAMMA_E*df*df));
  }
}

// per-triplet angle
__global__ void k_angle(const float* __restrict__ vec,
                        const int* __restrict__ kj, const int* __restrict__ ji,
                        float* __restrict__ angle){
  int t = blockIdx.x*256 + threadIdx.x;
  if (t >= T_) return;
  int ea = ji[t], eb = kj[t];
  float ax=vec[ea*3+0], ay=vec[ea*3+1], az=vec[ea*3+2];
  float bx=vec[eb*3+0], by=vec[eb*3+1], bz=vec[eb*3+2];
  float dot = ax*bx + ay*by + az*bz;
  float na = sqrtf(ax*ax+ay*ay+az*az + 1e-12f);
  float nb = sqrtf(bx*bx+by*by+bz*bz + 1e-12f);
  float c = dot / (na*nb + 1e-9f);
  c = fminf(fmaxf(c, -1.f + 1e-7f), 1.f - 1e-7f);
  angle[t] = acosf(c);
}

// ---------------- counting-sort kernels ----------------

__global__ void k_hist(const int* __restrict__ keys, int M, int* __restrict__ hist){
  int i = blockIdx.x*256 + threadIdx.x;
  if (i < M) atomicAdd(&hist[keys[i]], 1);
}

// per-1024-chunk exclusive scan (in-place safe), chunk totals to sums
__global__ void k_scan1(const int* __restrict__ in, int* __restrict__ out,
                        int* __restrict__ sums, int B){
  __shared__ int sh[1024];
  int base = blockIdx.x*1024, t = threadIdx.x;
  for (int j=t;j<1024;j+=256) sh[j] = (base+j<B) ? in[base+j] : 0;
  __syncthreads();
  for (int o=1;o<1024;o<<=1){
    int v[4];
    #pragma unroll
    for (int q=0;q<4;q++){ int idx=t+q*256; v[q]=(idx>=o)? sh[idx-o]:0; }
    __syncthreads();
    #pragma unroll
    for (int q=0;q<4;q++){ int idx=t+q*256; sh[idx]+=v[q]; }
    __syncthreads();
  }
  for (int j=t;j<1024;j+=256) if (base+j<B) out[base+j] = (j==0)?0:sh[j-1];
  if (t==0) sums[blockIdx.x] = sh[1023];
}

__global__ void k_scan2(int* __restrict__ sums, int nb){
  if (threadIdx.x==0 && blockIdx.x==0){
    int a=0;
    for (int i=0;i<nb;i++){ int x=sums[i]; sums[i]=a; a+=x; }
  }
}

__global__ void k_scan3(int* __restrict__ out, const int* __restrict__ sums, int B){
  int i = blockIdx.x*256+threadIdx.x;
  if (i<B) out[i] += sums[i>>10];
}

__global__ void k_fill(const int* __restrict__ keys, int M, int* __restrict__ cur,
                       int* __restrict__ perm){
  int i = blockIdx.x*256+threadIdx.x;
  if (i<M){ int p = atomicAdd(&cur[keys[i]],1); perm[p]=i; }
}

// ---------------- MFMA fused 2-layer MLP + sorted segment-scatter ----------------
// Rows processed in perm order (sorted by scatter key = idx2[perm[row]]).
// SM==1 (triplet, K1pad=96):  in = [rbf16[kj] | rbf16[ji] | angRBF], OUTgrp=1
//     out0[ji*128+col] += msg   (eagg, fp32, segment-flushed atomics)
// SM==2 (edge, K1pad=416):    in = [s16[src] | s16[dst] | rbf16[e] | bf16(eagg[e])]
//     og0: out0[dst*128+col] += m_s      (aggs)
//     og1: out1[(dst*128+col)*3+xyz] += m_v*dir[e]   (aggv)
__launch_bounds__(256, 3)
__global__ void k_mlp2_mfma(int SM,
    const int* __restrict__ perm,
    const int* __restrict__ idx1, const int* __restrict__ idx2,
    const ushort_t* __restrict__ rbf16, const float* __restrict__ angle,
    const ushort_t* __restrict__ s16, const float* __restrict__ eagg_in,
    const ushort_t* __restrict__ W1t, const float* __restrict__ b1, int K1pad,
    const ushort_t* __restrict__ W2t, const float* __restrict__ b2, int OUTgrp,
    const float* __restrict__ dir,
    float* __restrict__ out0, float* __restrict__ out1)
{
  __shared__ ushort_t hid[BROWS*HSTRIDE];   // 34816 B
  __shared__ float mchunk[BROWS][33];       // 16896 B
  __shared__ int   segk[BROWS];             // 512 B
  __shared__ float dirs[BROWS][3];          // 1536 B
  const int tid  = threadIdx.x;
  const int wave = tid >> 6;
  const int lane = tid & 63;
  const int n    = lane & 15;
  const int quad = lane >> 4;
  const int kq   = quad*8;
  const int wrow = blockIdx.x*BROWS + wave*MROWS;
  const int lrow = wave*MROWS;

  // block-wide: sorted keys + dir rows for the epilogue
  for (int i=tid; i<BROWS; i+=256){
    int e = perm[blockIdx.x*BROWS + i];
    segk[i] = idx2[e];
    if (SM == 2){
      dirs[i][0]=dir[e*3+0]; dirs[i][1]=dir[e*3+1]; dirs[i][2]=dir[e*3+2];
    }
  }

  const int e0 = perm[wrow + n];        // A-frag row (half 0), original id
  const int e1 = perm[wrow + 16 + n];   // A-frag row (half 1)

  int i1a = idx1[e0], i1b = idx1[e1];
  int i2a = idx2[e0], i2b = idx2[e1];
  float ang0 = 0.f, ang1 = 0.f;
  if (SM == 1){ ang0 = angle[e0]; ang1 = angle[e1]; }

  // ---------- phase A: hidden = silu(in @ W1 + b1) ----------
  f32x4 acc[2][8];
  #pragma unroll
  for (int rh=0;rh<2;rh++)
    #pragma unroll
    for (int ct=0;ct<8;ct++) acc[rh][ct] = (f32x4){0.f,0.f,0.f,0.f};

  for (int k0 = 0; k0 < K1pad; k0 += 32){
    short8 a0, a1;
    if (SM == 1){
      if (k0 == 0){
        a0 = *(const short8*)&rbf16[(size_t)i1a*32 + kq];
        a1 = *(const short8*)&rbf16[(size_t)i1b*32 + kq];
      } else if (k0 == 32){
        a0 = *(const short8*)&rbf16[(size_t)i2a*32 + kq];
        a1 = *(const short8*)&rbf16[(size_t)i2b*32 + kq];
      } else {
        #pragma unroll
        for (int j=0;j<8;j++){
          int kk = kq + j;
          float v0 = 0.f, v1 = 0.f;
          if (kk < 16){
            float c = (float)kk*STEP_A;
            float d0 = ang0 - c, d1 = ang1 - c;
            v0 = expf(-GAMMA_A*d0*d0); v1 = expf(-GAMMA_A*d1*d1);
          }
          a0[j] = (short)f2bf(v0); a1[j] = (short)f2bf(v1);
        }
      }
    } else {
      int k = k0 + kq;
      if (k0 < 128){
        a0 = *(const short8*)&s16[(size_t)i1a*128 + k];
        a1 = *(const short8*)&s16[(size_t)i1b*128 + k];
      } else if (k0 < 256){
        a0 = *(const short8*)&s16[(size_t)i2a*128 + (k-128)];
        a1 = *(const short8*)&s16[(size_t)i2b*128 + (k-128)];
      } else if (k0 < 288){
        a0 = *(const short8*)&rbf16[(size_t)e0*32 + (k-256)];
        a1 = *(const short8*)&rbf16[(size_t)e1*32 + (k-256)];
      } else {
        const float* p0 = &eagg_in[(size_t)e0*128 + (k-288)];
        const float* p1 = &eagg_in[(size_t)e1*128 + (k-288)];
        f32x4 x0 = *(const f32x4*)p0, x1 = *(const f32x4*)(p0+4);
        f32x4 y0 = *(const f32x4*)p1, y1 = *(const f32x4*)(p1+4);
        #pragma unroll
        for (int j=0;j<4;j++){
          a0[j] = (short)f2bf(x0[j]); a0[4+j] = (short)f2bf(x1[j]);
          a1[j] = (short)f2bf(y0[j]); a1[4+j] = (short)f2bf(y1[j]);
        }
      }
    }
    #pragma unroll
    for (int ct=0;ct<8;ct++){
      short8 b = *(const short8*)&W1t[(size_t)(ct*16 + n)*K1pad + k0 + kq];
      acc[0][ct] = __builtin_amdgcn_mfma_f32_16x16x32_bf16(a0, b, acc[0][ct], 0,0,0);
      acc[1][ct] = __builtin_amdgcn_mfma_f32_16x16x32_bf16(a1, b, acc[1][ct], 0,0,0);
    }
  }

  // bias + silu -> LDS (bf16). Rows are wave-private.
  #pragma unroll
  for (int rh=0;rh<2;rh++){
    #pragma unroll
    for (int ct=0;ct<8;ct++){
      int col = ct*16 + n;
      float bv = b1[col];
      #pragma unroll
      for (int reg=0;reg<4;reg++){
        int rloc = lrow + rh*16 + quad*4 + reg;
        float h = acc[rh][ct][reg] + bv;
        hid[rloc*HSTRIDE + col] = f2bf(silu_f(h));
      }
    }
  }

  // ---------- phase B: out = hidden @ W2 + b2, sorted segment-scatter ----------
  for (int og=0; og<OUTgrp; og++){
    f32x4 acc2[2][8];
    #pragma unroll
    for (int rh=0;rh<2;rh++)
      #pragma unroll
      for (int ct=0;ct<8;ct++) acc2[rh][ct] = (f32x4){0.f,0.f,0.f,0.f};

    #pragma unroll
    for (int k0=0;k0<128;k0+=32){
      short8 a0 = *(const short8*)&hid[(size_t)(lrow + n)*HSTRIDE + k0 + kq];
      short8 a1 = *(const short8*)&hid[(size_t)(lrow + 16 + n)*HSTRIDE + k0 + kq];
      #pragma unroll
      for (int ct=0;ct<8;ct++){
        short8 b = *(const short8*)&W2t[(size_t)(og*128 + ct*16 + n)*128 + k0 + kq];
        acc2[0][ct] = __builtin_amdgcn_mfma_f32_16x16x32_bf16(a0, b, acc2[0][ct], 0,0,0);
        acc2[1][ct] = __builtin_amdgcn_mfma_f32_16x16x32_bf16(a1, b, acc2[1][ct], 0,0,0);
      }
    }

    // epilogue: 4 column-chunks of 32; LDS transpose + per-column segment walk
    for (int ch=0; ch<4; ch++){
      const int c0 = ch*32;
      __syncthreads();   // previous chunk's walk done
      #pragma unroll
      for (int rh=0;rh<2;rh++){
        #pragma unroll
        for (int cti=0;cti<2;cti++){
          int ct = ch*2 + cti;
          int col = ct*16 + n;
          float bv = b2[og*128 + col];
          #pragma unroll
          for (int reg=0;reg<4;reg++){
            int r = lrow + rh*16 + quad*4 + reg;
            mchunk[r][col - c0] = acc2[rh][ct][reg] + bv;
          }
        }
      }
      __syncthreads();
      const int col = c0 + (tid & 31);
      const int w0r = (tid >> 5) * 16;     // 8 windows x 16 rows
      if (SM == 1 || og == 0){
        float a = 0.f; int prev = segk[w0r];
        for (int j=0;j<16;j++){
          int r = w0r + j;
          int k = segk[r];
          if (k != prev){ atomicAdd(&out0[(size_t)prev*128 + col], a); a = 0.f; prev = k; }
          a += mchunk[r][col - c0];
        }
        atomicAdd(&out0[(size_t)prev*128 + col], a);
      } else {
        float ax=0.f, ay=0.f, az=0.f; int prev = segk[w0r];
        for (int j=0;j<16;j++){
          int r = w0r + j;
          int k = segk[r];
          if (k != prev){
            size_t b = ((size_t)prev*128 + col)*3;
            atomicAdd(&out1[b+0], ax); atomicAdd(&out1[b+1], ay); atomicAdd(&out1[b+2], az);
            ax=ay=az=0.f; prev = k;
          }
          float m = mchunk[r][col - c0];
          ax += m*dirs[r][0]; ay += m*dirs[r][1]; az += m*dirs[r][2];
        }
        size_t b = ((size_t)prev*128 + col)*3;
        atomicAdd(&out1[b+0], ax); atomicAdd(&out1[b+1], ay); atomicAdd(&out1[b+2], az);
      }
    }
  }
}

// ---------------- generic fp32 row-MLP GEMM (node-level) ----------------
__launch_bounds__(128)
__global__ void k_gemm(int SM, int MODE,
                       const float* __restrict__ A,
                       const float* __restrict__ g1, const float* __restrict__ g2,
                       const float* __restrict__ g3,
                       const float* __restrict__ W, int WS, int woff,
                       const float* __restrict__ bias,
                       float* __restrict__ C, int OS, int coff,
                       int R, int K)
{
  __shared__ float ws[CW*128];
  __shared__ float as[RB][CW];
  const int tid = threadIdx.x;
  const int nchunk = (K + CW - 1) / CW;

  for (int rb = blockIdx.x*RB; rb < R; rb += gridDim.x*RB){
    float acc[RB];
    #pragma unroll
    for (int r=0;r<RB;r++) acc[r] = 0.f;

    for (int c=0;c<nchunk;c++){
      const int k0 = c*CW;
      for (int i=tid; i<CW*128; i+=128){
        int kk = i >> 7, col = i & 127;
        int k = k0 + kk;
        ws[i] = (k < K) ? W[k*WS + woff + col] : 0.f;
      }
      for (int i=tid; i<RB*CW; i+=128){
        int r  = i >> 6, kk = i & 63;
        int k  = k0 + kk;
        int row = rb + r;
        float v = 0.f;
        if (k < K){
          if (SM == 0){
            v = A[(long)row*K + k];
          } else {
            if (k < 128)      v = g1[row*128 + k];
            else if (k < 256) v = g2[row*128 + (k-128)];
            else {
              int h = k - 256;
              float v0 = g3[(row*128+h)*3+0];
              float v1 = g3[(row*128+h)*3+1];
              float v2 = g3[(row*128+h)*3+2];
              v = sqrtf(v0*v0 + v1*v1 + v2*v2 + 1e-12f);
            }
          }
        }
        as[r][kk] = v;
      }
      __syncthreads();
      #pragma unroll 4
      for (int kq2=0; kq2<CW/4; kq2++){
        float w0 = ws[(4*kq2+0)*128 + tid];
        float w1 = ws[(4*kq2+1)*128 + tid];
        float w2 = ws[(4*kq2+2)*128 + tid];
        float w3 = ws[(4*kq2+3)*128 + tid];
        #pragma unroll
        for (int r=0;r<RB;r++){
          const float4 av = *reinterpret_cast<const float4*>(&as[r][4*kq2]);
          acc[r] = fmaf(av.x, w0, acc[r]);
          acc[r] = fmaf(av.y, w1, acc[r]);
          acc[r] = fmaf(av.z, w2, acc[r]);
          acc[r] = fmaf(av.w, w3, acc[r]);
        }
      }
      __syncthreads();
    }

    const float bv = bias[woff + tid];
    #pragma unroll
    for (int r=0;r<RB;r++){
      int row = rb + r;
      float v = acc[r] + bv;
      if (MODE == 1) v = silu_f(v);
      float* cp = &C[(long)row*OS + coff + tid];
      if (MODE == 2) *cp += v; else *cp = v;
    }
  }
}

// ---------------- elementwise / reduction kernels ----------------

__global__ void k_sadd_batch(float* __restrict__ s, const float* __restrict__ t2,
                             const int* __restrict__ batch, ushort_t* __restrict__ s16){
  int i = blockIdx.x*256 + threadIdx.x;
  if (i >= N_*H_) return;
  int n = i >> 7, h = i & 127;
  float v = s[i] + t2[batch[n]*128 + h];
  s[i] = v;
  s16[i] = f2bf(v);
}

__global__ void k_gate_v(const float* __restrict__ dg, const float* __restrict__ aggv,
                         float* __restrict__ v){
  int i = blockIdx.x*256 + threadIdx.x;
  if (i >= N_*H_) return;
  float g = sigmoid_f(dg[i]);
  v[i*3+0] += g*aggv[i*3+0];
  v[i*3+1] += g*aggv[i*3+1];
  v[i*3+2] += g*aggv[i*3+2];
}

__global__ void k_ln_silu(float* __restrict__ s, const float* __restrict__ g,
                          const float* __restrict__ b){
  __shared__ float red[128];
  int n = blockIdx.x, tid = threadIdx.x;
  float x = s[n*128 + tid];
  red[tid] = x; __syncthreads();
  for (int o=64;o>0;o>>=1){ if (tid<o) red[tid]+=red[tid+o]; __syncthreads(); }
  float mu = red[0] * (1.f/128.f);
  __syncthreads();
  float dx = x - mu;
  red[tid] = dx*dx; __syncthreads();
  for (int o=64;o>0;o>>=1){ if (tid<o) red[tid]+=red[tid+o]; __syncthreads(); }
  float var = red[0] * (1.f/128.f);
  float y = dx * rsqrtf(var + 1e-5f) * g[tid] + b[tid];
  s[n*128 + tid] = silu_f(y);
}

__global__ void k_segsum(const float* __restrict__ s, const int* __restrict__ batch,
                         float* __restrict__ ssum){
  int i = blockIdx.x*256 + threadIdx.x;
  if (i >= N_*H_) return;
  int n = i >> 7, h = i & 127;
  atomicAdd(&ssum[batch[n]*128 + h], s[i]);
}

__global__ void k_scatter_nf(const float* __restrict__ s, const float* __restrict__ v,
                             const int* __restrict__ batch, float* __restrict__ addp){
  int i = blockIdx.x*256 + threadIdx.x;
  if (i >= N_*256) return;
  int n = i >> 8, j = i & 255;
  float val;
  if (j < 128){
    val = s[n*128 + j];
  } else {
    int h = j - 128;
    float v0 = v[(n*128+h)*3+0], v1 = v[(n*128+h)*3+1], v2 = v[(n*128+h)*3+2];
    val = sqrtf(v0*v0 + v1*v1 + v2*v2 + 1e-12f);
  }
  atomicAdd(&addp[batch[n]*256 + j], val);
}

__global__ void k_counts(const int* __restrict__ batch, float* __restrict__ counts){
  int n = blockIdx.x*256 + threadIdx.x;
  if (n < N_) atomicAdd(&counts[batch[n]], 1.f);
}

__global__ void k_build_g(const float* __restrict__ addp, const float* __restrict__ counts,
                          const float* __restrict__ vn, float* __restrict__ gbuf){
  int i = blockIdx.x*256 + threadIdx.x;
  if (i >= G_*640) return;
  int g = i / 640, j = i % 640;
  float val;
  if (j < 256)       val = addp[g*256 + j];
  else if (j < 512)  val = addp[g*256 + (j-256)] / fmaxf(counts[g], 1.f);
  else               val = vn[g*128 + (j-512)];
  gbuf[i] = val;
}

__global__ void k_head_final(const float* __restrict__ hh, const float* __restrict__ w2,
                             const float* __restrict__ b2, float* __restrict__ out){
  __shared__ float red[128];
  int g = blockIdx.x, tid = threadIdx.x;
  red[tid] = hh[g*128 + tid] * w2[tid];
  __syncthreads();
  for (int o=64;o>0;o>>=1){ if (tid<o) red[tid]+=red[tid+o]; __syncthreads(); }
  if (tid == 0) out[g] = red[0] + b2[0];
}

// ---------------- host launcher ----------------

extern "C" void kernel_launch(void* const* d_in, const int* in_sizes, int n_in,
                              void* d_out, int out_size, void* d_ws, size_t ws_size,
                              hipStream_t stream)
{
  const float* x         = (const float*)d_in[0];
  const float* pos       = (const float*)d_in[1];
  const float* edist     = (const float*)d_in[2];
  const float* node_in_w = (const float*)d_in[3];
  const float* node_in_b = (const float*)d_in[4];
  const float* tm_w1 = (const float*)d_in[5];
  const float* tm_b1 = (const float*)d_in[6];
  const float* tm_w2 = (const float*)d_in[7];
  const float* tm_b2 = (const float*)d_in[8];
  const float* mm_w1 = (const float*)d_in[9];
  const float* mm_b1 = (const float*)d_in[10];
  const float* mm_w2 = (const float*)d_in[11];
  const float* mm_b2 = (const float*)d_in[12];
  const float* us_w1 = (const float*)d_in[13];
  const float* us_b1 = (const float*)d_in[14];
  const float* us_w2 = (const float*)d_in[15];
  const float* us_b2 = (const float*)d_in[16];
  const float* gv_w1 = (const float*)d_in[17];
  const float* gv_b1 = (const float*)d_in[18];
  const float* gv_w2 = (const float*)d_in[19];
  const float* gv_b2 = (const float*)d_in[20];
  const float* ln_g  = (const float*)d_in[21];
  const float* ln_b  = (const float*)d_in[22];
  const float* vn_init = (const float*)d_in[23];
  const float* v2n_w1 = (const float*)d_in[24];
  const float* v2n_b1 = (const float*)d_in[25];
  const float* v2n_w2 = (const float*)d_in[26];
  const float* v2n_b2 = (const float*)d_in[27];
  const float* n2v_w1 = (const float*)d_in[28];
  const float* n2v_b1 = (const float*)d_in[29];
  const float* n2v_w2 = (const float*)d_in[30];
  const float* n2v_b2 = (const float*)d_in[31];
  const float* head_w1 = (const float*)d_in[32];
  const float* head_b1 = (const float*)d_in[33];
  const float* head_w2 = (const float*)d_in[34];
  const float* head_b2 = (const float*)d_in[35];
  const int* ei    = (const int*)d_in[36];
  const int* t_kj  = (const int*)d_in[37];
  const int* t_ji  = (const int*)d_in[38];
  const int* batch = (const int*)d_in[39];
  float* out = (float*)d_out;

  // ---- workspace layout (~118.7 MiB), unchanged budget ----
  float* f = (float*)d_ws;
  size_t off = 0;
  auto alloc = [&](size_t n){ n = (n + 3) & ~(size_t)3; float* p = f + off; off += n; return p; };
  float*    vec    = alloc((size_t)E_*3);   // aliased: perm_t (T ints) + perm_e (E ints) after k_angle
  float*    dir    = alloc((size_t)E_*3);
  ushort_t* rbf16  = (ushort_t*)alloc((size_t)E_*16);
  float*    angle  = alloc((size_t)T_);
  float*    eagg   = alloc((size_t)E_*128);
  float*    s      = alloc((size_t)N_*128);
  ushort_t* s16    = (ushort_t*)alloc((size_t)N_*64);
  float*    v      = alloc((size_t)N_*384);
  float*    aggs   = alloc((size_t)N_*128);
  float*    aggv   = alloc((size_t)N_*384);
  float*    hu     = alloc((size_t)N_*128); // aliased: sort hist/sums in prologue
  float*    hg     = alloc((size_t)N_*128);
  ushort_t* wtbuf  = (ushort_t*)alloc((size_t)229376/2);
  float*    vn     = alloc((size_t)G_*128);
  float*    tg1    = alloc((size_t)G_*128);
  float*    tg2    = alloc((size_t)G_*128);
  float*    ssum   = alloc((size_t)G_*128);
  float*    addp   = alloc((size_t)G_*256);
  float*    counts = alloc((size_t)G_);
  float*    gbuf   = alloc((size_t)G_*640);
  float*    hh     = alloc((size_t)G_*128);

  if (off * sizeof(float) > ws_size){
    k_sentinel<<<1, 64, 0, stream>>>(out, G_);
    return;
  }

  // aliases
  int* perm_t = (int*)vec;            // T ints
  int* perm_e = perm_t + T_;          // E ints  (perm_t+perm_e == E*3 exactly)
  int* ihist  = (int*)hu;             // up to 131072 ints
  int* isums  = ihist + 131072;       // up to 128 ints

  ushort_t* wt_tm1[2], *wt_tm2[2], *wt_mm1[2], *wt_mm2[2];
  {
    ushort_t* p = wtbuf;
    for (int l=0;l<2;l++){
      wt_tm1[l] = p; p += 128*96;
      wt_tm2[l] = p; p += 128*128;
      wt_mm1[l] = p; p += 128*416;
      wt_mm2[l] = p; p += 256*128;
    }
  }

  auto zero = [&](float* p, long n){
    int blocks = (int)((n + 255)/256); if (blocks > 16384) blocks = 16384;
    k_zero<<<blocks, 256, 0, stream>>>(p, n);
  };
  auto gemm = [&](int SM, int MODE, const float* A,
                  const float* g1, const float* g2, const float* g3,
                  const float* W, int WS, int woff, const float* bias,
                  float* C, int OS, int coff, int R, int K){
    int nblk = (R + RB - 1)/RB; if (nblk > 4096) nblk = 4096;
    k_gemm<<<nblk, 128, 0, stream>>>(SM, MODE, A, g1, g2, g3,
                                     W, WS, woff, bias, C, OS, coff, R, K);
  };
  auto wt = [&](const float* W, ushort_t* Wt, int K, int C, int Kpad){
    int n = C*Kpad;
    k_wt<<<(n + 255)/256, 256, 0, stream>>>(W, Wt, K, C, Kpad);
  };
  auto csort = [&](const int* keys, int M, int B, int* perm){
    zero((float*)ihist, B + (B+1023)/1024);
    k_hist<<<(M+255)/256, 256, 0, stream>>>(keys, M, ihist);
    int nb = (B+1023)/1024;
    k_scan1<<<nb, 256, 0, stream>>>(ihist, ihist, isums, B);
    k_scan2<<<1, 64, 0, stream>>>(isums, nb);
    k_scan3<<<(B+255)/256, 256, 0, stream>>>(ihist, isums, B);
    k_fill<<<(M+255)/256, 256, 0, stream>>>(keys, M, ihist, perm);
  };

  // ---- prologue ----
  zero(v, (long)N_*384);
  k_init_vn<<<(G_*H_ + 255)/256, 256, 0, stream>>>(vn, vn_init);
  k_geom<<<(E_ + 255)/256, 256, 0, stream>>>(pos, edist, ei, vec, dir, rbf16);
  k_angle<<<(T_ + 255)/256, 256, 0, stream>>>(vec, t_kj, t_ji, angle);
  // vec dead from here: build sort permutations in its storage
  csort(t_ji,   T_, E_,  perm_t);   // triplets sorted by ji
  csort(ei+E_,  E_, N_,  perm_e);   // edges sorted by dst
  for (int l=0;l<2;l++){
    wt(tm_w1 + l*80*128,  wt_tm1[l],  80, 128,  96);
    wt(tm_w2 + l*128*128, wt_tm2[l], 128, 128, 128);
    wt(mm_w1 + l*416*128, wt_mm1[l], 416, 128, 416);
    wt(mm_w2 + l*128*256, wt_mm2[l], 128, 256, 128);
  }
  gemm(0,0, x, nullptr,nullptr,nullptr,
       node_in_w,128,0, node_in_b, s,128,0, N_, IND_);

  for (int l=0; l<L_; l++){
    // 1) s += v2n_mlp(vn)[batch]  (also snapshots s16)
    gemm(0,1, vn, nullptr,nullptr,nullptr, v2n_w1,128,0, v2n_b1, tg1,128,0, G_,128);
    gemm(0,0, tg1,nullptr,nullptr,nullptr, v2n_w2,128,0, v2n_b2, tg2,128,0, G_,128);
    k_sadd_batch<<<(N_*H_ + 255)/256, 256, 0, stream>>>(s, tg2, batch, s16);

    // 2) triplet MLP (MFMA, sorted by ji) -> eagg
    zero(eagg, (long)E_*128);
    k_mlp2_mfma<<<T_/BROWS, 256, 0, stream>>>(1, perm_t, t_kj, t_ji, rbf16, angle, s16, eagg,
        wt_tm1[l], tm_b1 + l*128, 96,
        wt_tm2[l], tm_b2 + l*128, 1, dir, eagg, nullptr);

    // 3) edge MLP (MFMA, sorted by dst) -> aggs, aggv
    zero(aggs, (long)N_*128);
    zero(aggv, (long)N_*384);
    k_mlp2_mfma<<<E_/BROWS, 256, 0, stream>>>(2, perm_e, ei, ei + E_, rbf16, angle, s16, eagg,
        wt_mm1[l], mm_b1 + l*128, 416,
        wt_mm2[l], mm_b2 + l*256, 2, dir, aggs, aggv);

    // 4+5) node update + gate
    gemm(3,1, nullptr, s, aggs, v, us_w1 + l*384*128,128,0, us_b1 + l*128, hu,128,0, N_,384);
    gemm(3,1, nullptr, s, aggs, v, gv_w1 + l*384*128,128,0, gv_b1 + l*128, hg,128,0, N_,384);
    gemm(0,2, hu, nullptr,nullptr,nullptr, us_w2 + l*128*128,128,0, us_b2 + l*128, s,128,0, N_,128);
    gemm(0,0, hg, nullptr,nullptr,nullptr, gv_w2 + l*128*128,128,0, gv_b2 + l*128, hu,128,0, N_,128);
    k_gate_v<<<(N_*H_ + 255)/256, 256, 0, stream>>>(hu, aggv, v);

    // 7) s = silu(LN(s))
    k_ln_silu<<<N_, 128, 0, stream>>>(s, ln_g + l*128, ln_b + l*128);

    // 8) vn += n2v_mlp(segment_sum(s, batch))
    zero(ssum, (long)G_*128);
    k_segsum<<<(N_*H_ + 255)/256, 256, 0, stream>>>(s, batch, ssum);
    gemm(0,1, ssum,nullptr,nullptr,nullptr, n2v_w1,128,0, n2v_b1, tg1,128,0, G_,128);
    gemm(0,2, tg1, nullptr,nullptr,nullptr, n2v_w2,128,0, n2v_b2, vn,128,0, G_,128);
  }

  // ---- readout ----
  zero(addp, (long)(G_*256 + G_));
  k_scatter_nf<<<(N_*256 + 255)/256, 256, 0, stream>>>(s, v, batch, addp);
  k_counts<<<(N_ + 255)/256, 256, 0, stream>>>(batch, counts);
  k_build_g<<<(G_*640 + 255)/256, 256, 0, stream>>>(addp, counts, vn, gbuf);
  gemm(0,1, gbuf,nullptr,nullptr,nullptr, head_w1,128,0, head_b1, hh,128,0, G_,640);
  k_head_final<<<G_, 128, 0, stream>>>(hh, head_w2, head_b2, out);
}

// Round 6
// 1455.584 us; speedup vs baseline: 6.0389x; 1.7251x over previous
//
#include <hip/hip_runtime.h>
#include <math.h>

// ---- problem constants (from reference) ----
#define N_   8192
#define E_   131072
#define T_   262144
#define H_   128
#define IND_ 64
#define G_   32
#define L_   2

// generic fp32 GEMM tiling (node_in only)
#define CW 64
#define RB 16

// MFMA fused MLP tiling
#define MROWS 32     // rows per wave
#define BROWS 128    // rows per block (4 waves)
#define HSTRIDE 136  // LDS hidden row stride (bf16 elems)

// RBF constants
#define STEP_E  ((float)(5.0/31.0))
#define GAMMA_E ((float)(1.0/(2.0*((5.0/31.0)*(5.0/31.0) + 1e-12))))
#define PI_D    3.14159265358979323846
#define STEP_A  ((float)(PI_D/15.0))
#define GAMMA_A ((float)(1.0/(2.0*((PI_D/15.0)*(PI_D/15.0) + 1e-12))))

typedef __attribute__((ext_vector_type(8))) short short8;
typedef __attribute__((ext_vector_type(4))) float f32x4;
typedef unsigned short ushort_t;

static __device__ __forceinline__ float silu_f(float x){ return x / (1.f + expf(-x)); }
static __device__ __forceinline__ float sigmoid_f(float x){ return 1.f / (1.f + expf(-x)); }

static __device__ __forceinline__ ushort_t f2bf(float x){
  unsigned int u = __builtin_bit_cast(unsigned int, x);
  u += 0x7FFFu + ((u >> 16) & 1u);
  return (ushort_t)(u >> 16);
}
static __device__ __forceinline__ float bf2f(ushort_t h){
  unsigned int u = ((unsigned int)h) << 16;
  return __builtin_bit_cast(float, u);
}

// ---------------- small utility kernels ----------------

__global__ void k_zero(float* __restrict__ p, long n){
  long i = (long)blockIdx.x*256 + threadIdx.x;
  long stride = (long)gridDim.x*256;
  for (; i < n; i += stride) p[i] = 0.f;
}

__global__ void k_sentinel(float* __restrict__ p, int n){
  int i = blockIdx.x*256 + threadIdx.x;
  if (i < n) p[i] = 1.0e30f;
}

__global__ void k_init_vn(float* __restrict__ vn, const float* __restrict__ vn_init){
  int i = blockIdx.x*256 + threadIdx.x;
  if (i < G_*H_) vn[i] = vn_init[i & 127];
}

// weight convert+transpose (hi only): W fp32 [K][C] -> Wt bf16 [C][Kpad]
__global__ void k_wt(const float* __restrict__ W, ushort_t* __restrict__ Wt,
                     int K, int C, int Kpad){
  int i = blockIdx.x*256 + threadIdx.x;
  if (i >= C*Kpad) return;
  int c = i / Kpad, k = i % Kpad;
  Wt[i] = (k < K) ? f2bf(W[(size_t)k*C + c]) : (ushort_t)0;
}

// weight convert+transpose with residual: hi + lo (bf16x2 split)
__global__ void k_wt2(const float* __restrict__ W, ushort_t* __restrict__ Whi,
                      ushort_t* __restrict__ Wlo, int K, int C, int Kpad){
  int i = blockIdx.x*256 + threadIdx.x;
  if (i >= C*Kpad) return;
  int c = i / Kpad, k = i % Kpad;
  float w = (k < K) ? W[(size_t)k*C + c] : 0.f;
  ushort_t h = f2bf(w);
  Whi[i] = h;
  Wlo[i] = f2bf(w - bf2f(h));
}

// per-edge: vec, dir, edge RBF(32) in bf16
__global__ void k_geom(const float* __restrict__ pos, const float* __restrict__ dist,
                       const int* __restrict__ ei,
                       float* __restrict__ vec, float* __restrict__ dir,
                       ushort_t* __restrict__ rbf16){
  int e = blockIdx.x*256 + threadIdx.x;
  if (e >= E_) return;
  int s = ei[e], d = ei[E_ + e];
  float vx = pos[d*3+0] - pos[s*3+0];
  float vy = pos[d*3+1] - pos[s*3+1];
  float vz = pos[d*3+2] - pos[s*3+2];
  vec[e*3+0]=vx; vec[e*3+1]=vy; vec[e*3+2]=vz;
  float dd = dist[e];
  float inv = 1.f / (dd + 1e-9f);
  dir[e*3+0]=vx*inv; dir[e*3+1]=vy*inv; dir[e*3+2]=vz*inv;
  #pragma unroll
  for (int i=0;i<32;i++){
    float df = dd - i*STEP_E;
    rbf16[e*32+i] = f2bf(expf(-GAMMA_E*df*df));
  }
}

// per-triplet angle
__global__ void k_angle(const float* __restrict__ vec,
                        const int* __restrict__ kj, const int* __restrict__ ji,
                        float* __restrict__ angle){
  int t = blockIdx.x*256 + threadIdx.x;
  if (t >= T_) return;
  int ea = ji[t], eb = kj[t];
  float ax=vec[ea*3+0], ay=vec[ea*3+1], az=vec[ea*3+2];
  float bx=vec[eb*3+0], by=vec[eb*3+1], bz=vec[eb*3+2];
  float dot = ax*bx + ay*by + az*bz;
  float na = sqrtf(ax*ax+ay*ay+az*az + 1e-12f);
  float nb = sqrtf(bx*bx+by*by+bz*bz + 1e-12f);
  float c = dot / (na*nb + 1e-9f);
  c = fminf(fmaxf(c, -1.f + 1e-7f), 1.f - 1e-7f);
  angle[t] = acosf(c);
}

// ---------------- counting-sort kernels ----------------

__global__ void k_hist(const int* __restrict__ keys, int M, int* __restrict__ hist){
  int i = blockIdx.x*256 + threadIdx.x;
  if (i < M) atomicAdd(&hist[keys[i]], 1);
}

__global__ void k_scan1(const int* __restrict__ in, int* __restrict__ out,
                        int* __restrict__ sums, int B){
  __shared__ int sh[1024];
  int base = blockIdx.x*1024, t = threadIdx.x;
  for (int j=t;j<1024;j+=256) sh[j] = (base+j<B) ? in[base+j] : 0;
  __syncthreads();
  for (int o=1;o<1024;o<<=1){
    int v[4];
    #pragma unroll
    for (int q=0;q<4;q++){ int idx=t+q*256; v[q]=(idx>=o)? sh[idx-o]:0; }
    __syncthreads();
    #pragma unroll
    for (int q=0;q<4;q++){ int idx=t+q*256; sh[idx]+=v[q]; }
    __syncthreads();
  }
  for (int j=t;j<1024;j+=256) if (base+j<B) out[base+j] = (j==0)?0:sh[j-1];
  if (t==0) sums[blockIdx.x] = sh[1023];
}

__global__ void k_scan2(int* __restrict__ sums, int nb){
  if (threadIdx.x==0 && blockIdx.x==0){
    int a=0;
    for (int i=0;i<nb;i++){ int x=sums[i]; sums[i]=a; a+=x; }
  }
}

__global__ void k_scan3(int* __restrict__ out, const int* __restrict__ sums, int B){
  int i = blockIdx.x*256+threadIdx.x;
  if (i<B) out[i] += sums[i>>10];
}

__global__ void k_fill(const int* __restrict__ keys, int M, int* __restrict__ cur,
                       int* __restrict__ perm){
  int i = blockIdx.x*256+threadIdx.x;
  if (i<M){ int p = atomicAdd(&cur[keys[i]],1); perm[p]=i; }
}

// ---------------- MFMA fused 2-layer MLP + sorted segment-scatter ----------------
__launch_bounds__(256, 3)
__global__ void k_mlp2_mfma(int SM,
    const int* __restrict__ perm,
    const int* __restrict__ idx1, const int* __restrict__ idx2,
    const ushort_t* __restrict__ rbf16, const float* __restrict__ angle,
    const ushort_t* __restrict__ s16, const float* __restrict__ eagg_in,
    const ushort_t* __restrict__ W1t, const float* __restrict__ b1, int K1pad,
    const ushort_t* __restrict__ W2t, const float* __restrict__ b2, int OUTgrp,
    const float* __restrict__ dir,
    float* __restrict__ out0, float* __restrict__ out1)
{
  __shared__ ushort_t hid[BROWS*HSTRIDE];   // 34816 B
  __shared__ float mchunk[BROWS][33];       // 16896 B
  __shared__ int   segk[BROWS];
  __shared__ float dirs[BROWS][3];
  const int tid  = threadIdx.x;
  const int wave = tid >> 6;
  const int lane = tid & 63;
  const int n    = lane & 15;
  const int quad = lane >> 4;
  const int kq   = quad*8;
  const int wrow = blockIdx.x*BROWS + wave*MROWS;
  const int lrow = wave*MROWS;

  for (int i=tid; i<BROWS; i+=256){
    int e = perm[blockIdx.x*BROWS + i];
    segk[i] = idx2[e];
    if (SM == 2){
      dirs[i][0]=dir[e*3+0]; dirs[i][1]=dir[e*3+1]; dirs[i][2]=dir[e*3+2];
    }
  }

  const int e0 = perm[wrow + n];
  const int e1 = perm[wrow + 16 + n];

  int i1a = idx1[e0], i1b = idx1[e1];
  int i2a = idx2[e0], i2b = idx2[e1];
  float ang0 = 0.f, ang1 = 0.f;
  if (SM == 1){ ang0 = angle[e0]; ang1 = angle[e1]; }

  // ---------- phase A ----------
  f32x4 acc[2][8];
  #pragma unroll
  for (int rh=0;rh<2;rh++)
    #pragma unroll
    for (int ct=0;ct<8;ct++) acc[rh][ct] = (f32x4){0.f,0.f,0.f,0.f};

  for (int k0 = 0; k0 < K1pad; k0 += 32){
    short8 a0, a1;
    if (SM == 1){
      if (k0 == 0){
        a0 = *(const short8*)&rbf16[(size_t)i1a*32 + kq];
        a1 = *(const short8*)&rbf16[(size_t)i1b*32 + kq];
      } else if (k0 == 32){
        a0 = *(const short8*)&rbf16[(size_t)i2a*32 + kq];
        a1 = *(const short8*)&rbf16[(size_t)i2b*32 + kq];
      } else {
        #pragma unroll
        for (int j=0;j<8;j++){
          int kk = kq + j;
          float v0 = 0.f, v1 = 0.f;
          if (kk < 16){
            float c = (float)kk*STEP_A;
            float d0 = ang0 - c, d1 = ang1 - c;
            v0 = expf(-GAMMA_A*d0*d0); v1 = expf(-GAMMA_A*d1*d1);
          }
          a0[j] = (short)f2bf(v0); a1[j] = (short)f2bf(v1);
        }
      }
    } else {
      int k = k0 + kq;
      if (k0 < 128){
        a0 = *(const short8*)&s16[(size_t)i1a*128 + k];
        a1 = *(const short8*)&s16[(size_t)i1b*128 + k];
      } else if (k0 < 256){
        a0 = *(const short8*)&s16[(size_t)i2a*128 + (k-128)];
        a1 = *(const short8*)&s16[(size_t)i2b*128 + (k-128)];
      } else if (k0 < 288){
        a0 = *(const short8*)&rbf16[(size_t)e0*32 + (k-256)];
        a1 = *(const short8*)&rbf16[(size_t)e1*32 + (k-256)];
      } else {
        const float* p0 = &eagg_in[(size_t)e0*128 + (k-288)];
        const float* p1 = &eagg_in[(size_t)e1*128 + (k-288)];
        f32x4 x0 = *(const f32x4*)p0, x1 = *(const f32x4*)(p0+4);
        f32x4 y0 = *(const f32x4*)p1, y1 = *(const f32x4*)(p1+4);
        #pragma unroll
        for (int j=0;j<4;j++){
          a0[j] = (short)f2bf(x0[j]); a0[4+j] = (short)f2bf(x1[j]);
          a1[j] = (short)f2bf(y0[j]); a1[4+j] = (short)f2bf(y1[j]);
        }
      }
    }
    #pragma unroll
    for (int ct=0;ct<8;ct++){
      short8 b = *(const short8*)&W1t[(size_t)(ct*16 + n)*K1pad + k0 + kq];
      acc[0][ct] = __builtin_amdgcn_mfma_f32_16x16x32_bf16(a0, b, acc[0][ct], 0,0,0);
      acc[1][ct] = __builtin_amdgcn_mfma_f32_16x16x32_bf16(a1, b, acc[1][ct], 0,0,0);
    }
  }

  #pragma unroll
  for (int rh=0;rh<2;rh++){
    #pragma unroll
    for (int ct=0;ct<8;ct++){
      int col = ct*16 + n;
      float bv = b1[col];
      #pragma unroll
      for (int reg=0;reg<4;reg++){
        int rloc = lrow + rh*16 + quad*4 + reg;
        float h = acc[rh][ct][reg] + bv;
        hid[rloc*HSTRIDE + col] = f2bf(silu_f(h));
      }
    }
  }

  // ---------- phase B ----------
  for (int og=0; og<OUTgrp; og++){
    f32x4 acc2[2][8];
    #pragma unroll
    for (int rh=0;rh<2;rh++)
      #pragma unroll
      for (int ct=0;ct<8;ct++) acc2[rh][ct] = (f32x4){0.f,0.f,0.f,0.f};

    #pragma unroll
    for (int k0=0;k0<128;k0+=32){
      short8 a0 = *(const short8*)&hid[(size_t)(lrow + n)*HSTRIDE + k0 + kq];
      short8 a1 = *(const short8*)&hid[(size_t)(lrow + 16 + n)*HSTRIDE + k0 + kq];
      #pragma unroll
      for (int ct=0;ct<8;ct++){
        short8 b = *(const short8*)&W2t[(size_t)(og*128 + ct*16 + n)*128 + k0 + kq];
        acc2[0][ct] = __builtin_amdgcn_mfma_f32_16x16x32_bf16(a0, b, acc2[0][ct], 0,0,0);
        acc2[1][ct] = __builtin_amdgcn_mfma_f32_16x16x32_bf16(a1, b, acc2[1][ct], 0,0,0);
      }
    }

    for (int ch=0; ch<4; ch++){
      const int c0 = ch*32;
      __syncthreads();
      #pragma unroll
      for (int rh=0;rh<2;rh++){
        #pragma unroll
        for (int cti=0;cti<2;cti++){
          int ct = ch*2 + cti;
          int col = ct*16 + n;
          float bv = b2[og*128 + col];
          #pragma unroll
          for (int reg=0;reg<4;reg++){
            int r = lrow + rh*16 + quad*4 + reg;
            mchunk[r][col - c0] = acc2[rh][ct][reg] + bv;
          }
        }
      }
      __syncthreads();
      const int col = c0 + (tid & 31);
      const int w0r = (tid >> 5) * 16;
      if (SM == 1 || og == 0){
        float a = 0.f; int prev = segk[w0r];
        for (int j=0;j<16;j++){
          int r = w0r + j;
          int k = segk[r];
          if (k != prev){ atomicAdd(&out0[(size_t)prev*128 + col], a); a = 0.f; prev = k; }
          a += mchunk[r][col - c0];
        }
        atomicAdd(&out0[(size_t)prev*128 + col], a);
      } else {
        float ax=0.f, ay=0.f, az=0.f; int prev = segk[w0r];
        for (int j=0;j<16;j++){
          int r = w0r + j;
          int k = segk[r];
          if (k != prev){
            size_t b = ((size_t)prev*128 + col)*3;
            atomicAdd(&out1[b+0], ax); atomicAdd(&out1[b+1], ay); atomicAdd(&out1[b+2], az);
            ax=ay=az=0.f; prev = k;
          }
          float m = mchunk[r][col - c0];
          ax += m*dirs[r][0]; ay += m*dirs[r][1]; az += m*dirs[r][2];
        }
        size_t b = ((size_t)prev*128 + col)*3;
        atomicAdd(&out1[b+0], ax); atomicAdd(&out1[b+1], ay); atomicAdd(&out1[b+2], az);
      }
    }
  }
}

// ---------------- MFMA node-update kernel (us + gv), bf16x3 = fp32-equivalent ----------------
// ctx split hi/lo: x = hi + lo. x@W = hi@Whi + lo@Whi + hi@Wlo (lo@lo dropped).
// Hidden stored as hi/lo pair in LDS; layer 2 same 3-pass scheme.
// og0: s[node,col] += us_mlp ; og1: g = sigmoid(gv_mlp); v += g*aggv (row-aligned, no atomics)
__launch_bounds__(256, 2)
__global__ void k_node_mfma(
    const ushort_t* __restrict__ ctx_hi, const ushort_t* __restrict__ ctx_lo,
    float* __restrict__ s, float* __restrict__ v,
    const float* __restrict__ aggv,
    const ushort_t* __restrict__ us1h, const ushort_t* __restrict__ us1l, const float* __restrict__ us_b1,
    const ushort_t* __restrict__ us2h, const ushort_t* __restrict__ us2l, const float* __restrict__ us_b2,
    const ushort_t* __restrict__ gv1h, const ushort_t* __restrict__ gv1l, const float* __restrict__ gv_b1,
    const ushort_t* __restrict__ gv2h, const ushort_t* __restrict__ gv2l, const float* __restrict__ gv_b2)
{
  __shared__ ushort_t hidh[BROWS*HSTRIDE];   // 34816 B
  __shared__ ushort_t hidl[BROWS*HSTRIDE];   // 34816 B
  const int tid  = threadIdx.x;
  const int wave = tid >> 6;
  const int lane = tid & 63;
  const int n    = lane & 15;
  const int quad = lane >> 4;
  const int kq   = quad*8;
  const int wrow = blockIdx.x*BROWS + wave*MROWS;
  const int lrow = wave*MROWS;
  const int r0 = wrow + n;
  const int r1 = wrow + 16 + n;

  for (int og=0; og<2; og++){
    const ushort_t* W1h = og ? gv1h : us1h;
    const ushort_t* W1l = og ? gv1l : us1l;
    const float*    B1  = og ? gv_b1 : us_b1;
    const ushort_t* W2h = og ? gv2h : us2h;
    const ushort_t* W2l = og ? gv2l : us2l;
    const float*    B2  = og ? gv_b2 : us_b2;

    f32x4 acc[2][8];
    #pragma unroll
    for (int rh=0;rh<2;rh++)
      #pragma unroll
      for (int ct=0;ct<8;ct++) acc[rh][ct] = (f32x4){0.f,0.f,0.f,0.f};

    for (int k0=0; k0<384; k0+=32){
      short8 ah0 = *(const short8*)&ctx_hi[(size_t)r0*384 + k0 + kq];
      short8 ah1 = *(const short8*)&ctx_hi[(size_t)r1*384 + k0 + kq];
      short8 al0 = *(const short8*)&ctx_lo[(size_t)r0*384 + k0 + kq];
      short8 al1 = *(const short8*)&ctx_lo[(size_t)r1*384 + k0 + kq];
      #pragma unroll
      for (int ct=0;ct<8;ct++){
        short8 bh = *(const short8*)&W1h[(size_t)(ct*16 + n)*384 + k0 + kq];
        short8 bl = *(const short8*)&W1l[(size_t)(ct*16 + n)*384 + k0 + kq];
        acc[0][ct] = __builtin_amdgcn_mfma_f32_16x16x32_bf16(ah0, bh, acc[0][ct], 0,0,0);
        acc[0][ct] = __builtin_amdgcn_mfma_f32_16x16x32_bf16(al0, bh, acc[0][ct], 0,0,0);
        acc[0][ct] = __builtin_amdgcn_mfma_f32_16x16x32_bf16(ah0, bl, acc[0][ct], 0,0,0);
        acc[1][ct] = __builtin_amdgcn_mfma_f32_16x16x32_bf16(ah1, bh, acc[1][ct], 0,0,0);
        acc[1][ct] = __builtin_amdgcn_mfma_f32_16x16x32_bf16(al1, bh, acc[1][ct], 0,0,0);
        acc[1][ct] = __builtin_amdgcn_mfma_f32_16x16x32_bf16(ah1, bl, acc[1][ct], 0,0,0);
      }
    }

    #pragma unroll
    for (int rh=0;rh<2;rh++){
      #pragma unroll
      for (int ct=0;ct<8;ct++){
        int col = ct*16 + n;
        float bv = B1[col];
        #pragma unroll
        for (int reg=0;reg<4;reg++){
          int rloc = lrow + rh*16 + quad*4 + reg;
          float h = silu_f(acc[rh][ct][reg] + bv);
          ushort_t hh = f2bf(h);
          hidh[rloc*HSTRIDE + col] = hh;
          hidl[rloc*HSTRIDE + col] = f2bf(h - bf2f(hh));
        }
      }
    }

    f32x4 acc2[2][8];
    #pragma unroll
    for (int rh=0;rh<2;rh++)
      #pragma unroll
      for (int ct=0;ct<8;ct++) acc2[rh][ct] = (f32x4){0.f,0.f,0.f,0.f};

    #pragma unroll
    for (int k0=0;k0<128;k0+=32){
      short8 ah0 = *(const short8*)&hidh[(size_t)(lrow + n)*HSTRIDE + k0 + kq];
      short8 ah1 = *(const short8*)&hidh[(size_t)(lrow + 16 + n)*HSTRIDE + k0 + kq];
      short8 al0 = *(const short8*)&hidl[(size_t)(lrow + n)*HSTRIDE + k0 + kq];
      short8 al1 = *(const short8*)&hidl[(size_t)(lrow + 16 + n)*HSTRIDE + k0 + kq];
      #pragma unroll
      for (int ct=0;ct<8;ct++){
        short8 bh = *(const short8*)&W2h[(size_t)(ct*16 + n)*128 + k0 + kq];
        short8 bl = *(const short8*)&W2l[(size_t)(ct*16 + n)*128 + k0 + kq];
        acc2[0][ct] = __builtin_amdgcn_mfma_f32_16x16x32_bf16(ah0, bh, acc2[0][ct], 0,0,0);
        acc2[0][ct] = __builtin_amdgcn_mfma_f32_16x16x32_bf16(al0, bh, acc2[0][ct], 0,0,0);
        acc2[0][ct] = __builtin_amdgcn_mfma_f32_16x16x32_bf16(ah0, bl, acc2[0][ct], 0,0,0);
        acc2[1][ct] = __builtin_amdgcn_mfma_f32_16x16x32_bf16(ah1, bh, acc2[1][ct], 0,0,0);
        acc2[1][ct] = __builtin_amdgcn_mfma_f32_16x16x32_bf16(al1, bh, acc2[1][ct], 0,0,0);
        acc2[1][ct] = __builtin_amdgcn_mfma_f32_16x16x32_bf16(ah1, bl, acc2[1][ct], 0,0,0);
      }
    }

    if (og == 0){
      #pragma unroll
      for (int rh=0;rh<2;rh++){
        #pragma unroll
        for (int ct=0;ct<8;ct++){
          int col = ct*16 + n;
          float bv = B2[col];
          #pragma unroll
          for (int reg=0;reg<4;reg++){
            int row = wrow + rh*16 + quad*4 + reg;
            size_t idx = (size_t)row*128 + col;
            s[idx] += acc2[rh][ct][reg] + bv;
          }
        }
      }
    } else {
      #pragma unroll
      for (int rh=0;rh<2;rh++){
        #pragma unroll
        for (int ct=0;ct<8;ct++){
          int col = ct*16 + n;
          float bv = B2[col];
          #pragma unroll
          for (int reg=0;reg<4;reg++){
            int row = wrow + rh*16 + quad*4 + reg;
            size_t idx = (size_t)row*128 + col;
            float g = sigmoid_f(acc2[rh][ct][reg] + bv);
            size_t base = idx*3;
            v[base+0] += g*aggv[base+0];
            v[base+1] += g*aggv[base+1];
            v[base+2] += g*aggv[base+2];
          }
        }
      }
    }
  }
}

// ---------------- generic fp32 row-MLP GEMM (node_in only) ----------------
__launch_bounds__(128)
__global__ void k_gemm(const float* __restrict__ A,
                       const float* __restrict__ W,
                       const float* __restrict__ bias,
                       float* __restrict__ C, int R, int K)
{
  __shared__ float ws[CW*128];
  __shared__ float as[RB][CW];
  const int tid = threadIdx.x;
  const int nchunk = (K + CW - 1) / CW;

  for (int rb = blockIdx.x*RB; rb < R; rb += gridDim.x*RB){
    float acc[RB];
    #pragma unroll
    for (int r=0;r<RB;r++) acc[r] = 0.f;

    for (int c=0;c<nchunk;c++){
      const int k0 = c*CW;
      for (int i=tid; i<CW*128; i+=128){
        int kk = i >> 7, col = i & 127;
        int k = k0 + kk;
        ws[i] = (k < K) ? W[k*128 + col] : 0.f;
      }
      for (int i=tid; i<RB*CW; i+=128){
        int r  = i >> 6, kk = i & 63;
        int k  = k0 + kk;
        as[r][kk] = (k < K) ? A[(long)(rb+r)*K + k] : 0.f;
      }
      __syncthreads();
      #pragma unroll 4
      for (int kq2=0; kq2<CW/4; kq2++){
        float w0 = ws[(4*kq2+0)*128 + tid];
        float w1 = ws[(4*kq2+1)*128 + tid];
        float w2 = ws[(4*kq2+2)*128 + tid];
        float w3 = ws[(4*kq2+3)*128 + tid];
        #pragma unroll
        for (int r=0;r<RB;r++){
          const float4 av = *reinterpret_cast<const float4*>(&as[r][4*kq2]);
          acc[r] = fmaf(av.x, w0, acc[r]);
          acc[r] = fmaf(av.y, w1, acc[r]);
          acc[r] = fmaf(av.z, w2, acc[r]);
          acc[r] = fmaf(av.w, w3, acc[r]);
        }
      }
      __syncthreads();
    }

    const float bv = bias[tid];
    #pragma unroll
    for (int r=0;r<RB;r++)
      C[(long)(rb+r)*128 + tid] = acc[r] + bv;
  }
}

// ---------------- small fused kernels ----------------

// 32-row 2-layer MLP (v2n / n2v), single block, 256 threads
__launch_bounds__(256)
__global__ void k_small_mlp2(const float* __restrict__ in,
                             const float* __restrict__ w1, const float* __restrict__ b1,
                             const float* __restrict__ w2, const float* __restrict__ b2,
                             float* __restrict__ outp, int accumulate){
  __shared__ float a[32][128];
  __shared__ float h[32][128];
  int tid = threadIdx.x;
  for (int i=tid;i<32*128;i+=256) a[i>>7][i&127] = in[i];
  __syncthreads();
  int col = tid & 127, rg = tid >> 7;
  float acc[16];
  #pragma unroll
  for (int r=0;r<16;r++) acc[r]=0.f;
  for (int k=0;k<128;k++){
    float w = w1[k*128+col];
    #pragma unroll
    for (int r=0;r<16;r++) acc[r] = fmaf(a[rg*16+r][k], w, acc[r]);
  }
  {
    float bv = b1[col];
    #pragma unroll
    for (int r=0;r<16;r++) h[rg*16+r][col] = silu_f(acc[r]+bv);
  }
  __syncthreads();
  #pragma unroll
  for (int r=0;r<16;r++) acc[r]=0.f;
  for (int k=0;k<128;k++){
    float w = w2[k*128+col];
    #pragma unroll
    for (int r=0;r<16;r++) acc[r] = fmaf(h[rg*16+r][k], w, acc[r]);
  }
  {
    float bv = b2[col];
    #pragma unroll
    for (int r=0;r<16;r++){
      int idx = (rg*16+r)*128+col;
      float val = acc[r]+bv;
      outp[idx] = accumulate ? outp[idx]+val : val;
    }
  }
}

// head MLP + final dot, one block per graph
__global__ void k_head(const float* __restrict__ gbuf,
                       const float* __restrict__ w1, const float* __restrict__ b1,
                       const float* __restrict__ w2, const float* __restrict__ b2,
                       float* __restrict__ outp){
  __shared__ float red[128];
  int g = blockIdx.x, tid = threadIdx.x;
  float acc = 0.f;
  for (int k=0;k<640;k++) acc = fmaf(gbuf[g*640+k], w1[k*128+tid], acc);
  float h = silu_f(acc + b1[tid]);
  red[tid] = h * w2[tid];
  __syncthreads();
  for (int o=64;o>0;o>>=1){ if (tid<o) red[tid]+=red[tid+o]; __syncthreads(); }
  if (tid == 0) outp[g] = red[0] + b2[0];
}

// ---------------- elementwise / reduction kernels ----------------

__global__ void k_sadd_batch(float* __restrict__ s, const float* __restrict__ t2,
                             const int* __restrict__ batch, ushort_t* __restrict__ s16){
  int i = blockIdx.x*256 + threadIdx.x;
  if (i >= N_*H_) return;
  int n = i >> 7, h = i & 127;
  float v = s[i] + t2[batch[n]*128 + h];
  s[i] = v;
  s16[i] = f2bf(v);
}

// build ctx hi/lo = split([s | aggs | ||v||]) in bf16 pairs
__global__ void k_ctx16(const float* __restrict__ s, const float* __restrict__ aggs,
                        const float* __restrict__ v,
                        ushort_t* __restrict__ ctx_hi, ushort_t* __restrict__ ctx_lo){
  int i = blockIdx.x*256 + threadIdx.x;
  if (i >= N_*H_) return;
  int n = i >> 7, h = i & 127;
  float v0 = v[(size_t)i*3+0], v1 = v[(size_t)i*3+1], v2 = v[(size_t)i*3+2];
  float vals[3];
  vals[0] = s[i];
  vals[1] = aggs[i];
  vals[2] = sqrtf(v0*v0 + v1*v1 + v2*v2 + 1e-12f);
  #pragma unroll
  for (int p=0;p<3;p++){
    size_t idx = (size_t)n*384 + p*128 + h;
    ushort_t hi = f2bf(vals[p]);
    ctx_hi[idx] = hi;
    ctx_lo[idx] = f2bf(vals[p] - bf2f(hi));
  }
}

__global__ void k_ln_silu(float* __restrict__ s, const float* __restrict__ g,
                          const float* __restrict__ b){
  __shared__ float red[128];
  int n = blockIdx.x, tid = threadIdx.x;
  float x = s[n*128 + tid];
  red[tid] = x; __syncthreads();
  for (int o=64;o>0;o>>=1){ if (tid<o) red[tid]+=red[tid+o]; __syncthreads(); }
  float mu = red[0] * (1.f/128.f);
  __syncthreads();
  float dx = x - mu;
  red[tid] = dx*dx; __syncthreads();
  for (int o=64;o>0;o>>=1){ if (tid<o) red[tid]+=red[tid+o]; __syncthreads(); }
  float var = red[0] * (1.f/128.f);
  float y = dx * rsqrtf(var + 1e-5f) * g[tid] + b[tid];
  s[n*128 + tid] = silu_f(y);
}

__global__ void k_segsum(const float* __restrict__ s, const int* __restrict__ batch,
                         float* __restrict__ ssum){
  int i = blockIdx.x*256 + threadIdx.x;
  if (i >= N_*H_) return;
  int n = i >> 7, h = i & 127;
  atomicAdd(&ssum[batch[n]*128 + h], s[i]);
}

__global__ void k_scatter_nf(const float* __restrict__ s, const float* __restrict__ v,
                             const int* __restrict__ batch, float* __restrict__ addp,
                             float* __restrict__ counts){
  int i = blockIdx.x*256 + threadIdx.x;
  if (i >= N_*256) return;
  int n = i >> 8, j = i & 255;
  float val;
  if (j < 128){
    val = s[n*128 + j];
  } else {
    int h = j - 128;
    float v0 = v[((size_t)n*128+h)*3+0], v1 = v[((size_t)n*128+h)*3+1], v2 = v[((size_t)n*128+h)*3+2];
    val = sqrtf(v0*v0 + v1*v1 + v2*v2 + 1e-12f);
  }
  int b = batch[n];
  atomicAdd(&addp[b*256 + j], val);
  if (j == 0) atomicAdd(&counts[b], 1.f);
}

__global__ void k_build_g(const float* __restrict__ addp, const float* __restrict__ counts,
                          const float* __restrict__ vn, float* __restrict__ gbuf){
  int i = blockIdx.x*256 + threadIdx.x;
  if (i >= G_*640) return;
  int g = i / 640, j = i % 640;
  float val;
  if (j < 256)       val = addp[g*256 + j];
  else if (j < 512)  val = addp[g*256 + (j-256)] / fmaxf(counts[g], 1.f);
  else               val = vn[g*128 + (j-512)];
  gbuf[i] = val;
}

// ---------------- host launcher ----------------

extern "C" void kernel_launch(void* const* d_in, const int* in_sizes, int n_in,
                              void* d_out, int out_size, void* d_ws, size_t ws_size,
                              hipStream_t stream)
{
  const float* x         = (const float*)d_in[0];
  const float* pos       = (const float*)d_in[1];
  const float* edist     = (const float*)d_in[2];
  const float* node_in_w = (const float*)d_in[3];
  const float* node_in_b = (const float*)d_in[4];
  const float* tm_w1 = (const float*)d_in[5];
  const float* tm_b1 = (const float*)d_in[6];
  const float* tm_w2 = (const float*)d_in[7];
  const float* tm_b2 = (const float*)d_in[8];
  const float* mm_w1 = (const float*)d_in[9];
  const float* mm_b1 = (const float*)d_in[10];
  const float* mm_w2 = (const float*)d_in[11];
  const float* mm_b2 = (const float*)d_in[12];
  const float* us_w1 = (const float*)d_in[13];
  const float* us_b1 = (const float*)d_in[14];
  const float* us_w2 = (const float*)d_in[15];
  const float* us_b2 = (const float*)d_in[16];
  const float* gv_w1 = (const float*)d_in[17];
  const float* gv_b1 = (const float*)d_in[18];
  const float* gv_w2 = (const float*)d_in[19];
  const float* gv_b2 = (const float*)d_in[20];
  const float* ln_g  = (const float*)d_in[21];
  const float* ln_b  = (const float*)d_in[22];
  const float* vn_init = (const float*)d_in[23];
  const float* v2n_w1 = (const float*)d_in[24];
  const float* v2n_b1 = (const float*)d_in[25];
  const float* v2n_w2 = (const float*)d_in[26];
  const float* v2n_b2 = (const float*)d_in[27];
  const float* n2v_w1 = (const float*)d_in[28];
  const float* n2v_b1 = (const float*)d_in[29];
  const float* n2v_w2 = (const float*)d_in[30];
  const float* n2v_b2 = (const float*)d_in[31];
  const float* head_w1 = (const float*)d_in[32];
  const float* head_b1 = (const float*)d_in[33];
  const float* head_w2 = (const float*)d_in[34];
  const float* head_b2 = (const float*)d_in[35];
  const int* ei    = (const int*)d_in[36];
  const int* t_kj  = (const int*)d_in[37];
  const int* t_ji  = (const int*)d_in[38];
  const int* batch = (const int*)d_in[39];
  float* out = (float*)d_out;

  // ---- workspace layout (~117.5 MiB) ----
  float* f = (float*)d_ws;
  size_t off = 0;
  auto alloc = [&](size_t n){ n = (n + 3) & ~(size_t)3; float* p = f + off; off += n; return p; };
  float*    vec    = alloc((size_t)E_*3);   // aliased: perm_t + perm_e after k_angle
  float*    dir    = alloc((size_t)E_*3);
  ushort_t* rbf16  = (ushort_t*)alloc((size_t)E_*16);
  float*    angle  = alloc((size_t)T_);
  float*    eagg   = alloc((size_t)E_*128);  // also hosts ctx_hi/ctx_lo (disjoint lifetime)
  float*    s      = alloc((size_t)N_*128);
  ushort_t* s16    = (ushort_t*)alloc((size_t)N_*64);
  float*    v      = alloc((size_t)N_*384);
  float*    aggs   = alloc((size_t)N_*128);  // aliased: ihist in prologue
  float*    aggv   = alloc((size_t)N_*384);
  float*    wtbuf_f= alloc((size_t)376832);  // bf16 transposed weights (hi + node-lo)
  float*    vn     = alloc((size_t)G_*128);
  float*    tg2    = alloc((size_t)G_*128);
  float*    ssum   = alloc((size_t)G_*128);
  float*    addp   = alloc((size_t)G_*256);
  float*    counts = alloc((size_t)G_);
  float*    gbuf   = alloc((size_t)G_*640);

  if (off * sizeof(float) > ws_size){
    k_sentinel<<<1, 64, 0, stream>>>(out, G_);
    return;
  }

  // aliases
  int* perm_t = (int*)vec;
  int* perm_e = perm_t + T_;
  int* ihist  = (int*)aggs;           // prologue only
  int* isums  = ihist + 131072;
  ushort_t* ctx_hi = (ushort_t*)eagg;            // N*384 bf16 (lifetime: step 4..4.5)
  ushort_t* ctx_lo = ctx_hi + (size_t)N_*384;    // N*384 bf16

  ushort_t* wtp = (ushort_t*)wtbuf_f;
  ushort_t *wt_tm1[2], *wt_tm2[2], *wt_mm1[2], *wt_mm2[2];
  ushort_t *wt_us1h[2], *wt_us1l[2], *wt_us2h[2], *wt_us2l[2];
  ushort_t *wt_gv1h[2], *wt_gv1l[2], *wt_gv2h[2], *wt_gv2l[2];
  for (int l=0;l<2;l++){
    wt_tm1[l] = wtp; wtp += 128*96;
    wt_tm2[l] = wtp; wtp += 128*128;
    wt_mm1[l] = wtp; wtp += 128*416;
    wt_mm2[l] = wtp; wtp += 256*128;
    wt_us1h[l] = wtp; wtp += 128*384;
    wt_us1l[l] = wtp; wtp += 128*384;
    wt_us2h[l] = wtp; wtp += 128*128;
    wt_us2l[l] = wtp; wtp += 128*128;
    wt_gv1h[l] = wtp; wtp += 128*384;
    wt_gv1l[l] = wtp; wtp += 128*384;
    wt_gv2h[l] = wtp; wtp += 128*128;
    wt_gv2l[l] = wtp; wtp += 128*128;
  }

  auto zero = [&](float* p, long n){
    int blocks = (int)((n + 255)/256); if (blocks > 16384) blocks = 16384;
    k_zero<<<blocks, 256, 0, stream>>>(p, n);
  };
  auto wt = [&](const float* W, ushort_t* Wt, int K, int C, int Kpad){
    int n = C*Kpad;
    k_wt<<<(n + 255)/256, 256, 0, stream>>>(W, Wt, K, C, Kpad);
  };
  auto wt2 = [&](const float* W, ushort_t* Whi, ushort_t* Wlo, int K, int C, int Kpad){
    int n = C*Kpad;
    k_wt2<<<(n + 255)/256, 256, 0, stream>>>(W, Whi, Wlo, K, C, Kpad);
  };
  auto csort = [&](const int* keys, int M, int B, int* perm){
    zero((float*)ihist, B + (B+1023)/1024);
    k_hist<<<(M+255)/256, 256, 0, stream>>>(keys, M, ihist);
    int nb = (B+1023)/1024;
    k_scan1<<<nb, 256, 0, stream>>>(ihist, ihist, isums, B);
    k_scan2<<<1, 64, 0, stream>>>(isums, nb);
    k_scan3<<<(B+255)/256, 256, 0, stream>>>(ihist, isums, B);
    k_fill<<<(M+255)/256, 256, 0, stream>>>(keys, M, ihist, perm);
  };

  // ---- prologue ----
  zero(v, (long)N_*384);
  k_init_vn<<<(G_*H_ + 255)/256, 256, 0, stream>>>(vn, vn_init);
  k_geom<<<(E_ + 255)/256, 256, 0, stream>>>(pos, edist, ei, vec, dir, rbf16);
  k_angle<<<(T_ + 255)/256, 256, 0, stream>>>(vec, t_kj, t_ji, angle);
  csort(t_ji,   T_, E_,  perm_t);
  csort(ei+E_,  E_, N_,  perm_e);
  for (int l=0;l<2;l++){
    wt(tm_w1 + l*80*128,   wt_tm1[l],  80, 128,  96);
    wt(tm_w2 + l*128*128,  wt_tm2[l], 128, 128, 128);
    wt(mm_w1 + l*416*128,  wt_mm1[l], 416, 128, 416);
    wt(mm_w2 + l*128*256,  wt_mm2[l], 128, 256, 128);
    wt2(us_w1 + l*384*128, wt_us1h[l], wt_us1l[l], 384, 128, 384);
    wt2(us_w2 + l*128*128, wt_us2h[l], wt_us2l[l], 128, 128, 128);
    wt2(gv_w1 + l*384*128, wt_gv1h[l], wt_gv1l[l], 384, 128, 384);
    wt2(gv_w2 + l*128*128, wt_gv2h[l], wt_gv2l[l], 128, 128, 128);
  }
  k_gemm<<<512, 128, 0, stream>>>(x, node_in_w, node_in_b, s, N_, IND_);

  for (int l=0; l<L_; l++){
    // 1) s += v2n_mlp(vn)[batch]  (snapshots s16)
    k_small_mlp2<<<1, 256, 0, stream>>>(vn, v2n_w1, v2n_b1, v2n_w2, v2n_b2, tg2, 0);
    k_sadd_batch<<<(N_*H_ + 255)/256, 256, 0, stream>>>(s, tg2, batch, s16);

    // 2) triplet MLP (MFMA, sorted by ji) -> eagg
    zero(eagg, (long)E_*128);
    k_mlp2_mfma<<<T_/BROWS, 256, 0, stream>>>(1, perm_t, t_kj, t_ji, rbf16, angle, s16, eagg,
        wt_tm1[l], tm_b1 + l*128, 96,
        wt_tm2[l], tm_b2 + l*128, 1, dir, eagg, nullptr);

    // 3) edge MLP (MFMA, sorted by dst) -> aggs, aggv
    zero(aggs, (long)N_*128);
    zero(aggv, (long)N_*384);
    k_mlp2_mfma<<<E_/BROWS, 256, 0, stream>>>(2, perm_e, ei, ei + E_, rbf16, angle, s16, eagg,
        wt_mm1[l], mm_b1 + l*128, 416,
        wt_mm2[l], mm_b2 + l*256, 2, dir, aggs, aggv);

    // 4+5+6) node update + gated v update (MFMA bf16x3, fp32-equivalent; ctx lives in eagg space)
    k_ctx16<<<(N_*H_ + 255)/256, 256, 0, stream>>>(s, aggs, v, ctx_hi, ctx_lo);
    k_node_mfma<<<N_/BROWS, 256, 0, stream>>>(ctx_hi, ctx_lo, s, v, aggv,
        wt_us1h[l], wt_us1l[l], us_b1 + l*128, wt_us2h[l], wt_us2l[l], us_b2 + l*128,
        wt_gv1h[l], wt_gv1l[l], gv_b1 + l*128, wt_gv2h[l], wt_gv2l[l], gv_b2 + l*128);

    // 7) s = silu(LN(s))
    k_ln_silu<<<N_, 128, 0, stream>>>(s, ln_g + l*128, ln_b + l*128);

    // 8) vn += n2v_mlp(segment_sum(s, batch))
    zero(ssum, (long)G_*128);
    k_segsum<<<(N_*H_ + 255)/256, 256, 0, stream>>>(s, batch, ssum);
    k_small_mlp2<<<1, 256, 0, stream>>>(ssum, n2v_w1, n2v_b1, n2v_w2, n2v_b2, vn, 1);
  }

  // ---- readout ----
  zero(addp, (long)(G_*256 + G_));   // addp and counts contiguous
  k_scatter_nf<<<(N_*256 + 255)/256, 256, 0, stream>>>(s, v, batch, addp, counts);
  k_build_g<<<(G_*640 + 255)/256, 256, 0, stream>>>(addp, counts, vn, gbuf);
  k_head<<<G_, 128, 0, stream>>>(gbuf, head_w1, head_b1, head_w2, head_b2, out);
}

// Round 7
// 1213.858 us; speedup vs baseline: 7.2415x; 1.1991x over previous
//
#include <hip/hip_runtime.h>
#include <math.h>

// ---- problem constants (from reference) ----
#define N_   8192
#define E_   131072
#define T_   262144
#define H_   128
#define IND_ 64
#define G_   32
#define L_   2

// generic fp32 GEMM tiling (node_in only)
#define CW 64
#define RB 16

// MFMA fused MLP tiling
#define MROWS 32     // rows per wave
#define BROWS 128    // rows per block (4 waves)
#define HSTRIDE 136  // LDS hidden row stride (bf16 elems)

// RBF constants
#define STEP_E  ((float)(5.0/31.0))
#define GAMMA_E ((float)(1.0/(2.0*((5.0/31.0)*(5.0/31.0) + 1e-12))))
#define PI_D    3.14159265358979323846
#define STEP_A  ((float)(PI_D/15.0))
#define GAMMA_A ((float)(1.0/(2.0*((PI_D/15.0)*(PI_D/15.0) + 1e-12))))

typedef __attribute__((ext_vector_type(8))) short short8;
typedef __attribute__((ext_vector_type(4))) float f32x4;
typedef unsigned short ushort_t;

static __device__ __forceinline__ float silu_f(float x){ return x / (1.f + expf(-x)); }
static __device__ __forceinline__ float sigmoid_f(float x){ return 1.f / (1.f + expf(-x)); }

static __device__ __forceinline__ ushort_t f2bf(float x){
  unsigned int u = __builtin_bit_cast(unsigned int, x);
  u += 0x7FFFu + ((u >> 16) & 1u);
  return (ushort_t)(u >> 16);
}
static __device__ __forceinline__ float bf2f(ushort_t h){
  unsigned int u = ((unsigned int)h) << 16;
  return __builtin_bit_cast(float, u);
}

// ---------------- small utility kernels ----------------

__global__ void k_zero(float* __restrict__ p, long n){
  long i = (long)blockIdx.x*256 + threadIdx.x;
  long stride = (long)gridDim.x*256;
  for (; i < n; i += stride) p[i] = 0.f;
}

__global__ void k_sentinel(float* __restrict__ p, int n){
  int i = blockIdx.x*256 + threadIdx.x;
  if (i < n) p[i] = 1.0e30f;
}

__global__ void k_init_vn(float* __restrict__ vn, const float* __restrict__ vn_init){
  int i = blockIdx.x*256 + threadIdx.x;
  if (i < G_*H_) vn[i] = vn_init[i & 127];
}

// weight convert+transpose (hi only): W fp32 [K][C] -> Wt bf16 [C][Kpad]
__global__ void k_wt(const float* __restrict__ W, ushort_t* __restrict__ Wt,
                     int K, int C, int Kpad){
  int i = blockIdx.x*256 + threadIdx.x;
  if (i >= C*Kpad) return;
  int c = i / Kpad, k = i % Kpad;
  Wt[i] = (k < K) ? f2bf(W[(size_t)k*C + c]) : (ushort_t)0;
}

// weight convert+transpose with residual: hi + lo (bf16x2 split)
__global__ void k_wt2(const float* __restrict__ W, ushort_t* __restrict__ Whi,
                      ushort_t* __restrict__ Wlo, int K, int C, int Kpad){
  int i = blockIdx.x*256 + threadIdx.x;
  if (i >= C*Kpad) return;
  int c = i / Kpad, k = i % Kpad;
  float w = (k < K) ? W[(size_t)k*C + c] : 0.f;
  ushort_t h = f2bf(w);
  Whi[i] = h;
  Wlo[i] = f2bf(w - bf2f(h));
}

// per-edge: vec, dir, edge RBF(32) in bf16
__global__ void k_geom(const float* __restrict__ pos, const float* __restrict__ dist,
                       const int* __restrict__ ei,
                       float* __restrict__ vec, float* __restrict__ dir,
                       ushort_t* __restrict__ rbf16){
  int e = blockIdx.x*256 + threadIdx.x;
  if (e >= E_) return;
  int s = ei[e], d = ei[E_ + e];
  float vx = pos[d*3+0] - pos[s*3+0];
  float vy = pos[d*3+1] - pos[s*3+1];
  float vz = pos[d*3+2] - pos[s*3+2];
  vec[e*3+0]=vx; vec[e*3+1]=vy; vec[e*3+2]=vz;
  float dd = dist[e];
  float inv = 1.f / (dd + 1e-9f);
  dir[e*3+0]=vx*inv; dir[e*3+1]=vy*inv; dir[e*3+2]=vz*inv;
  #pragma unroll
  for (int i=0;i<32;i++){
    float df = dd - i*STEP_E;
    rbf16[e*32+i] = f2bf(expf(-GAMMA_E*df*df));
  }
}

// per-triplet angle
__global__ void k_angle(const float* __restrict__ vec,
                        const int* __restrict__ kj, const int* __restrict__ ji,
                        float* __restrict__ angle){
  int t = blockIdx.x*256 + threadIdx.x;
  if (t >= T_) return;
  int ea = ji[t], eb = kj[t];
  float ax=vec[ea*3+0], ay=vec[ea*3+1], az=vec[ea*3+2];
  float bx=vec[eb*3+0], by=vec[eb*3+1], bz=vec[eb*3+2];
  float dot = ax*bx + ay*by + az*bz;
  float na = sqrtf(ax*ax+ay*ay+az*az + 1e-12f);
  float nb = sqrtf(bx*bx+by*by+bz*bz + 1e-12f);
  float c = dot / (na*nb + 1e-9f);
  c = fminf(fmaxf(c, -1.f + 1e-7f), 1.f - 1e-7f);
  angle[t] = acosf(c);
}

// ---------------- counting-sort kernels ----------------

__global__ void k_hist(const int* __restrict__ keys, int M, int* __restrict__ hist){
  int i = blockIdx.x*256 + threadIdx.x;
  if (i < M) atomicAdd(&hist[keys[i]], 1);
}

__global__ void k_scan1(const int* __restrict__ in, int* __restrict__ out,
                        int* __restrict__ sums, int B){
  __shared__ int sh[1024];
  int base = blockIdx.x*1024, t = threadIdx.x;
  for (int j=t;j<1024;j+=256) sh[j] = (base+j<B) ? in[base+j] : 0;
  __syncthreads();
  for (int o=1;o<1024;o<<=1){
    int v[4];
    #pragma unroll
    for (int q=0;q<4;q++){ int idx=t+q*256; v[q]=(idx>=o)? sh[idx-o]:0; }
    __syncthreads();
    #pragma unroll
    for (int q=0;q<4;q++){ int idx=t+q*256; sh[idx]+=v[q]; }
    __syncthreads();
  }
  for (int j=t;j<1024;j+=256) if (base+j<B) out[base+j] = (j==0)?0:sh[j-1];
  if (t==0) sums[blockIdx.x] = sh[1023];
}

__global__ void k_scan2(int* __restrict__ sums, int nb){
  if (threadIdx.x==0 && blockIdx.x==0){
    int a=0;
    for (int i=0;i<nb;i++){ int x=sums[i]; sums[i]=a; a+=x; }
  }
}

__global__ void k_scan3(int* __restrict__ out, const int* __restrict__ sums, int B){
  int i = blockIdx.x*256+threadIdx.x;
  if (i<B) out[i] += sums[i>>10];
}

__global__ void k_fill(const int* __restrict__ keys, int M, int* __restrict__ cur,
                       int* __restrict__ perm){
  int i = blockIdx.x*256+threadIdx.x;
  if (i<M){ int p = atomicAdd(&cur[keys[i]],1); perm[p]=i; }
}

// ---------------- MFMA fused 2-layer MLP + sorted segment-scatter ----------------
__launch_bounds__(256, 3)
__global__ void k_mlp2_mfma(int SM,
    const int* __restrict__ perm,
    const int* __restrict__ idx1, const int* __restrict__ idx2,
    const ushort_t* __restrict__ rbf16, const float* __restrict__ angle,
    const ushort_t* __restrict__ s16, const float* __restrict__ eagg_in,
    const ushort_t* __restrict__ W1t, const float* __restrict__ b1, int K1pad,
    const ushort_t* __restrict__ W2t, const float* __restrict__ b2, int OUTgrp,
    const float* __restrict__ dir,
    float* __restrict__ out0, float* __restrict__ out1)
{
  __shared__ ushort_t hid[BROWS*HSTRIDE];   // 34816 B
  __shared__ float mchunk[BROWS][33];       // 16896 B
  __shared__ int   segk[BROWS];
  __shared__ float dirs[BROWS][3];
  const int tid  = threadIdx.x;
  const int wave = tid >> 6;
  const int lane = tid & 63;
  const int n    = lane & 15;
  const int quad = lane >> 4;
  const int kq   = quad*8;
  const int wrow = blockIdx.x*BROWS + wave*MROWS;
  const int lrow = wave*MROWS;

  for (int i=tid; i<BROWS; i+=256){
    int e = perm[blockIdx.x*BROWS + i];
    segk[i] = idx2[e];
    if (SM == 2){
      dirs[i][0]=dir[e*3+0]; dirs[i][1]=dir[e*3+1]; dirs[i][2]=dir[e*3+2];
    }
  }

  const int e0 = perm[wrow + n];
  const int e1 = perm[wrow + 16 + n];

  int i1a = idx1[e0], i1b = idx1[e1];
  int i2a = idx2[e0], i2b = idx2[e1];
  float ang0 = 0.f, ang1 = 0.f;
  if (SM == 1){ ang0 = angle[e0]; ang1 = angle[e1]; }

  // ---------- phase A ----------
  f32x4 acc[2][8];
  #pragma unroll
  for (int rh=0;rh<2;rh++)
    #pragma unroll
    for (int ct=0;ct<8;ct++) acc[rh][ct] = (f32x4){0.f,0.f,0.f,0.f};

  for (int k0 = 0; k0 < K1pad; k0 += 32){
    short8 a0, a1;
    if (SM == 1){
      if (k0 == 0){
        a0 = *(const short8*)&rbf16[(size_t)i1a*32 + kq];
        a1 = *(const short8*)&rbf16[(size_t)i1b*32 + kq];
      } else if (k0 == 32){
        a0 = *(const short8*)&rbf16[(size_t)i2a*32 + kq];
        a1 = *(const short8*)&rbf16[(size_t)i2b*32 + kq];
      } else {
        #pragma unroll
        for (int j=0;j<8;j++){
          int kk = kq + j;
          float v0 = 0.f, v1 = 0.f;
          if (kk < 16){
            float c = (float)kk*STEP_A;
            float d0 = ang0 - c, d1 = ang1 - c;
            v0 = expf(-GAMMA_A*d0*d0); v1 = expf(-GAMMA_A*d1*d1);
          }
          a0[j] = (short)f2bf(v0); a1[j] = (short)f2bf(v1);
        }
      }
    } else {
      int k = k0 + kq;
      if (k0 < 128){
        a0 = *(const short8*)&s16[(size_t)i1a*128 + k];
        a1 = *(const short8*)&s16[(size_t)i1b*128 + k];
      } else if (k0 < 256){
        a0 = *(const short8*)&s16[(size_t)i2a*128 + (k-128)];
        a1 = *(const short8*)&s16[(size_t)i2b*128 + (k-128)];
      } else if (k0 < 288){
        a0 = *(const short8*)&rbf16[(size_t)e0*32 + (k-256)];
        a1 = *(const short8*)&rbf16[(size_t)e1*32 + (k-256)];
      } else {
        const float* p0 = &eagg_in[(size_t)e0*128 + (k-288)];
        const float* p1 = &eagg_in[(size_t)e1*128 + (k-288)];
        f32x4 x0 = *(const f32x4*)p0, x1 = *(const f32x4*)(p0+4);
        f32x4 y0 = *(const f32x4*)p1, y1 = *(const f32x4*)(p1+4);
        #pragma unroll
        for (int j=0;j<4;j++){
          a0[j] = (short)f2bf(x0[j]); a0[4+j] = (short)f2bf(x1[j]);
          a1[j] = (short)f2bf(y0[j]); a1[4+j] = (short)f2bf(y1[j]);
        }
      }
    }
    #pragma unroll
    for (int ct=0;ct<8;ct++){
      short8 b = *(const short8*)&W1t[(size_t)(ct*16 + n)*K1pad + k0 + kq];
      acc[0][ct] = __builtin_amdgcn_mfma_f32_16x16x32_bf16(a0, b, acc[0][ct], 0,0,0);
      acc[1][ct] = __builtin_amdgcn_mfma_f32_16x16x32_bf16(a1, b, acc[1][ct], 0,0,0);
    }
  }

  #pragma unroll
  for (int rh=0;rh<2;rh++){
    #pragma unroll
    for (int ct=0;ct<8;ct++){
      int col = ct*16 + n;
      float bv = b1[col];
      #pragma unroll
      for (int reg=0;reg<4;reg++){
        int rloc = lrow + rh*16 + quad*4 + reg;
        float h = acc[rh][ct][reg] + bv;
        hid[rloc*HSTRIDE + col] = f2bf(silu_f(h));
      }
    }
  }

  // ---------- phase B ----------
  for (int og=0; og<OUTgrp; og++){
    f32x4 acc2[2][8];
    #pragma unroll
    for (int rh=0;rh<2;rh++)
      #pragma unroll
      for (int ct=0;ct<8;ct++) acc2[rh][ct] = (f32x4){0.f,0.f,0.f,0.f};

    #pragma unroll
    for (int k0=0;k0<128;k0+=32){
      short8 a0 = *(const short8*)&hid[(size_t)(lrow + n)*HSTRIDE + k0 + kq];
      short8 a1 = *(const short8*)&hid[(size_t)(lrow + 16 + n)*HSTRIDE + k0 + kq];
      #pragma unroll
      for (int ct=0;ct<8;ct++){
        short8 b = *(const short8*)&W2t[(size_t)(og*128 + ct*16 + n)*128 + k0 + kq];
        acc2[0][ct] = __builtin_amdgcn_mfma_f32_16x16x32_bf16(a0, b, acc2[0][ct], 0,0,0);
        acc2[1][ct] = __builtin_amdgcn_mfma_f32_16x16x32_bf16(a1, b, acc2[1][ct], 0,0,0);
      }
    }

    for (int ch=0; ch<4; ch++){
      const int c0 = ch*32;
      __syncthreads();
      #pragma unroll
      for (int rh=0;rh<2;rh++){
        #pragma unroll
        for (int cti=0;cti<2;cti++){
          int ct = ch*2 + cti;
          int col = ct*16 + n;
          float bv = b2[og*128 + col];
          #pragma unroll
          for (int reg=0;reg<4;reg++){
            int r = lrow + rh*16 + quad*4 + reg;
            mchunk[r][col - c0] = acc2[rh][ct][reg] + bv;
          }
        }
      }
      __syncthreads();
      const int col = c0 + (tid & 31);
      const int w0r = (tid >> 5) * 16;
      if (SM == 1 || og == 0){
        float a = 0.f; int prev = segk[w0r];
        for (int j=0;j<16;j++){
          int r = w0r + j;
          int k = segk[r];
          if (k != prev){ atomicAdd(&out0[(size_t)prev*128 + col], a); a = 0.f; prev = k; }
          a += mchunk[r][col - c0];
        }
        atomicAdd(&out0[(size_t)prev*128 + col], a);
      } else {
        float ax=0.f, ay=0.f, az=0.f; int prev = segk[w0r];
        for (int j=0;j<16;j++){
          int r = w0r + j;
          int k = segk[r];
          if (k != prev){
            size_t b = ((size_t)prev*128 + col)*3;
            atomicAdd(&out1[b+0], ax); atomicAdd(&out1[b+1], ay); atomicAdd(&out1[b+2], az);
            ax=ay=az=0.f; prev = k;
          }
          float m = mchunk[r][col - c0];
          ax += m*dirs[r][0]; ay += m*dirs[r][1]; az += m*dirs[r][2];
        }
        size_t b = ((size_t)prev*128 + col)*3;
        atomicAdd(&out1[b+0], ax); atomicAdd(&out1[b+1], ay); atomicAdd(&out1[b+2], az);
      }
    }
  }
}

// ---------------- prep: split aggs and ||v|| into bf16 hi/lo ----------------
__global__ void k_prep(const float* __restrict__ aggs, const float* __restrict__ v,
                       ushort_t* __restrict__ a16h, ushort_t* __restrict__ a16l,
                       ushort_t* __restrict__ vnh,  ushort_t* __restrict__ vnl){
  int i = blockIdx.x*256 + threadIdx.x;
  if (i >= N_*H_) return;
  float a = aggs[i];
  ushort_t ah = f2bf(a);
  a16h[i] = ah; a16l[i] = f2bf(a - bf2f(ah));
  float v0 = v[(size_t)i*3+0], v1 = v[(size_t)i*3+1], v2 = v[(size_t)i*3+2];
  float nv = sqrtf(v0*v0 + v1*v1 + v2*v2 + 1e-12f);
  ushort_t nh = f2bf(nv);
  vnh[i] = nh; vnl[i] = f2bf(nv - bf2f(nh));
}

// ---------------- MFMA node-update kernel (one wave per block, og = blockIdx.y) ----------------
// ctx = [s | aggs | ||v||] split hi/lo; bf16x3 fp32-equivalent.
// og0: s2[node,col] = s[node,col] + us_mlp(ctx)
// og1: g = sigmoid(gv_mlp(ctx)); v[node,col,xyz] += g*aggv[node,col,xyz]
__launch_bounds__(64, 4)
__global__ void k_node_mfma(
    const float* __restrict__ s_in,
    const ushort_t* __restrict__ a16h, const ushort_t* __restrict__ a16l,
    const ushort_t* __restrict__ vnh,  const ushort_t* __restrict__ vnl,
    float* __restrict__ s2, float* __restrict__ v_out,
    const float* __restrict__ aggv,
    const ushort_t* __restrict__ us1h, const ushort_t* __restrict__ us1l, const float* __restrict__ us_b1,
    const ushort_t* __restrict__ us2h, const ushort_t* __restrict__ us2l, const float* __restrict__ us_b2,
    const ushort_t* __restrict__ gv1h, const ushort_t* __restrict__ gv1l, const float* __restrict__ gv_b1,
    const ushort_t* __restrict__ gv2h, const ushort_t* __restrict__ gv2l, const float* __restrict__ gv_b2)
{
  __shared__ ushort_t hidh[32*HSTRIDE];   // 8704 B
  __shared__ ushort_t hidl[32*HSTRIDE];   // 8704 B
  const int lane = threadIdx.x;
  const int n    = lane & 15;
  const int quad = lane >> 4;
  const int kq   = quad*8;
  const int og   = blockIdx.y;
  const int wrow = blockIdx.x*32;
  const int r0 = wrow + n;
  const int r1 = wrow + 16 + n;

  const ushort_t* W1h = og ? gv1h : us1h;
  const ushort_t* W1l = og ? gv1l : us1l;
  const float*    B1  = og ? gv_b1 : us_b1;
  const ushort_t* W2h = og ? gv2h : us2h;
  const ushort_t* W2l = og ? gv2l : us2l;
  const float*    B2  = og ? gv_b2 : us_b2;

  // ---------- phase A: hidden = silu(ctx @ W1 + b1), bf16x3 ----------
  f32x4 acc[2][8];
  #pragma unroll
  for (int rh=0;rh<2;rh++)
    #pragma unroll
    for (int ct=0;ct<8;ct++) acc[rh][ct] = (f32x4){0.f,0.f,0.f,0.f};

  for (int k0=0; k0<384; k0+=32){
    short8 ah0, al0, ah1, al1;
    const int k = k0 + kq;
    if (k0 < 128){
      // s part: fp32 load + in-register hi/lo split
      const float* p0 = &s_in[(size_t)r0*128 + k];
      const float* p1 = &s_in[(size_t)r1*128 + k];
      f32x4 x0 = *(const f32x4*)p0, x1 = *(const f32x4*)(p0+4);
      f32x4 y0 = *(const f32x4*)p1, y1 = *(const f32x4*)(p1+4);
      #pragma unroll
      for (int j=0;j<4;j++){
        ushort_t h;
        h = f2bf(x0[j]); ah0[j]   = (short)h; al0[j]   = (short)f2bf(x0[j] - bf2f(h));
        h = f2bf(x1[j]); ah0[4+j] = (short)h; al0[4+j] = (short)f2bf(x1[j] - bf2f(h));
        h = f2bf(y0[j]); ah1[j]   = (short)h; al1[j]   = (short)f2bf(y0[j] - bf2f(h));
        h = f2bf(y1[j]); ah1[4+j] = (short)h; al1[4+j] = (short)f2bf(y1[j] - bf2f(h));
      }
    } else if (k0 < 256){
      int kk = k - 128;
      ah0 = *(const short8*)&a16h[(size_t)r0*128 + kk];
      al0 = *(const short8*)&a16l[(size_t)r0*128 + kk];
      ah1 = *(const short8*)&a16h[(size_t)r1*128 + kk];
      al1 = *(const short8*)&a16l[(size_t)r1*128 + kk];
    } else {
      int kk = k - 256;
      ah0 = *(const short8*)&vnh[(size_t)r0*128 + kk];
      al0 = *(const short8*)&vnl[(size_t)r0*128 + kk];
      ah1 = *(const short8*)&vnh[(size_t)r1*128 + kk];
      al1 = *(const short8*)&vnl[(size_t)r1*128 + kk];
    }
    #pragma unroll
    for (int ct=0;ct<8;ct++){
      short8 bh = *(const short8*)&W1h[(size_t)(ct*16 + n)*384 + k0 + kq];
      short8 bl = *(const short8*)&W1l[(size_t)(ct*16 + n)*384 + k0 + kq];
      acc[0][ct] = __builtin_amdgcn_mfma_f32_16x16x32_bf16(ah0, bh, acc[0][ct], 0,0,0);
      acc[0][ct] = __builtin_amdgcn_mfma_f32_16x16x32_bf16(al0, bh, acc[0][ct], 0,0,0);
      acc[0][ct] = __builtin_amdgcn_mfma_f32_16x16x32_bf16(ah0, bl, acc[0][ct], 0,0,0);
      acc[1][ct] = __builtin_amdgcn_mfma_f32_16x16x32_bf16(ah1, bh, acc[1][ct], 0,0,0);
      acc[1][ct] = __builtin_amdgcn_mfma_f32_16x16x32_bf16(al1, bh, acc[1][ct], 0,0,0);
      acc[1][ct] = __builtin_amdgcn_mfma_f32_16x16x32_bf16(ah1, bl, acc[1][ct], 0,0,0);
    }
  }

  // bias + silu -> LDS hi/lo (single wave: no barrier needed)
  #pragma unroll
  for (int rh=0;rh<2;rh++){
    #pragma unroll
    for (int ct=0;ct<8;ct++){
      int col = ct*16 + n;
      float bv = B1[col];
      #pragma unroll
      for (int reg=0;reg<4;reg++){
        int rloc = rh*16 + quad*4 + reg;
        float h = silu_f(acc[rh][ct][reg] + bv);
        ushort_t hh = f2bf(h);
        hidh[rloc*HSTRIDE + col] = hh;
        hidl[rloc*HSTRIDE + col] = f2bf(h - bf2f(hh));
      }
    }
  }

  // ---------- phase B: out = hidden @ W2 + b2, bf16x3 ----------
  f32x4 acc2[2][8];
  #pragma unroll
  for (int rh=0;rh<2;rh++)
    #pragma unroll
    for (int ct=0;ct<8;ct++) acc2[rh][ct] = (f32x4){0.f,0.f,0.f,0.f};

  #pragma unroll
  for (int k0=0;k0<128;k0+=32){
    short8 ah0 = *(const short8*)&hidh[(size_t)(n)*HSTRIDE + k0 + kq];
    short8 ah1 = *(const short8*)&hidh[(size_t)(16 + n)*HSTRIDE + k0 + kq];
    short8 al0 = *(const short8*)&hidl[(size_t)(n)*HSTRIDE + k0 + kq];
    short8 al1 = *(const short8*)&hidl[(size_t)(16 + n)*HSTRIDE + k0 + kq];
    #pragma unroll
    for (int ct=0;ct<8;ct++){
      short8 bh = *(const short8*)&W2h[(size_t)(ct*16 + n)*128 + k0 + kq];
      short8 bl = *(const short8*)&W2l[(size_t)(ct*16 + n)*128 + k0 + kq];
      acc2[0][ct] = __builtin_amdgcn_mfma_f32_16x16x32_bf16(ah0, bh, acc2[0][ct], 0,0,0);
      acc2[0][ct] = __builtin_amdgcn_mfma_f32_16x16x32_bf16(al0, bh, acc2[0][ct], 0,0,0);
      acc2[0][ct] = __builtin_amdgcn_mfma_f32_16x16x32_bf16(ah0, bl, acc2[0][ct], 0,0,0);
      acc2[1][ct] = __builtin_amdgcn_mfma_f32_16x16x32_bf16(ah1, bh, acc2[1][ct], 0,0,0);
      acc2[1][ct] = __builtin_amdgcn_mfma_f32_16x16x32_bf16(al1, bh, acc2[1][ct], 0,0,0);
      acc2[1][ct] = __builtin_amdgcn_mfma_f32_16x16x32_bf16(ah1, bl, acc2[1][ct], 0,0,0);
    }
  }

  if (og == 0){
    #pragma unroll
    for (int rh=0;rh<2;rh++){
      #pragma unroll
      for (int ct=0;ct<8;ct++){
        int col = ct*16 + n;
        float bv = B2[col];
        #pragma unroll
        for (int reg=0;reg<4;reg++){
          int row = wrow + rh*16 + quad*4 + reg;
          size_t idx = (size_t)row*128 + col;
          s2[idx] = s_in[idx] + acc2[rh][ct][reg] + bv;
        }
      }
    }
  } else {
    #pragma unroll
    for (int rh=0;rh<2;rh++){
      #pragma unroll
      for (int ct=0;ct<8;ct++){
        int col = ct*16 + n;
        float bv = B2[col];
        #pragma unroll
        for (int reg=0;reg<4;reg++){
          int row = wrow + rh*16 + quad*4 + reg;
          size_t idx = (size_t)row*128 + col;
          float g = sigmoid_f(acc2[rh][ct][reg] + bv);
          size_t base = idx*3;
          v_out[base+0] += g*aggv[base+0];
          v_out[base+1] += g*aggv[base+1];
          v_out[base+2] += g*aggv[base+2];
        }
      }
    }
  }
}

// ---------------- generic fp32 row-MLP GEMM (node_in only) ----------------
__launch_bounds__(128)
__global__ void k_gemm(const float* __restrict__ A,
                       const float* __restrict__ W,
                       const float* __restrict__ bias,
                       float* __restrict__ C, int R, int K)
{
  __shared__ float ws[CW*128];
  __shared__ float as[RB][CW];
  const int tid = threadIdx.x;
  const int nchunk = (K + CW - 1) / CW;

  for (int rb = blockIdx.x*RB; rb < R; rb += gridDim.x*RB){
    float acc[RB];
    #pragma unroll
    for (int r=0;r<RB;r++) acc[r] = 0.f;

    for (int c=0;c<nchunk;c++){
      const int k0 = c*CW;
      for (int i=tid; i<CW*128; i+=128){
        int kk = i >> 7, col = i & 127;
        int k = k0 + kk;
        ws[i] = (k < K) ? W[k*128 + col] : 0.f;
      }
      for (int i=tid; i<RB*CW; i+=128){
        int r  = i >> 6, kk = i & 63;
        int k  = k0 + kk;
        as[r][kk] = (k < K) ? A[(long)(rb+r)*K + k] : 0.f;
      }
      __syncthreads();
      #pragma unroll 4
      for (int kq2=0; kq2<CW/4; kq2++){
        float w0 = ws[(4*kq2+0)*128 + tid];
        float w1 = ws[(4*kq2+1)*128 + tid];
        float w2 = ws[(4*kq2+2)*128 + tid];
        float w3 = ws[(4*kq2+3)*128 + tid];
        #pragma unroll
        for (int r=0;r<RB;r++){
          const float4 av = *reinterpret_cast<const float4*>(&as[r][4*kq2]);
          acc[r] = fmaf(av.x, w0, acc[r]);
          acc[r] = fmaf(av.y, w1, acc[r]);
          acc[r] = fmaf(av.z, w2, acc[r]);
          acc[r] = fmaf(av.w, w3, acc[r]);
        }
      }
      __syncthreads();
    }

    const float bv = bias[tid];
    #pragma unroll
    for (int r=0;r<RB;r++)
      C[(long)(rb+r)*128 + tid] = acc[r] + bv;
  }
}

// ---------------- small fused kernels ----------------

__launch_bounds__(256)
__global__ void k_small_mlp2(const float* __restrict__ in,
                             const float* __restrict__ w1, const float* __restrict__ b1,
                             const float* __restrict__ w2, const float* __restrict__ b2,
                             float* __restrict__ outp, int accumulate){
  __shared__ float a[32][128];
  __shared__ float h[32][128];
  int tid = threadIdx.x;
  for (int i=tid;i<32*128;i+=256) a[i>>7][i&127] = in[i];
  __syncthreads();
  int col = tid & 127, rg = tid >> 7;
  float acc[16];
  #pragma unroll
  for (int r=0;r<16;r++) acc[r]=0.f;
  for (int k=0;k<128;k++){
    float w = w1[k*128+col];
    #pragma unroll
    for (int r=0;r<16;r++) acc[r] = fmaf(a[rg*16+r][k], w, acc[r]);
  }
  {
    float bv = b1[col];
    #pragma unroll
    for (int r=0;r<16;r++) h[rg*16+r][col] = silu_f(acc[r]+bv);
  }
  __syncthreads();
  #pragma unroll
  for (int r=0;r<16;r++) acc[r]=0.f;
  for (int k=0;k<128;k++){
    float w = w2[k*128+col];
    #pragma unroll
    for (int r=0;r<16;r++) acc[r] = fmaf(h[rg*16+r][k], w, acc[r]);
  }
  {
    float bv = b2[col];
    #pragma unroll
    for (int r=0;r<16;r++){
      int idx = (rg*16+r)*128+col;
      float val = acc[r]+bv;
      outp[idx] = accumulate ? outp[idx]+val : val;
    }
  }
}

__global__ void k_head(const float* __restrict__ gbuf,
                       const float* __restrict__ w1, const float* __restrict__ b1,
                       const float* __restrict__ w2, const float* __restrict__ b2,
                       float* __restrict__ outp){
  __shared__ float red[128];
  int g = blockIdx.x, tid = threadIdx.x;
  float acc = 0.f;
  for (int k=0;k<640;k++) acc = fmaf(gbuf[g*640+k], w1[k*128+tid], acc);
  float h = silu_f(acc + b1[tid]);
  red[tid] = h * w2[tid];
  __syncthreads();
  for (int o=64;o>0;o>>=1){ if (tid<o) red[tid]+=red[tid+o]; __syncthreads(); }
  if (tid == 0) outp[g] = red[0] + b2[0];
}

// ---------------- elementwise / reduction kernels ----------------

__global__ void k_sadd_batch(float* __restrict__ s, const float* __restrict__ t2,
                             const int* __restrict__ batch, ushort_t* __restrict__ s16){
  int i = blockIdx.x*256 + threadIdx.x;
  if (i >= N_*H_) return;
  int n = i >> 7, h = i & 127;
  float v = s[i] + t2[batch[n]*128 + h];
  s[i] = v;
  s16[i] = f2bf(v);
}

// LN + silu: reads in, writes out
__global__ void k_ln_silu(const float* __restrict__ in, float* __restrict__ outp,
                          const float* __restrict__ g, const float* __restrict__ b){
  __shared__ float red[128];
  int n = blockIdx.x, tid = threadIdx.x;
  float x = in[n*128 + tid];
  red[tid] = x; __syncthreads();
  for (int o=64;o>0;o>>=1){ if (tid<o) red[tid]+=red[tid+o]; __syncthreads(); }
  float mu = red[0] * (1.f/128.f);
  __syncthreads();
  float dx = x - mu;
  red[tid] = dx*dx; __syncthreads();
  for (int o=64;o>0;o>>=1){ if (tid<o) red[tid]+=red[tid+o]; __syncthreads(); }
  float var = red[0] * (1.f/128.f);
  float y = dx * rsqrtf(var + 1e-5f) * g[tid] + b[tid];
  outp[n*128 + tid] = silu_f(y);
}

__global__ void k_segsum(const float* __restrict__ s, const int* __restrict__ batch,
                         float* __restrict__ ssum){
  int i = blockIdx.x*256 + threadIdx.x;
  if (i >= N_*H_) return;
  int n = i >> 7, h = i & 127;
  atomicAdd(&ssum[batch[n]*128 + h], s[i]);
}

__global__ void k_scatter_nf(const float* __restrict__ s, const float* __restrict__ v,
                             const int* __restrict__ batch, float* __restrict__ addp,
                             float* __restrict__ counts){
  int i = blockIdx.x*256 + threadIdx.x;
  if (i >= N_*256) return;
  int n = i >> 8, j = i & 255;
  float val;
  if (j < 128){
    val = s[n*128 + j];
  } else {
    int h = j - 128;
    float v0 = v[((size_t)n*128+h)*3+0], v1 = v[((size_t)n*128+h)*3+1], v2 = v[((size_t)n*128+h)*3+2];
    val = sqrtf(v0*v0 + v1*v1 + v2*v2 + 1e-12f);
  }
  int b = batch[n];
  atomicAdd(&addp[b*256 + j], val);
  if (j == 0) atomicAdd(&counts[b], 1.f);
}

__global__ void k_build_g(const float* __restrict__ addp, const float* __restrict__ counts,
                          const float* __restrict__ vn, float* __restrict__ gbuf){
  int i = blockIdx.x*256 + threadIdx.x;
  if (i >= G_*640) return;
  int g = i / 640, j = i % 640;
  float val;
  if (j < 256)       val = addp[g*256 + j];
  else if (j < 512)  val = addp[g*256 + (j-256)] / fmaxf(counts[g], 1.f);
  else               val = vn[g*128 + (j-512)];
  gbuf[i] = val;
}

// ---------------- host launcher ----------------

extern "C" void kernel_launch(void* const* d_in, const int* in_sizes, int n_in,
                              void* d_out, int out_size, void* d_ws, size_t ws_size,
                              hipStream_t stream)
{
  const float* x         = (const float*)d_in[0];
  const float* pos       = (const float*)d_in[1];
  const float* edist     = (const float*)d_in[2];
  const float* node_in_w = (const float*)d_in[3];
  const float* node_in_b = (const float*)d_in[4];
  const float* tm_w1 = (const float*)d_in[5];
  const float* tm_b1 = (const float*)d_in[6];
  const float* tm_w2 = (const float*)d_in[7];
  const float* tm_b2 = (const float*)d_in[8];
  const float* mm_w1 = (const float*)d_in[9];
  const float* mm_b1 = (const float*)d_in[10];
  const float* mm_w2 = (const float*)d_in[11];
  const float* mm_b2 = (const float*)d_in[12];
  const float* us_w1 = (const float*)d_in[13];
  const float* us_b1 = (const float*)d_in[14];
  const float* us_w2 = (const float*)d_in[15];
  const float* us_b2 = (const float*)d_in[16];
  const float* gv_w1 = (const float*)d_in[17];
  const float* gv_b1 = (const float*)d_in[18];
  const float* gv_w2 = (const float*)d_in[19];
  const float* gv_b2 = (const float*)d_in[20];
  const float* ln_g  = (const float*)d_in[21];
  const float* ln_b  = (const float*)d_in[22];
  const float* vn_init = (const float*)d_in[23];
  const float* v2n_w1 = (const float*)d_in[24];
  const float* v2n_b1 = (const float*)d_in[25];
  const float* v2n_w2 = (const float*)d_in[26];
  const float* v2n_b2 = (const float*)d_in[27];
  const float* n2v_w1 = (const float*)d_in[28];
  const float* n2v_b1 = (const float*)d_in[29];
  const float* n2v_w2 = (const float*)d_in[30];
  const float* n2v_b2 = (const float*)d_in[31];
  const float* head_w1 = (const float*)d_in[32];
  const float* head_b1 = (const float*)d_in[33];
  const float* head_w2 = (const float*)d_in[34];
  const float* head_b2 = (const float*)d_in[35];
  const int* ei    = (const int*)d_in[36];
  const int* t_kj  = (const int*)d_in[37];
  const int* t_ji  = (const int*)d_in[38];
  const int* batch = (const int*)d_in[39];
  float* out = (float*)d_out;

  // ---- workspace layout (~117.5 MiB) ----
  float* f = (float*)d_ws;
  size_t off = 0;
  auto alloc = [&](size_t n){ n = (n + 3) & ~(size_t)3; float* p = f + off; off += n; return p; };
  float*    vec    = alloc((size_t)E_*3);   // aliased: perm_t + perm_e after k_angle
  float*    dir    = alloc((size_t)E_*3);
  ushort_t* rbf16  = (ushort_t*)alloc((size_t)E_*16);
  float*    angle  = alloc((size_t)T_);
  float*    eagg   = alloc((size_t)E_*128);  // also hosts a16h/a16l/vnh/vnl/s2 (disjoint lifetime)
  float*    s      = alloc((size_t)N_*128);
  ushort_t* s16    = (ushort_t*)alloc((size_t)N_*64);
  float*    v      = alloc((size_t)N_*384);
  float*    aggs   = alloc((size_t)N_*128);  // aliased: ihist in prologue
  float*    aggv   = alloc((size_t)N_*384);  // contiguous after aggs: zeroed together
  float*    wtbuf_f= alloc((size_t)376832);  // bf16 transposed weights (hi + node-lo)
  float*    vn     = alloc((size_t)G_*128);
  float*    tg2    = alloc((size_t)G_*128);
  float*    ssum   = alloc((size_t)G_*128);
  float*    addp   = alloc((size_t)G_*256);
  float*    counts = alloc((size_t)G_);
  float*    gbuf   = alloc((size_t)G_*640);

  if (off * sizeof(float) > ws_size){
    k_sentinel<<<1, 64, 0, stream>>>(out, G_);
    return;
  }

  // aliases
  int* perm_t = (int*)vec;
  int* perm_e = perm_t + T_;
  int* ihist  = (int*)aggs;           // prologue only
  int* isums  = ihist + 131072;
  // node-update scratch inside eagg (lifetime: after edge MLP, before next-layer eagg zero)
  ushort_t* a16h = (ushort_t*)eagg;                 // N*128 bf16
  ushort_t* a16l = a16h + (size_t)N_*128;
  ushort_t* vnh  = a16l + (size_t)N_*128;
  ushort_t* vnl  = vnh  + (size_t)N_*128;
  float*    s2   = (float*)(vnl + (size_t)N_*128);  // N*128 fp32

  ushort_t* wtp = (ushort_t*)wtbuf_f;
  ushort_t *wt_tm1[2], *wt_tm2[2], *wt_mm1[2], *wt_mm2[2];
  ushort_t *wt_us1h[2], *wt_us1l[2], *wt_us2h[2], *wt_us2l[2];
  ushort_t *wt_gv1h[2], *wt_gv1l[2], *wt_gv2h[2], *wt_gv2l[2];
  for (int l=0;l<2;l++){
    wt_tm1[l] = wtp; wtp += 128*96;
    wt_tm2[l] = wtp; wtp += 128*128;
    wt_mm1[l] = wtp; wtp += 128*416;
    wt_mm2[l] = wtp; wtp += 256*128;
    wt_us1h[l] = wtp; wtp += 128*384;
    wt_us1l[l] = wtp; wtp += 128*384;
    wt_us2h[l] = wtp; wtp += 128*128;
    wt_us2l[l] = wtp; wtp += 128*128;
    wt_gv1h[l] = wtp; wtp += 128*384;
    wt_gv1l[l] = wtp; wtp += 128*384;
    wt_gv2h[l] = wtp; wtp += 128*128;
    wt_gv2l[l] = wtp; wtp += 128*128;
  }

  auto zero = [&](float* p, long n){
    int blocks = (int)((n + 255)/256); if (blocks > 16384) blocks = 16384;
    k_zero<<<blocks, 256, 0, stream>>>(p, n);
  };
  auto wt = [&](const float* W, ushort_t* Wt, int K, int C, int Kpad){
    int n = C*Kpad;
    k_wt<<<(n + 255)/256, 256, 0, stream>>>(W, Wt, K, C, Kpad);
  };
  auto wt2 = [&](const float* W, ushort_t* Whi, ushort_t* Wlo, int K, int C, int Kpad){
    int n = C*Kpad;
    k_wt2<<<(n + 255)/256, 256, 0, stream>>>(W, Whi, Wlo, K, C, Kpad);
  };
  auto csort = [&](const int* keys, int M, int B, int* perm){
    zero((float*)ihist, B + (B+1023)/1024);
    k_hist<<<(M+255)/256, 256, 0, stream>>>(keys, M, ihist);
    int nb = (B+1023)/1024;
    k_scan1<<<nb, 256, 0, stream>>>(ihist, ihist, isums, B);
    k_scan2<<<1, 64, 0, stream>>>(isums, nb);
    k_scan3<<<(B+255)/256, 256, 0, stream>>>(ihist, isums, B);
    k_fill<<<(M+255)/256, 256, 0, stream>>>(keys, M, ihist, perm);
  };

  // ---- prologue ----
  zero(v, (long)N_*384);
  k_init_vn<<<(G_*H_ + 255)/256, 256, 0, stream>>>(vn, vn_init);
  k_geom<<<(E_ + 255)/256, 256, 0, stream>>>(pos, edist, ei, vec, dir, rbf16);
  k_angle<<<(T_ + 255)/256, 256, 0, stream>>>(vec, t_kj, t_ji, angle);
  csort(t_ji,   T_, E_,  perm_t);
  csort(ei+E_,  E_, N_,  perm_e);
  for (int l=0;l<2;l++){
    wt(tm_w1 + l*80*128,   wt_tm1[l],  80, 128,  96);
    wt(tm_w2 + l*128*128,  wt_tm2[l], 128, 128, 128);
    wt(mm_w1 + l*416*128,  wt_mm1[l], 416, 128, 416);
    wt(mm_w2 + l*128*256,  wt_mm2[l], 128, 256, 128);
    wt2(us_w1 + l*384*128, wt_us1h[l], wt_us1l[l], 384, 128, 384);
    wt2(us_w2 + l*128*128, wt_us2h[l], wt_us2l[l], 128, 128, 128);
    wt2(gv_w1 + l*384*128, wt_gv1h[l], wt_gv1l[l], 384, 128, 384);
    wt2(gv_w2 + l*128*128, wt_gv2h[l], wt_gv2l[l], 128, 128, 128);
  }
  k_gemm<<<512, 128, 0, stream>>>(x, node_in_w, node_in_b, s, N_, IND_);

  for (int l=0; l<L_; l++){
    // 1) s += v2n_mlp(vn)[batch]  (snapshots s16)
    k_small_mlp2<<<1, 256, 0, stream>>>(vn, v2n_w1, v2n_b1, v2n_w2, v2n_b2, tg2, 0);
    k_sadd_batch<<<(N_*H_ + 255)/256, 256, 0, stream>>>(s, tg2, batch, s16);

    // 2) triplet MLP (MFMA, sorted by ji) -> eagg
    zero(eagg, (long)E_*128);
    k_mlp2_mfma<<<T_/BROWS, 256, 0, stream>>>(1, perm_t, t_kj, t_ji, rbf16, angle, s16, eagg,
        wt_tm1[l], tm_b1 + l*128, 96,
        wt_tm2[l], tm_b2 + l*128, 1, dir, eagg, nullptr);

    // 3) edge MLP (MFMA, sorted by dst) -> aggs, aggv  (one merged zero: adjacent buffers)
    zero(aggs, (long)N_*512);
    k_mlp2_mfma<<<E_/BROWS, 256, 0, stream>>>(2, perm_e, ei, ei + E_, rbf16, angle, s16, eagg,
        wt_mm1[l], mm_b1 + l*128, 416,
        wt_mm2[l], mm_b2 + l*256, 2, dir, aggs, aggv);

    // 4) prep ctx hi/lo pieces (into eagg space — eagg is dead until next layer)
    k_prep<<<(N_*H_ + 255)/256, 256, 0, stream>>>(aggs, v, a16h, a16l, vnh, vnl);

    // 5+6) node update (s2 = s + us_mlp) + gated v update; one wave/block, og split
    k_node_mfma<<<dim3(N_/32, 2), 64, 0, stream>>>(s, a16h, a16l, vnh, vnl, s2, v, aggv,
        wt_us1h[l], wt_us1l[l], us_b1 + l*128, wt_us2h[l], wt_us2l[l], us_b2 + l*128,
        wt_gv1h[l], wt_gv1l[l], gv_b1 + l*128, wt_gv2h[l], wt_gv2l[l], gv_b2 + l*128);

    // 7) s = silu(LN(s2))
    k_ln_silu<<<N_, 128, 0, stream>>>(s2, s, ln_g + l*128, ln_b + l*128);

    // 8) vn += n2v_mlp(segment_sum(s, batch))
    zero(ssum, (long)G_*128);
    k_segsum<<<(N_*H_ + 255)/256, 256, 0, stream>>>(s, batch, ssum);
    k_small_mlp2<<<1, 256, 0, stream>>>(ssum, n2v_w1, n2v_b1, n2v_w2, n2v_b2, vn, 1);
  }

  // ---- readout ----
  zero(addp, (long)(G_*256 + G_));   // addp and counts contiguous
  k_scatter_nf<<<(N_*256 + 255)/256, 256, 0, stream>>>(s, v, batch, addp, counts);
  k_build_g<<<(G_*640 + 255)/256, 256, 0, stream>>>(addp, counts, vn, gbuf);
  k_head<<<G_, 128, 0, stream>>>(gbuf, head_w1, head_b1, head_w2, head_b2, out);
}

// Round 8
// 1211.467 us; speedup vs baseline: 7.2558x; 1.0020x over previous
//
#include <hip/hip_runtime.h>
#include <math.h>

// ---- problem constants (from reference) ----
#define N_   8192
#define E_   131072
#define T_   262144
#define H_   128
#define IND_ 64
#define G_   32
#define L_   2

// generic fp32 GEMM tiling (node_in only)
#define CW 64
#define RB 16

// MFMA fused MLP tiling
#define MROWS 32     // rows per wave
#define BROWS 128    // rows per block (4 waves)
#define HSTRIDE 136  // LDS hidden row stride (bf16 elems)

// RBF constants
#define STEP_E  ((float)(5.0/31.0))
#define GAMMA_E ((float)(1.0/(2.0*((5.0/31.0)*(5.0/31.0) + 1e-12))))
#define PI_D    3.14159265358979323846
#define STEP_A  ((float)(PI_D/15.0))
#define GAMMA_A ((float)(1.0/(2.0*((PI_D/15.0)*(PI_D/15.0) + 1e-12))))

typedef __attribute__((ext_vector_type(8))) short short8;
typedef __attribute__((ext_vector_type(4))) float f32x4;
typedef unsigned short ushort_t;

static __device__ __forceinline__ float silu_f(float x){ return x / (1.f + expf(-x)); }
static __device__ __forceinline__ float sigmoid_f(float x){ return 1.f / (1.f + expf(-x)); }

static __device__ __forceinline__ ushort_t f2bf(float x){
  unsigned int u = __builtin_bit_cast(unsigned int, x);
  u += 0x7FFFu + ((u >> 16) & 1u);
  return (ushort_t)(u >> 16);
}
static __device__ __forceinline__ float bf2f(ushort_t h){
  unsigned int u = ((unsigned int)h) << 16;
  return __builtin_bit_cast(float, u);
}

// ---------------- small utility kernels ----------------

__global__ void k_zero(float* __restrict__ p, long n){
  long i = (long)blockIdx.x*256 + threadIdx.x;
  long stride = (long)gridDim.x*256;
  for (; i < n; i += stride) p[i] = 0.f;
}

__global__ void k_sentinel(float* __restrict__ p, int n){
  int i = blockIdx.x*256 + threadIdx.x;
  if (i < n) p[i] = 1.0e30f;
}

__global__ void k_init_vn(float* __restrict__ vn, const float* __restrict__ vn_init){
  int i = blockIdx.x*256 + threadIdx.x;
  if (i < G_*H_) vn[i] = vn_init[i & 127];
}

// weight convert+transpose (hi only): W fp32 [K][C] -> Wt bf16 [C][Kpad]
__global__ void k_wt(const float* __restrict__ W, ushort_t* __restrict__ Wt,
                     int K, int C, int Kpad){
  int i = blockIdx.x*256 + threadIdx.x;
  if (i >= C*Kpad) return;
  int c = i / Kpad, k = i % Kpad;
  Wt[i] = (k < K) ? f2bf(W[(size_t)k*C + c]) : (ushort_t)0;
}

// weight convert+transpose with residual: hi + lo (bf16x2 split)
__global__ void k_wt2(const float* __restrict__ W, ushort_t* __restrict__ Whi,
                      ushort_t* __restrict__ Wlo, int K, int C, int Kpad){
  int i = blockIdx.x*256 + threadIdx.x;
  if (i >= C*Kpad) return;
  int c = i / Kpad, k = i % Kpad;
  float w = (k < K) ? W[(size_t)k*C + c] : 0.f;
  ushort_t h = f2bf(w);
  Whi[i] = h;
  Wlo[i] = f2bf(w - bf2f(h));
}

// per-edge: vec, dir, edge RBF(32) in bf16
__global__ void k_geom(const float* __restrict__ pos, const float* __restrict__ dist,
                       const int* __restrict__ ei,
                       float* __restrict__ vec, float* __restrict__ dir,
                       ushort_t* __restrict__ rbf16){
  int e = blockIdx.x*256 + threadIdx.x;
  if (e >= E_) return;
  int s = ei[e], d = ei[E_ + e];
  float vx = pos[d*3+0] - pos[s*3+0];
  float vy = pos[d*3+1] - pos[s*3+1];
  float vz = pos[d*3+2] - pos[s*3+2];
  vec[e*3+0]=vx; vec[e*3+1]=vy; vec[e*3+2]=vz;
  float dd = dist[e];
  float inv = 1.f / (dd + 1e-9f);
  dir[e*3+0]=vx*inv; dir[e*3+1]=vy*inv; dir[e*3+2]=vz*inv;
  #pragma unroll
  for (int i=0;i<32;i++){
    float df = dd - i*STEP_E;
    rbf16[e*32+i] = f2bf(expf(-GAMMA_E*df*df));
  }
}

// per-triplet angle
__global__ void k_angle(const float* __restrict__ vec,
                        const int* __restrict__ kj, const int* __restrict__ ji,
                        float* __restrict__ angle){
  int t = blockIdx.x*256 + threadIdx.x;
  if (t >= T_) return;
  int ea = ji[t], eb = kj[t];
  float ax=vec[ea*3+0], ay=vec[ea*3+1], az=vec[ea*3+2];
  float bx=vec[eb*3+0], by=vec[eb*3+1], bz=vec[eb*3+2];
  float dot = ax*bx + ay*by + az*bz;
  float na = sqrtf(ax*ax+ay*ay+az*az + 1e-12f);
  float nb = sqrtf(bx*bx+by*by+bz*bz + 1e-12f);
  float c = dot / (na*nb + 1e-9f);
  c = fminf(fmaxf(c, -1.f + 1e-7f), 1.f - 1e-7f);
  angle[t] = acosf(c);
}

// ---------------- counting-sort kernels ----------------

__global__ void k_hist(const int* __restrict__ keys, int M, int* __restrict__ hist){
  int i = blockIdx.x*256 + threadIdx.x;
  if (i < M) atomicAdd(&hist[keys[i]], 1);
}

// keyed variant: key = map[keys[i]]
__global__ void k_hist2(const int* __restrict__ keys, const int* __restrict__ map,
                        int M, int* __restrict__ hist){
  int i = blockIdx.x*256 + threadIdx.x;
  if (i < M) atomicAdd(&hist[map[keys[i]]], 1);
}

__global__ void k_scan1(const int* __restrict__ in, int* __restrict__ out,
                        int* __restrict__ sums, int B){
  __shared__ int sh[1024];
  int base = blockIdx.x*1024, t = threadIdx.x;
  for (int j=t;j<1024;j+=256) sh[j] = (base+j<B) ? in[base+j] : 0;
  __syncthreads();
  for (int o=1;o<1024;o<<=1){
    int v[4];
    #pragma unroll
    for (int q=0;q<4;q++){ int idx=t+q*256; v[q]=(idx>=o)? sh[idx-o]:0; }
    __syncthreads();
    #pragma unroll
    for (int q=0;q<4;q++){ int idx=t+q*256; sh[idx]+=v[q]; }
    __syncthreads();
  }
  for (int j=t;j<1024;j+=256) if (base+j<B) out[base+j] = (j==0)?0:sh[j-1];
  if (t==0) sums[blockIdx.x] = sh[1023];
}

__global__ void k_scan2(int* __restrict__ sums, int nb){
  if (threadIdx.x==0 && blockIdx.x==0){
    int a=0;
    for (int i=0;i<nb;i++){ int x=sums[i]; sums[i]=a; a+=x; }
  }
}

__global__ void k_scan3(int* __restrict__ out, const int* __restrict__ sums, int B){
  int i = blockIdx.x*256+threadIdx.x;
  if (i<B) out[i] += sums[i>>10];
}

__global__ void k_fill(const int* __restrict__ keys, int M, int* __restrict__ cur,
                       int* __restrict__ perm){
  int i = blockIdx.x*256+threadIdx.x;
  if (i<M){ int p = atomicAdd(&cur[keys[i]],1); perm[p]=i; }
}

__global__ void k_fill2(const int* __restrict__ keys, const int* __restrict__ map,
                        int M, int* __restrict__ cur, int* __restrict__ perm){
  int i = blockIdx.x*256+threadIdx.x;
  if (i<M){ int p = atomicAdd(&cur[map[keys[i]]],1); perm[p]=i; }
}

// rank[perm[i]] = i
__global__ void k_invert(const int* __restrict__ perm, int* __restrict__ rank, int M){
  int i = blockIdx.x*256+threadIdx.x;
  if (i<M) rank[perm[i]] = i;
}

// ---------------- MFMA fused 2-layer MLP + sorted segment-scatter ----------------
// SM==1 (triplet): rows sorted by rank_e[ji]; scatter key = scatmap[ji] = rank_e[ji];
//                  out0 row index = rank (permuted eagg layout).
// SM==2 (edge):    rows sorted by dst; eagg read is POSITIONAL (row = sorted position)
//                  because eagg was written in rank (= sorted-edge-position) order.
__launch_bounds__(256, 3)
__global__ void k_mlp2_mfma(int SM,
    const int* __restrict__ perm, const int* __restrict__ scatmap,
    const int* __restrict__ idx1, const int* __restrict__ idx2,
    const ushort_t* __restrict__ rbf16, const float* __restrict__ angle,
    const ushort_t* __restrict__ s16, const float* __restrict__ eagg_in,
    const ushort_t* __restrict__ W1t, const float* __restrict__ b1, int K1pad,
    const ushort_t* __restrict__ W2t, const float* __restrict__ b2, int OUTgrp,
    const float* __restrict__ dir,
    float* __restrict__ out0, float* __restrict__ out1)
{
  __shared__ ushort_t hid[BROWS*HSTRIDE];   // 34816 B
  __shared__ float mchunk[BROWS][33];       // 16896 B
  __shared__ int   segk[BROWS];
  __shared__ float dirs[BROWS][3];
  const int tid  = threadIdx.x;
  const int wave = tid >> 6;
  const int lane = tid & 63;
  const int n    = lane & 15;
  const int quad = lane >> 4;
  const int kq   = quad*8;
  const int wrow = blockIdx.x*BROWS + wave*MROWS;
  const int lrow = wave*MROWS;

  for (int i=tid; i<BROWS; i+=256){
    int e = perm[blockIdx.x*BROWS + i];
    int key = idx2[e];
    segk[i] = scatmap ? scatmap[key] : key;
    if (SM == 2){
      dirs[i][0]=dir[e*3+0]; dirs[i][1]=dir[e*3+1]; dirs[i][2]=dir[e*3+2];
    }
  }

  const int e0 = perm[wrow + n];
  const int e1 = perm[wrow + 16 + n];

  int i1a = idx1[e0], i1b = idx1[e1];
  int i2a = idx2[e0], i2b = idx2[e1];
  float ang0 = 0.f, ang1 = 0.f;
  if (SM == 1){ ang0 = angle[e0]; ang1 = angle[e1]; }

  // ---------- phase A ----------
  f32x4 acc[2][8];
  #pragma unroll
  for (int rh=0;rh<2;rh++)
    #pragma unroll
    for (int ct=0;ct<8;ct++) acc[rh][ct] = (f32x4){0.f,0.f,0.f,0.f};

  for (int k0 = 0; k0 < K1pad; k0 += 32){
    short8 a0, a1;
    if (SM == 1){
      if (k0 == 0){
        a0 = *(const short8*)&rbf16[(size_t)i1a*32 + kq];
        a1 = *(const short8*)&rbf16[(size_t)i1b*32 + kq];
      } else if (k0 == 32){
        a0 = *(const short8*)&rbf16[(size_t)i2a*32 + kq];
        a1 = *(const short8*)&rbf16[(size_t)i2b*32 + kq];
      } else {
        #pragma unroll
        for (int j=0;j<8;j++){
          int kk = kq + j;
          float v0 = 0.f, v1 = 0.f;
          if (kk < 16){
            float c = (float)kk*STEP_A;
            float d0 = ang0 - c, d1 = ang1 - c;
            v0 = expf(-GAMMA_A*d0*d0); v1 = expf(-GAMMA_A*d1*d1);
          }
          a0[j] = (short)f2bf(v0); a1[j] = (short)f2bf(v1);
        }
      }
    } else {
      int k = k0 + kq;
      if (k0 < 128){
        a0 = *(const short8*)&s16[(size_t)i1a*128 + k];
        a1 = *(const short8*)&s16[(size_t)i1b*128 + k];
      } else if (k0 < 256){
        a0 = *(const short8*)&s16[(size_t)i2a*128 + (k-128)];
        a1 = *(const short8*)&s16[(size_t)i2b*128 + (k-128)];
      } else if (k0 < 288){
        a0 = *(const short8*)&rbf16[(size_t)e0*32 + (k-256)];
        a1 = *(const short8*)&rbf16[(size_t)e1*32 + (k-256)];
      } else {
        // eagg stored in sorted-edge-position order -> sequential rows
        const float* p0 = &eagg_in[(size_t)(wrow + n)*128 + (k-288)];
        const float* p1 = &eagg_in[(size_t)(wrow + 16 + n)*128 + (k-288)];
        f32x4 x0 = *(const f32x4*)p0, x1 = *(const f32x4*)(p0+4);
        f32x4 y0 = *(const f32x4*)p1, y1 = *(const f32x4*)(p1+4);
        #pragma unroll
        for (int j=0;j<4;j++){
          a0[j] = (short)f2bf(x0[j]); a0[4+j] = (short)f2bf(x1[j]);
          a1[j] = (short)f2bf(y0[j]); a1[4+j] = (short)f2bf(y1[j]);
        }
      }
    }
    #pragma unroll
    for (int ct=0;ct<8;ct++){
      short8 b = *(const short8*)&W1t[(size_t)(ct*16 + n)*K1pad + k0 + kq];
      acc[0][ct] = __builtin_amdgcn_mfma_f32_16x16x32_bf16(a0, b, acc[0][ct], 0,0,0);
      acc[1][ct] = __builtin_amdgcn_mfma_f32_16x16x32_bf16(a1, b, acc[1][ct], 0,0,0);
    }
  }

  #pragma unroll
  for (int rh=0;rh<2;rh++){
    #pragma unroll
    for (int ct=0;ct<8;ct++){
      int col = ct*16 + n;
      float bv = b1[col];
      #pragma unroll
      for (int reg=0;reg<4;reg++){
        int rloc = lrow + rh*16 + quad*4 + reg;
        float h = acc[rh][ct][reg] + bv;
        hid[rloc*HSTRIDE + col] = f2bf(silu_f(h));
      }
    }
  }

  // ---------- phase B ----------
  for (int og=0; og<OUTgrp; og++){
    f32x4 acc2[2][8];
    #pragma unroll
    for (int rh=0;rh<2;rh++)
      #pragma unroll
      for (int ct=0;ct<8;ct++) acc2[rh][ct] = (f32x4){0.f,0.f,0.f,0.f};

    #pragma unroll
    for (int k0=0;k0<128;k0+=32){
      short8 a0 = *(const short8*)&hid[(size_t)(lrow + n)*HSTRIDE + k0 + kq];
      short8 a1 = *(const short8*)&hid[(size_t)(lrow + 16 + n)*HSTRIDE + k0 + kq];
      #pragma unroll
      for (int ct=0;ct<8;ct++){
        short8 b = *(const short8*)&W2t[(size_t)(og*128 + ct*16 + n)*128 + k0 + kq];
        acc2[0][ct] = __builtin_amdgcn_mfma_f32_16x16x32_bf16(a0, b, acc2[0][ct], 0,0,0);
        acc2[1][ct] = __builtin_amdgcn_mfma_f32_16x16x32_bf16(a1, b, acc2[1][ct], 0,0,0);
      }
    }

    for (int ch=0; ch<4; ch++){
      const int c0 = ch*32;
      __syncthreads();
      #pragma unroll
      for (int rh=0;rh<2;rh++){
        #pragma unroll
        for (int cti=0;cti<2;cti++){
          int ct = ch*2 + cti;
          int col = ct*16 + n;
          float bv = b2[og*128 + col];
          #pragma unroll
          for (int reg=0;reg<4;reg++){
            int r = lrow + rh*16 + quad*4 + reg;
            mchunk[r][col - c0] = acc2[rh][ct][reg] + bv;
          }
        }
      }
      __syncthreads();
      const int col = c0 + (tid & 31);
      const int w0r = (tid >> 5) * 16;
      if (SM == 1 || og == 0){
        float a = 0.f; int prev = segk[w0r];
        for (int j=0;j<16;j++){
          int r = w0r + j;
          int k = segk[r];
          if (k != prev){ atomicAdd(&out0[(size_t)prev*128 + col], a); a = 0.f; prev = k; }
          a += mchunk[r][col - c0];
        }
        atomicAdd(&out0[(size_t)prev*128 + col], a);
      } else {
        float ax=0.f, ay=0.f, az=0.f; int prev = segk[w0r];
        for (int j=0;j<16;j++){
          int r = w0r + j;
          int k = segk[r];
          if (k != prev){
            size_t b = ((size_t)prev*128 + col)*3;
            atomicAdd(&out1[b+0], ax); atomicAdd(&out1[b+1], ay); atomicAdd(&out1[b+2], az);
            ax=ay=az=0.f; prev = k;
          }
          float m = mchunk[r][col - c0];
          ax += m*dirs[r][0]; ay += m*dirs[r][1]; az += m*dirs[r][2];
        }
        size_t b = ((size_t)prev*128 + col)*3;
        atomicAdd(&out1[b+0], ax); atomicAdd(&out1[b+1], ay); atomicAdd(&out1[b+2], az);
      }
    }
  }
}

// ---------------- prep: split aggs and ||v|| into bf16 hi/lo ----------------
__global__ void k_prep(const float* __restrict__ aggs, const float* __restrict__ v,
                       ushort_t* __restrict__ a16h, ushort_t* __restrict__ a16l,
                       ushort_t* __restrict__ vnh,  ushort_t* __restrict__ vnl){
  int i = blockIdx.x*256 + threadIdx.x;
  if (i >= N_*H_) return;
  float a = aggs[i];
  ushort_t ah = f2bf(a);
  a16h[i] = ah; a16l[i] = f2bf(a - bf2f(ah));
  float v0 = v[(size_t)i*3+0], v1 = v[(size_t)i*3+1], v2 = v[(size_t)i*3+2];
  float nv = sqrtf(v0*v0 + v1*v1 + v2*v2 + 1e-12f);
  ushort_t nh = f2bf(nv);
  vnh[i] = nh; vnl[i] = f2bf(nv - bf2f(nh));
}

// ---------------- MFMA node-update kernel (one wave per block, og = blockIdx.y) ----------------
__launch_bounds__(64, 4)
__global__ void k_node_mfma(
    const float* __restrict__ s_in,
    const ushort_t* __restrict__ a16h, const ushort_t* __restrict__ a16l,
    const ushort_t* __restrict__ vnh,  const ushort_t* __restrict__ vnl,
    float* __restrict__ s2, float* __restrict__ v_out,
    const float* __restrict__ aggv,
    const ushort_t* __restrict__ us1h, const ushort_t* __restrict__ us1l, const float* __restrict__ us_b1,
    const ushort_t* __restrict__ us2h, const ushort_t* __restrict__ us2l, const float* __restrict__ us_b2,
    const ushort_t* __restrict__ gv1h, const ushort_t* __restrict__ gv1l, const float* __restrict__ gv_b1,
    const ushort_t* __restrict__ gv2h, const ushort_t* __restrict__ gv2l, const float* __restrict__ gv_b2)
{
  __shared__ ushort_t hidh[32*HSTRIDE];   // 8704 B
  __shared__ ushort_t hidl[32*HSTRIDE];   // 8704 B
  const int lane = threadIdx.x;
  const int n    = lane & 15;
  const int quad = lane >> 4;
  const int kq   = quad*8;
  const int og   = blockIdx.y;
  const int wrow = blockIdx.x*32;
  const int r0 = wrow + n;
  const int r1 = wrow + 16 + n;

  const ushort_t* W1h = og ? gv1h : us1h;
  const ushort_t* W1l = og ? gv1l : us1l;
  const float*    B1  = og ? gv_b1 : us_b1;
  const ushort_t* W2h = og ? gv2h : us2h;
  const ushort_t* W2l = og ? gv2l : us2l;
  const float*    B2  = og ? gv_b2 : us_b2;

  // ---------- phase A: hidden = silu(ctx @ W1 + b1), bf16x3 ----------
  f32x4 acc[2][8];
  #pragma unroll
  for (int rh=0;rh<2;rh++)
    #pragma unroll
    for (int ct=0;ct<8;ct++) acc[rh][ct] = (f32x4){0.f,0.f,0.f,0.f};

  for (int k0=0; k0<384; k0+=32){
    short8 ah0, al0, ah1, al1;
    const int k = k0 + kq;
    if (k0 < 128){
      const float* p0 = &s_in[(size_t)r0*128 + k];
      const float* p1 = &s_in[(size_t)r1*128 + k];
      f32x4 x0 = *(const f32x4*)p0, x1 = *(const f32x4*)(p0+4);
      f32x4 y0 = *(const f32x4*)p1, y1 = *(const f32x4*)(p1+4);
      #pragma unroll
      for (int j=0;j<4;j++){
        ushort_t h;
        h = f2bf(x0[j]); ah0[j]   = (short)h; al0[j]   = (short)f2bf(x0[j] - bf2f(h));
        h = f2bf(x1[j]); ah0[4+j] = (short)h; al0[4+j] = (short)f2bf(x1[j] - bf2f(h));
        h = f2bf(y0[j]); ah1[j]   = (short)h; al1[j]   = (short)f2bf(y0[j] - bf2f(h));
        h = f2bf(y1[j]); ah1[4+j] = (short)h; al1[4+j] = (short)f2bf(y1[j] - bf2f(h));
      }
    } else if (k0 < 256){
      int kk = k - 128;
      ah0 = *(const short8*)&a16h[(size_t)r0*128 + kk];
      al0 = *(const short8*)&a16l[(size_t)r0*128 + kk];
      ah1 = *(const short8*)&a16h[(size_t)r1*128 + kk];
      al1 = *(const short8*)&a16l[(size_t)r1*128 + kk];
    } else {
      int kk = k - 256;
      ah0 = *(const short8*)&vnh[(size_t)r0*128 + kk];
      al0 = *(const short8*)&vnl[(size_t)r0*128 + kk];
      ah1 = *(const short8*)&vnh[(size_t)r1*128 + kk];
      al1 = *(const short8*)&vnl[(size_t)r1*128 + kk];
    }
    #pragma unroll
    for (int ct=0;ct<8;ct++){
      short8 bh = *(const short8*)&W1h[(size_t)(ct*16 + n)*384 + k0 + kq];
      short8 bl = *(const short8*)&W1l[(size_t)(ct*16 + n)*384 + k0 + kq];
      acc[0][ct] = __builtin_amdgcn_mfma_f32_16x16x32_bf16(ah0, bh, acc[0][ct], 0,0,0);
      acc[0][ct] = __builtin_amdgcn_mfma_f32_16x16x32_bf16(al0, bh, acc[0][ct], 0,0,0);
      acc[0][ct] = __builtin_amdgcn_mfma_f32_16x16x32_bf16(ah0, bl, acc[0][ct], 0,0,0);
      acc[1][ct] = __builtin_amdgcn_mfma_f32_16x16x32_bf16(ah1, bh, acc[1][ct], 0,0,0);
      acc[1][ct] = __builtin_amdgcn_mfma_f32_16x16x32_bf16(al1, bh, acc[1][ct], 0,0,0);
      acc[1][ct] = __builtin_amdgcn_mfma_f32_16x16x32_bf16(ah1, bl, acc[1][ct], 0,0,0);
    }
  }

  #pragma unroll
  for (int rh=0;rh<2;rh++){
    #pragma unroll
    for (int ct=0;ct<8;ct++){
      int col = ct*16 + n;
      float bv = B1[col];
      #pragma unroll
      for (int reg=0;reg<4;reg++){
        int rloc = rh*16 + quad*4 + reg;
        float h = silu_f(acc[rh][ct][reg] + bv);
        ushort_t hh = f2bf(h);
        hidh[rloc*HSTRIDE + col] = hh;
        hidl[rloc*HSTRIDE + col] = f2bf(h - bf2f(hh));
      }
    }
  }

  // ---------- phase B ----------
  f32x4 acc2[2][8];
  #pragma unroll
  for (int rh=0;rh<2;rh++)
    #pragma unroll
    for (int ct=0;ct<8;ct++) acc2[rh][ct] = (f32x4){0.f,0.f,0.f,0.f};

  #pragma unroll
  for (int k0=0;k0<128;k0+=32){
    short8 ah0 = *(const short8*)&hidh[(size_t)(n)*HSTRIDE + k0 + kq];
    short8 ah1 = *(const short8*)&hidh[(size_t)(16 + n)*HSTRIDE + k0 + kq];
    short8 al0 = *(const short8*)&hidl[(size_t)(n)*HSTRIDE + k0 + kq];
    short8 al1 = *(const short8*)&hidl[(size_t)(16 + n)*HSTRIDE + k0 + kq];
    #pragma unroll
    for (int ct=0;ct<8;ct++){
      short8 bh = *(const short8*)&W2h[(size_t)(ct*16 + n)*128 + k0 + kq];
      short8 bl = *(const short8*)&W2l[(size_t)(ct*16 + n)*128 + k0 + kq];
      acc2[0][ct] = __builtin_amdgcn_mfma_f32_16x16x32_bf16(ah0, bh, acc2[0][ct], 0,0,0);
      acc2[0][ct] = __builtin_amdgcn_mfma_f32_16x16x32_bf16(al0, bh, acc2[0][ct], 0,0,0);
      acc2[0][ct] = __builtin_amdgcn_mfma_f32_16x16x32_bf16(ah0, bl, acc2[0][ct], 0,0,0);
      acc2[1][ct] = __builtin_amdgcn_mfma_f32_16x16x32_bf16(ah1, bh, acc2[1][ct], 0,0,0);
      acc2[1][ct] = __builtin_amdgcn_mfma_f32_16x16x32_bf16(al1, bh, acc2[1][ct], 0,0,0);
      acc2[1][ct] = __builtin_amdgcn_mfma_f32_16x16x32_bf16(ah1, bl, acc2[1][ct], 0,0,0);
    }
  }

  if (og == 0){
    #pragma unroll
    for (int rh=0;rh<2;rh++){
      #pragma unroll
      for (int ct=0;ct<8;ct++){
        int col = ct*16 + n;
        float bv = B2[col];
        #pragma unroll
        for (int reg=0;reg<4;reg++){
          int row = wrow + rh*16 + quad*4 + reg;
          size_t idx = (size_t)row*128 + col;
          s2[idx] = s_in[idx] + acc2[rh][ct][reg] + bv;
        }
      }
    }
  } else {
    #pragma unroll
    for (int rh=0;rh<2;rh++){
      #pragma unroll
      for (int ct=0;ct<8;ct++){
        int col = ct*16 + n;
        float bv = B2[col];
        #pragma unroll
        for (int reg=0;reg<4;reg++){
          int row = wrow + rh*16 + quad*4 + reg;
          size_t idx = (size_t)row*128 + col;
          float g = sigmoid_f(acc2[rh][ct][reg] + bv);
          size_t base = idx*3;
          v_out[base+0] += g*aggv[base+0];
          v_out[base+1] += g*aggv[base+1];
          v_out[base+2] += g*aggv[base+2];
        }
      }
    }
  }
}

// ---------------- generic fp32 row-MLP GEMM (node_in only) ----------------
__launch_bounds__(128)
__global__ void k_gemm(const float* __restrict__ A,
                       const float* __restrict__ W,
                       const float* __restrict__ bias,
                       float* __restrict__ C, int R, int K)
{
  __shared__ float ws[CW*128];
  __shared__ float as[RB][CW];
  const int tid = threadIdx.x;
  const int nchunk = (K + CW - 1) / CW;

  for (int rb = blockIdx.x*RB; rb < R; rb += gridDim.x*RB){
    float acc[RB];
    #pragma unroll
    for (int r=0;r<RB;r++) acc[r] = 0.f;

    for (int c=0;c<nchunk;c++){
      const int k0 = c*CW;
      for (int i=tid; i<CW*128; i+=128){
        int kk = i >> 7, col = i & 127;
        int k = k0 + kk;
        ws[i] = (k < K) ? W[k*128 + col] : 0.f;
      }
      for (int i=tid; i<RB*CW; i+=128){
        int r  = i >> 6, kk = i & 63;
        int k  = k0 + kk;
        as[r][kk] = (k < K) ? A[(long)(rb+r)*K + k] : 0.f;
      }
      __syncthreads();
      #pragma unroll 4
      for (int kq2=0; kq2<CW/4; kq2++){
        float w0 = ws[(4*kq2+0)*128 + tid];
        float w1 = ws[(4*kq2+1)*128 + tid];
        float w2 = ws[(4*kq2+2)*128 + tid];
        float w3 = ws[(4*kq2+3)*128 + tid];
        #pragma unroll
        for (int r=0;r<RB;r++){
          const float4 av = *reinterpret_cast<const float4*>(&as[r][4*kq2]);
          acc[r] = fmaf(av.x, w0, acc[r]);
          acc[r] = fmaf(av.y, w1, acc[r]);
          acc[r] = fmaf(av.z, w2, acc[r]);
          acc[r] = fmaf(av.w, w3, acc[r]);
        }
      }
      __syncthreads();
    }

    const float bv = bias[tid];
    #pragma unroll
    for (int r=0;r<RB;r++)
      C[(long)(rb+r)*128 + tid] = acc[r] + bv;
  }
}

// ---------------- small fused kernels ----------------

__launch_bounds__(256)
__global__ void k_small_mlp2(const float* __restrict__ in,
                             const float* __restrict__ w1, const float* __restrict__ b1,
                             const float* __restrict__ w2, const float* __restrict__ b2,
                             float* __restrict__ outp, int accumulate){
  __shared__ float a[32][128];
  __shared__ float h[32][128];
  int tid = threadIdx.x;
  for (int i=tid;i<32*128;i+=256) a[i>>7][i&127] = in[i];
  __syncthreads();
  int col = tid & 127, rg = tid >> 7;
  float acc[16];
  #pragma unroll
  for (int r=0;r<16;r++) acc[r]=0.f;
  for (int k=0;k<128;k++){
    float w = w1[k*128+col];
    #pragma unroll
    for (int r=0;r<16;r++) acc[r] = fmaf(a[rg*16+r][k], w, acc[r]);
  }
  {
    float bv = b1[col];
    #pragma unroll
    for (int r=0;r<16;r++) h[rg*16+r][col] = silu_f(acc[r]+bv);
  }
  __syncthreads();
  #pragma unroll
  for (int r=0;r<16;r++) acc[r]=0.f;
  for (int k=0;k<128;k++){
    float w = w2[k*128+col];
    #pragma unroll
    for (int r=0;r<16;r++) acc[r] = fmaf(h[rg*16+r][k], w, acc[r]);
  }
  {
    float bv = b2[col];
    #pragma unroll
    for (int r=0;r<16;r++){
      int idx = (rg*16+r)*128+col;
      float val = acc[r]+bv;
      outp[idx] = accumulate ? outp[idx]+val : val;
    }
  }
}

__global__ void k_head(const float* __restrict__ gbuf,
                       const float* __restrict__ w1, const float* __restrict__ b1,
                       const float* __restrict__ w2, const float* __restrict__ b2,
                       float* __restrict__ outp){
  __shared__ float red[128];
  int g = blockIdx.x, tid = threadIdx.x;
  float acc = 0.f;
  for (int k=0;k<640;k++) acc = fmaf(gbuf[g*640+k], w1[k*128+tid], acc);
  float h = silu_f(acc + b1[tid]);
  red[tid] = h * w2[tid];
  __syncthreads();
  for (int o=64;o>0;o>>=1){ if (tid<o) red[tid]+=red[tid+o]; __syncthreads(); }
  if (tid == 0) outp[g] = red[0] + b2[0];
}

// ---------------- elementwise / reduction kernels ----------------

__global__ void k_sadd_batch(float* __restrict__ s, const float* __restrict__ t2,
                             const int* __restrict__ batch, ushort_t* __restrict__ s16){
  int i = blockIdx.x*256 + threadIdx.x;
  if (i >= N_*H_) return;
  int n = i >> 7, h = i & 127;
  float v = s[i] + t2[batch[n]*128 + h];
  s[i] = v;
  s16[i] = f2bf(v);
}

__global__ void k_ln_silu(const float* __restrict__ in, float* __restrict__ outp,
                          const float* __restrict__ g, const float* __restrict__ b){
  __shared__ float red[128];
  int n = blockIdx.x, tid = threadIdx.x;
  float x = in[n*128 + tid];
  red[tid] = x; __syncthreads();
  for (int o=64;o>0;o>>=1){ if (tid<o) red[tid]+=red[tid+o]; __syncthreads(); }
  float mu = red[0] * (1.f/128.f);
  __syncthreads();
  float dx = x - mu;
  red[tid] = dx*dx; __syncthreads();
  for (int o=64;o>0;o>>=1){ if (tid<o) red[tid]+=red[tid+o]; __syncthreads(); }
  float var = red[0] * (1.f/128.f);
  float y = dx * rsqrtf(var + 1e-5f) * g[tid] + b[tid];
  outp[n*128 + tid] = silu_f(y);
}

__global__ void k_segsum(const float* __restrict__ s, const int* __restrict__ batch,
                         float* __restrict__ ssum){
  int i = blockIdx.x*256 + threadIdx.x;
  if (i >= N_*H_) return;
  int n = i >> 7, h = i & 127;
  atomicAdd(&ssum[batch[n]*128 + h], s[i]);
}

__global__ void k_scatter_nf(const float* __restrict__ s, const float* __restrict__ v,
                             const int* __restrict__ batch, float* __restrict__ addp,
                             float* __restrict__ counts){
  int i = blockIdx.x*256 + threadIdx.x;
  if (i >= N_*256) return;
  int n = i >> 8, j = i & 255;
  float val;
  if (j < 128){
    val = s[n*128 + j];
  } else {
    int h = j - 128;
    float v0 = v[((size_t)n*128+h)*3+0], v1 = v[((size_t)n*128+h)*3+1], v2 = v[((size_t)n*128+h)*3+2];
    val = sqrtf(v0*v0 + v1*v1 + v2*v2 + 1e-12f);
  }
  int b = batch[n];
  atomicAdd(&addp[b*256 + j], val);
  if (j == 0) atomicAdd(&counts[b], 1.f);
}

__global__ void k_build_g(const float* __restrict__ addp, const float* __restrict__ counts,
                          const float* __restrict__ vn, float* __restrict__ gbuf){
  int i = blockIdx.x*256 + threadIdx.x;
  if (i >= G_*640) return;
  int g = i / 640, j = i % 640;
  float val;
  if (j < 256)       val = addp[g*256 + j];
  else if (j < 512)  val = addp[g*256 + (j-256)] / fmaxf(counts[g], 1.f);
  else               val = vn[g*128 + (j-512)];
  gbuf[i] = val;
}

// ---------------- host launcher ----------------

extern "C" void kernel_launch(void* const* d_in, const int* in_sizes, int n_in,
                              void* d_out, int out_size, void* d_ws, size_t ws_size,
                              hipStream_t stream)
{
  const float* x         = (const float*)d_in[0];
  const float* pos       = (const float*)d_in[1];
  const float* edist     = (const float*)d_in[2];
  const float* node_in_w = (const float*)d_in[3];
  const float* node_in_b = (const float*)d_in[4];
  const float* tm_w1 = (const float*)d_in[5];
  const float* tm_b1 = (const float*)d_in[6];
  const float* tm_w2 = (const float*)d_in[7];
  const float* tm_b2 = (const float*)d_in[8];
  const float* mm_w1 = (const float*)d_in[9];
  const float* mm_b1 = (const float*)d_in[10];
  const float* mm_w2 = (const float*)d_in[11];
  const float* mm_b2 = (const float*)d_in[12];
  const float* us_w1 = (const float*)d_in[13];
  const float* us_b1 = (const float*)d_in[14];
  const float* us_w2 = (const float*)d_in[15];
  const float* us_b2 = (const float*)d_in[16];
  const float* gv_w1 = (const float*)d_in[17];
  const float* gv_b1 = (const float*)d_in[18];
  const float* gv_w2 = (const float*)d_in[19];
  const float* gv_b2 = (const float*)d_in[20];
  const float* ln_g  = (const float*)d_in[21];
  const float* ln_b  = (const float*)d_in[22];
  const float* vn_init = (const float*)d_in[23];
  const float* v2n_w1 = (const float*)d_in[24];
  const float* v2n_b1 = (const float*)d_in[25];
  const float* v2n_w2 = (const float*)d_in[26];
  const float* v2n_b2 = (const float*)d_in[27];
  const float* n2v_w1 = (const float*)d_in[28];
  const float* n2v_b1 = (const float*)d_in[29];
  const float* n2v_w2 = (const float*)d_in[30];
  const float* n2v_b2 = (const float*)d_in[31];
  const float* head_w1 = (const float*)d_in[32];
  const float* head_b1 = (const float*)d_in[33];
  const float* head_w2 = (const float*)d_in[34];
  const float* head_b2 = (const float*)d_in[35];
  const int* ei    = (const int*)d_in[36];
  const int* t_kj  = (const int*)d_in[37];
  const int* t_ji  = (const int*)d_in[38];
  const int* batch = (const int*)d_in[39];
  float* out = (float*)d_out;

  // ---- workspace layout (~118.0 MiB) ----
  float* f = (float*)d_ws;
  size_t off = 0;
  auto alloc = [&](size_t n){ n = (n + 3) & ~(size_t)3; float* p = f + off; off += n; return p; };
  float*    vec    = alloc((size_t)E_*3);   // aliased: perm_t + perm_e after k_angle
  float*    dir    = alloc((size_t)E_*3);
  ushort_t* rbf16  = (ushort_t*)alloc((size_t)E_*16);
  float*    angle  = alloc((size_t)T_);
  float*    eagg   = alloc((size_t)E_*128);  // permuted-row layout; also hosts node scratch
  float*    s      = alloc((size_t)N_*128);
  ushort_t* s16    = (ushort_t*)alloc((size_t)N_*64);
  float*    v      = alloc((size_t)N_*384);
  float*    aggs   = alloc((size_t)N_*128);  // aliased: ihist in prologue
  float*    aggv   = alloc((size_t)N_*384);  // contiguous after aggs: zeroed together
  float*    rank_f = alloc((size_t)E_);      // rank_e (E ints)
  float*    wtbuf_f= alloc((size_t)376832);  // bf16 transposed weights (hi + node-lo)
  float*    vn     = alloc((size_t)G_*128);
  float*    tg2    = alloc((size_t)G_*128);
  float*    ssum   = alloc((size_t)G_*128);
  float*    addp   = alloc((size_t)G_*256);
  float*    counts = alloc((size_t)G_);
  float*    gbuf   = alloc((size_t)G_*640);

  if (off * sizeof(float) > ws_size){
    k_sentinel<<<1, 64, 0, stream>>>(out, G_);
    return;
  }

  // aliases
  int* perm_t = (int*)vec;
  int* perm_e = perm_t + T_;
  int* rank_e = (int*)rank_f;
  int* ihist  = (int*)aggs;           // prologue only
  int* isums  = ihist + 131072;
  // node-update scratch inside eagg (lifetime: after edge MLP, before next-layer eagg zero)
  ushort_t* a16h = (ushort_t*)eagg;                 // N*128 bf16
  ushort_t* a16l = a16h + (size_t)N_*128;
  ushort_t* vnh  = a16l + (size_t)N_*128;
  ushort_t* vnl  = vnh  + (size_t)N_*128;
  float*    s2   = (float*)(vnl + (size_t)N_*128);  // N*128 fp32

  ushort_t* wtp = (ushort_t*)wtbuf_f;
  ushort_t *wt_tm1[2], *wt_tm2[2], *wt_mm1[2], *wt_mm2[2];
  ushort_t *wt_us1h[2], *wt_us1l[2], *wt_us2h[2], *wt_us2l[2];
  ushort_t *wt_gv1h[2], *wt_gv1l[2], *wt_gv2h[2], *wt_gv2l[2];
  for (int l=0;l<2;l++){
    wt_tm1[l] = wtp; wtp += 128*96;
    wt_tm2[l] = wtp; wtp += 128*128;
    wt_mm1[l] = wtp; wtp += 128*416;
    wt_mm2[l] = wtp; wtp += 256*128;
    wt_us1h[l] = wtp; wtp += 128*384;
    wt_us1l[l] = wtp; wtp += 128*384;
    wt_us2h[l] = wtp; wtp += 128*128;
    wt_us2l[l] = wtp; wtp += 128*128;
    wt_gv1h[l] = wtp; wtp += 128*384;
    wt_gv1l[l] = wtp; wtp += 128*384;
    wt_gv2h[l] = wtp; wtp += 128*128;
    wt_gv2l[l] = wtp; wtp += 128*128;
  }

  auto zero = [&](float* p, long n){
    int blocks = (int)((n + 255)/256); if (blocks > 16384) blocks = 16384;
    k_zero<<<blocks, 256, 0, stream>>>(p, n);
  };
  auto wt = [&](const float* W, ushort_t* Wt, int K, int C, int Kpad){
    int n = C*Kpad;
    k_wt<<<(n + 255)/256, 256, 0, stream>>>(W, Wt, K, C, Kpad);
  };
  auto wt2 = [&](const float* W, ushort_t* Whi, ushort_t* Wlo, int K, int C, int Kpad){
    int n = C*Kpad;
    k_wt2<<<(n + 255)/256, 256, 0, stream>>>(W, Whi, Wlo, K, C, Kpad);
  };
  auto csort = [&](const int* keys, const int* map, int M, int B, int* perm){
    zero((float*)ihist, B + (B+1023)/1024);
    if (map) k_hist2<<<(M+255)/256, 256, 0, stream>>>(keys, map, M, ihist);
    else     k_hist <<<(M+255)/256, 256, 0, stream>>>(keys, M, ihist);
    int nb = (B+1023)/1024;
    k_scan1<<<nb, 256, 0, stream>>>(ihist, ihist, isums, B);
    k_scan2<<<1, 64, 0, stream>>>(isums, nb);
    k_scan3<<<(B+255)/256, 256, 0, stream>>>(ihist, isums, B);
    if (map) k_fill2<<<(M+255)/256, 256, 0, stream>>>(keys, map, M, ihist, perm);
    else     k_fill <<<(M+255)/256, 256, 0, stream>>>(keys, M, ihist, perm);
  };

  // ---- prologue ----
  zero(v, (long)N_*384);
  k_init_vn<<<(G_*H_ + 255)/256, 256, 0, stream>>>(vn, vn_init);
  k_geom<<<(E_ + 255)/256, 256, 0, stream>>>(pos, edist, ei, vec, dir, rbf16);
  k_angle<<<(T_ + 255)/256, 256, 0, stream>>>(vec, t_kj, t_ji, angle);
  // edges sorted by dst, then rank_e = inverse perm, then triplets sorted by rank_e[ji]
  csort(ei+E_, nullptr, E_, N_, perm_e);
  k_invert<<<(E_+255)/256, 256, 0, stream>>>(perm_e, rank_e, E_);
  csort(t_ji, rank_e, T_, E_, perm_t);
  for (int l=0;l<2;l++){
    wt(tm_w1 + l*80*128,   wt_tm1[l],  80, 128,  96);
    wt(tm_w2 + l*128*128,  wt_tm2[l], 128, 128, 128);
    wt(mm_w1 + l*416*128,  wt_mm1[l], 416, 128, 416);
    wt(mm_w2 + l*128*256,  wt_mm2[l], 128, 256, 128);
    wt2(us_w1 + l*384*128, wt_us1h[l], wt_us1l[l], 384, 128, 384);
    wt2(us_w2 + l*128*128, wt_us2h[l], wt_us2l[l], 128, 128, 128);
    wt2(gv_w1 + l*384*128, wt_gv1h[l], wt_gv1l[l], 384, 128, 384);
    wt2(gv_w2 + l*128*128, wt_gv2h[l], wt_gv2l[l], 128, 128, 128);
  }
  k_gemm<<<512, 128, 0, stream>>>(x, node_in_w, node_in_b, s, N_, IND_);

  for (int l=0; l<L_; l++){
    // 1) s += v2n_mlp(vn)[batch]  (snapshots s16)
    k_small_mlp2<<<1, 256, 0, stream>>>(vn, v2n_w1, v2n_b1, v2n_w2, v2n_b2, tg2, 0);
    k_sadd_batch<<<(N_*H_ + 255)/256, 256, 0, stream>>>(s, tg2, batch, s16);

    // 2) triplet MLP (MFMA, sorted by rank_e[ji]) -> eagg in permuted-row order
    zero(eagg, (long)E_*128);
    k_mlp2_mfma<<<T_/BROWS, 256, 0, stream>>>(1, perm_t, rank_e, t_kj, t_ji, rbf16, angle, s16, eagg,
        wt_tm1[l], tm_b1 + l*128, 96,
        wt_tm2[l], tm_b2 + l*128, 1, dir, eagg, nullptr);

    // 3) edge MLP (MFMA, sorted by dst; eagg read sequentially) -> aggs, aggv
    zero(aggs, (long)N_*512);
    k_mlp2_mfma<<<E_/BROWS, 256, 0, stream>>>(2, perm_e, nullptr, ei, ei + E_, rbf16, angle, s16, eagg,
        wt_mm1[l], mm_b1 + l*128, 416,
        wt_mm2[l], mm_b2 + l*256, 2, dir, aggs, aggv);

    // 4) prep ctx hi/lo pieces (into eagg space — eagg is dead until next layer)
    k_prep<<<(N_*H_ + 255)/256, 256, 0, stream>>>(aggs, v, a16h, a16l, vnh, vnl);

    // 5+6) node update (s2 = s + us_mlp) + gated v update; one wave/block, og split
    k_node_mfma<<<dim3(N_/32, 2), 64, 0, stream>>>(s, a16h, a16l, vnh, vnl, s2, v, aggv,
        wt_us1h[l], wt_us1l[l], us_b1 + l*128, wt_us2h[l], wt_us2l[l], us_b2 + l*128,
        wt_gv1h[l], wt_gv1l[l], gv_b1 + l*128, wt_gv2h[l], wt_gv2l[l], gv_b2 + l*128);

    // 7) s = silu(LN(s2))
    k_ln_silu<<<N_, 128, 0, stream>>>(s2, s, ln_g + l*128, ln_b + l*128);

    // 8) vn += n2v_mlp(segment_sum(s, batch))
    zero(ssum, (long)G_*128);
    k_segsum<<<(N_*H_ + 255)/256, 256, 0, stream>>>(s, batch, ssum);
    k_small_mlp2<<<1, 256, 0, stream>>>(ssum, n2v_w1, n2v_b1, n2v_w2, n2v_b2, vn, 1);
  }

  // ---- readout ----
  zero(addp, (long)(G_*256 + G_));   // addp and counts contiguous
  k_scatter_nf<<<(N_*256 + 255)/256, 256, 0, stream>>>(s, v, batch, addp, counts);
  k_build_g<<<(G_*640 + 255)/256, 256, 0, stream>>>(addp, counts, vn, gbuf);
  k_head<<<G_, 128, 0, stream>>>(gbuf, head_w1, head_b1, head_w2, head_b2, out);
}